// Round 2
// baseline (3221.683 us; speedup 1.0000x reference)
//
#include <hip/hip_runtime.h>
#include <cstdint>
#include <cstddef>

#define Bdim 8
#define Tdim 128
#define Sdim 256
#define Hdim 1024
#define Vdim 32000

typedef unsigned short u16;
typedef __attribute__((ext_vector_type(8))) short short8;
typedef __attribute__((ext_vector_type(4))) short short4v;
typedef __attribute__((ext_vector_type(4))) float f32x4;

union Frag { short8 v; short4v h[2]; };

__device__ __forceinline__ float bf2f(u16 u){
  union { unsigned int i; float f; } x; x.i = ((unsigned int)u) << 16; return x.f;
}
__device__ __forceinline__ u16 f2b(float f){
  union { float f; unsigned int u; } x; x.f = f;
  unsigned int r = x.u + 0x7FFFu + ((x.u >> 16) & 1u);  // RNE
  return (u16)(r >> 16);
}

__device__ __forceinline__ void gload16(const void* g, void* l){
  __builtin_amdgcn_global_load_lds((const __attribute__((address_space(1))) unsigned int*)g,
                                   (__attribute__((address_space(3))) unsigned int*)l, 16, 0, 0);
}

// Bool dtype detector: bool arrays may arrive as int32 or byte-sized.
// For int32 little-endian 0/1 values, every byte at index i%4!=0 is 0.
// flag=1 -> byte bools, flag=0 -> int32 bools.
__global__ __launch_bounds__(256) void detect_bool_k(const unsigned char* __restrict__ p, int* __restrict__ flag){
  __shared__ int s;
  if (threadIdx.x == 0) s = 0;
  __syncthreads();
  int loc = 0;
  for (int i = threadIdx.x; i < 65536; i += 256)
    if ((i & 3) && p[i]) loc = 1;
  if (loc) atomicOr(&s, 1);
  __syncthreads();
  if (threadIdx.x == 0) *flag = s;
}

__device__ __forceinline__ bool mask_at(const void* m, size_t idx, int byteflag){
  if (byteflag) return ((const unsigned char*)m)[idx] != 0;
  return ((const int*)m)[idx] != 0;
}

// ---------------- generic GEMM: C[m][n] = alpha*sum_k A[m][k]*Bt[n][k] + bias[n]
// A bf16 (u16 bits). Bt either bf16 (BF32=false, staged via global_load_lds) or
// fp32 (BF32=true, reg-staged + converted). PERMB applies the LSTM gate-row
// interleave perm to Bt row index (w_ih case). MASKED fuses pattern_masks.
template<typename OutT, bool BF32, bool MASKED, bool PERMB>
__global__ __launch_bounds__(256) void gemm_bt(
    const u16* __restrict__ A, int lda, long sA,
    const void* __restrict__ Bp, int ldb, long sB,
    OutT* __restrict__ C, int ldc, long sC,
    const float* __restrict__ bias,
    const void* __restrict__ mask,
    const int* __restrict__ mflag,
    int K, float alpha)
{
  __shared__ alignas(16) char ldsA[8192];   // 128 x 32 bf16
  __shared__ alignas(16) char ldsB[8192];
  const int tid  = threadIdx.x;
  const int lane = tid & 63, wid = tid >> 6;
  const int lm = lane & 15, lg = lane >> 4;
  const int wm = wid >> 1, wn = wid & 1;            // 2x2 waves, 64x64 each
  const int m0 = blockIdx.y * 128, n0 = blockIdx.x * 128;
  const int z  = blockIdx.z;
  const char* Ab = (const char*)(A + (size_t)z * sA);

  f32x4 acc[4][4];
#pragma unroll
  for (int i = 0; i < 4; i++)
#pragma unroll
    for (int j = 0; j < 4; j++) acc[i][j] = (f32x4){0.f, 0.f, 0.f, 0.f};

  // fp32-B staging coords (one row per 2 threads, 16 floats each)
  const int brow = tid >> 1, bhalf = tid & 1;
  int bsrow = n0 + brow;
  if (PERMB) bsrow = (bsrow & 3) * Hdim + (bsrow >> 2);

  for (int k0 = 0; k0 < K; k0 += 32) {
    {  // stage A tile via async global->LDS, 16B/lane, linear layout
      const char* ga = Ab + ((size_t)m0 * lda + k0) * 2;
      const int f0 = tid, f1 = tid + 256;
      gload16(ga + (size_t)(f0 >> 2) * (lda * 2) + (f0 & 3) * 16, ldsA + (f0 & ~63) * 16);
      gload16(ga + (size_t)(f1 >> 2) * (lda * 2) + (f1 & 3) * 16, ldsA + (f1 & ~63) * 16);
    }
    if (BF32) {
      const float* Bf = (const float*)Bp + (size_t)z * sB;
      const float4* src = (const float4*)(Bf + (size_t)bsrow * ldb + k0 + bhalf * 16);
      float4 v0 = src[0], v1 = src[1], v2 = src[2], v3 = src[3];
      union { short8 v; short s[8]; } p0, p1;
      p0.s[0]=(short)f2b(v0.x); p0.s[1]=(short)f2b(v0.y); p0.s[2]=(short)f2b(v0.z); p0.s[3]=(short)f2b(v0.w);
      p0.s[4]=(short)f2b(v1.x); p0.s[5]=(short)f2b(v1.y); p0.s[6]=(short)f2b(v1.z); p0.s[7]=(short)f2b(v1.w);
      p1.s[0]=(short)f2b(v2.x); p1.s[1]=(short)f2b(v2.y); p1.s[2]=(short)f2b(v2.z); p1.s[3]=(short)f2b(v2.w);
      p1.s[4]=(short)f2b(v3.x); p1.s[5]=(short)f2b(v3.y); p1.s[6]=(short)f2b(v3.z); p1.s[7]=(short)f2b(v3.w);
      char* d = ldsB + brow * 64 + bhalf * 32;
      *(short8*)d        = p0.v;
      *(short8*)(d + 16) = p1.v;
    } else {
      const char* gb = (const char*)Bp + (size_t)z * sB * 2 + ((size_t)n0 * ldb + k0) * 2;
      const int f0 = tid, f1 = tid + 256;
      gload16(gb + (size_t)(f0 >> 2) * (ldb * 2) + (f0 & 3) * 16, ldsB + (f0 & ~63) * 16);
      gload16(gb + (size_t)(f1 >> 2) * (ldb * 2) + (f1 & 3) * 16, ldsB + (f1 & ~63) * 16);
    }
    __syncthreads();

    Frag a[4], b[4];
#pragma unroll
    for (int mi = 0; mi < 4; mi++) {
      const char* p = ldsA + (wm * 64 + mi * 16 + lm) * 64 + lg * 8;
      a[mi].h[0] = *(const short4v*)p;
      a[mi].h[1] = *(const short4v*)(p + 32);
    }
#pragma unroll
    for (int ni = 0; ni < 4; ni++) {
      const char* p = ldsB + (wn * 64 + ni * 16 + lm) * 64 + lg * 8;
      b[ni].h[0] = *(const short4v*)p;
      b[ni].h[1] = *(const short4v*)(p + 32);
    }
#pragma unroll
    for (int mi = 0; mi < 4; mi++)
#pragma unroll
      for (int ni = 0; ni < 4; ni++)
        acc[mi][ni] = __builtin_amdgcn_mfma_f32_16x16x32_bf16(a[mi].v, b[ni].v, acc[mi][ni], 0, 0, 0);
    __syncthreads();
  }

  const int bflag = MASKED ? *mflag : 0;
  // epilogue: D row=(lane>>4)*4+j, col=lane&15   [m89-verified mapping]
#pragma unroll
  for (int mi = 0; mi < 4; mi++) {
#pragma unroll
    for (int ni = 0; ni < 4; ni++) {
      const int row = m0 + wm * 64 + mi * 16 + lg * 4;
      const int col = n0 + wn * 64 + ni * 16 + lm;
      const float bb = bias ? bias[col] : 0.f;
#pragma unroll
      for (int j = 0; j < 4; j++) {
        float v = acc[mi][ni][j] * alpha + bb;
        if (MASKED) { if (!mask_at(mask, (size_t)(row + j) * ldc + col, bflag)) v = -10000.0f; }
        const size_t o = (size_t)z * sC + (size_t)(row + j) * ldc + col;
        if constexpr (sizeof(OutT) == 2) C[o] = (OutT)f2b(v); else C[o] = (OutT)v;
      }
    }
  }
}

// ---------------- fused LSTM step: gates = xpre[:,t,:] + h @ whh_perm.T ; cell update
// gate rows permuted so cols 4j..4j+3 = (i,f,g,o) of hidden unit j.
__global__ __launch_bounds__(256) void lstm_step(
    const u16* __restrict__ xpre,   // (1024 rows = b*128+t, 4096) bf16, includes b_ih+b_hh
    const u16* __restrict__ whh,    // (4096, 1024) bf16, gate-permuted rows
    u16* __restrict__ hpad,         // (16, 1024) bf16, rows 8..15 zero
    float* __restrict__ cbuf,       // (8, 1024) f32
    u16* __restrict__ cat,          // (1024, 2048) bf16; h written to left half
    int t)
{
  __shared__ float g_lds[4][8][17];
  const int tid  = threadIdx.x;
  const int lane = tid & 63, wid = tid >> 6;
  const int lm = lane & 15, lg = lane >> 4;
  const int n0 = (blockIdx.x * 4 + wid) * 16;   // 16 gate-cols per wave = 4 hidden units

  f32x4 acc;
#pragma unroll
  for (int j = 0; j < 4; j++) {
    const int m = lg * 4 + j;
    acc[j] = (m < 8) ? bf2f(xpre[(size_t)(m * Tdim + t) * 4096 + n0 + lm]) : 0.f;
  }
  const u16* bt = whh + (size_t)(n0 + lm) * Hdim;   // Bt row = gate col
  const u16* at = hpad + (size_t)lm * Hdim;         // A row = batch
#pragma unroll 4
  for (int kk = 0; kk < 32; kk++) {
    const int kb = kk * 32 + lg * 4;
    Frag a, b;
    a.h[0] = *(const short4v*)(at + kb);
    a.h[1] = *(const short4v*)(at + kb + 16);
    b.h[0] = *(const short4v*)(bt + kb);
    b.h[1] = *(const short4v*)(bt + kb + 16);
    acc = __builtin_amdgcn_mfma_f32_16x16x32_bf16(a.v, b.v, acc, 0, 0, 0);
  }
#pragma unroll
  for (int j = 0; j < 4; j++) {
    const int m = lg * 4 + j;
    if (m < 8) g_lds[wid][m][lm] = acc[j];
  }
  __syncthreads();
  if (lane < 32) {
    const int m = lane & 7, u = lane >> 3;
    const float gi = g_lds[wid][m][u * 4 + 0];
    const float gf = g_lds[wid][m][u * 4 + 1];
    const float gg = g_lds[wid][m][u * 4 + 2];
    const float go = g_lds[wid][m][u * 4 + 3];
    const int hj = (n0 >> 2) + u;
    const float cold = cbuf[m * Hdim + hj];
    const float si = 1.f / (1.f + expf(-gi));
    const float sf = 1.f / (1.f + expf(-gf));
    const float so = 1.f / (1.f + expf(-go));
    const float cn = sf * cold + si * tanhf(gg);
    const float hn = so * tanhf(cn);
    cbuf[m * Hdim + hj] = cn;
    const u16 hb = f2b(hn);
    hpad[m * Hdim + hj] = hb;
    cat[(size_t)(m * Tdim + t) * 2048 + hj] = hb;
  }
}

// ---------------- small kernels
__global__ __launch_bounds__(256) void conv_whh_perm(const float* __restrict__ w, u16* __restrict__ o){
  const int n = blockIdx.x;
  const int p = (n & 3) * Hdim + (n >> 2);
  const int k0 = threadIdx.x * 4;
  const float4 v = *(const float4*)(w + (size_t)p * Hdim + k0);
  u16* op = o + (size_t)n * Hdim + k0;
  op[0] = f2b(v.x); op[1] = f2b(v.y); op[2] = f2b(v.z); op[3] = f2b(v.w);
}
__global__ __launch_bounds__(256) void bias_fold_k(const float* __restrict__ bi, const float* __restrict__ bh, float* __restrict__ o){
  const int n = blockIdx.x * 256 + threadIdx.x;
  const int p = (n & 3) * Hdim + (n >> 2);
  o[n] = bi[p] + bh[p];
}
__global__ __launch_bounds__(256) void embed_k(const int* __restrict__ ids, const float* __restrict__ tok,
                                               const float* __restrict__ pos, u16* __restrict__ x){
  const int row = blockIdx.x;
  const int t = row & (Tdim - 1);
  const int id = ids[row];
  const int h0 = threadIdx.x * 4;
  const float4 a = *(const float4*)(tok + (size_t)id * Hdim + h0);
  const float4 p = *(const float4*)(pos + (size_t)t * Hdim + h0);
  u16* op = x + (size_t)row * Hdim + h0;
  op[0] = f2b(a.x + p.x); op[1] = f2b(a.y + p.y); op[2] = f2b(a.z + p.z); op[3] = f2b(a.w + p.w);
}
__global__ __launch_bounds__(256) void cvt_bf16_k(const float* __restrict__ in, u16* __restrict__ out){
  const size_t i = ((size_t)blockIdx.x * 256 + threadIdx.x) * 4;
  const float4 v = *(const float4*)(in + i);
  out[i] = f2b(v.x); out[i+1] = f2b(v.y); out[i+2] = f2b(v.z); out[i+3] = f2b(v.w);
}
__global__ __launch_bounds__(256) void init_hc_k(u16* __restrict__ hpad, float* __restrict__ cbuf){
  const int i = blockIdx.x * 256 + threadIdx.x;
  if (i < 16 * Hdim) hpad[i] = 0;
  if (i < 8 * Hdim) cbuf[i] = 0.f;
}
__global__ __launch_bounds__(256) void ln_rows(const float* __restrict__ in, u16* __restrict__ out,
                                               const float* __restrict__ g, const float* __restrict__ be){
  const int row = blockIdx.x, tid = threadIdx.x;
  const int lane = tid & 63, wid = tid >> 6;
  const float4 x = *(const float4*)(in + (size_t)row * Hdim + tid * 4);
  float s = x.x + x.y + x.z + x.w;
  float q = x.x * x.x + x.y * x.y + x.z * x.z + x.w * x.w;
  for (int o = 32; o; o >>= 1) { s += __shfl_down(s, o, 64); q += __shfl_down(q, o, 64); }
  __shared__ float sm[8];
  if (lane == 0) { sm[wid] = s; sm[4 + wid] = q; }
  __syncthreads();
  const float ts = sm[0] + sm[1] + sm[2] + sm[3];
  const float tq = sm[4] + sm[5] + sm[6] + sm[7];
  const float mean = ts * (1.f / Hdim);
  const float var  = tq * (1.f / Hdim) - mean * mean;
  const float r = rsqrtf(var + 1e-5f);
  const int h0 = tid * 4;
  const float4 gv = *(const float4*)(g + h0);
  const float4 bv = *(const float4*)(be + h0);
  u16* op = out + (size_t)row * Hdim + h0;
  op[0] = f2b((x.x - mean) * r * gv.x + bv.x);
  op[1] = f2b((x.y - mean) * r * gv.y + bv.y);
  op[2] = f2b((x.z - mean) * r * gv.z + bv.z);
  op[3] = f2b((x.w - mean) * r * gv.w + bv.w);
}
__global__ __launch_bounds__(256) void softmax_k(const float* __restrict__ sc, const void* __restrict__ am,
                                                 const int* __restrict__ mflag, u16* __restrict__ w){
  const int row = blockIdx.x, tid = threadIdx.x;
  const int lane = tid & 63, wid = tid >> 6;
  const int b = row >> 7;
  const int bflag = *mflag;
  const float v = sc[(size_t)row * Sdim + tid];
  const bool mk = mask_at(am, (size_t)b * Sdim + tid, bflag);
  const float vm = mk ? v : -10000.0f;
  float mx = vm;
  for (int o = 32; o; o >>= 1) mx = fmaxf(mx, __shfl_down(mx, o, 64));
  __shared__ float sm[8];
  if (lane == 0) sm[wid] = mx;
  __syncthreads();
  mx = fmaxf(fmaxf(sm[0], sm[1]), fmaxf(sm[2], sm[3]));
  const float ex = mk ? expf(vm - mx) : 0.f;
  float ss = ex;
  for (int o = 32; o; o >>= 1) ss += __shfl_down(ss, o, 64);
  if (lane == 0) sm[4 + wid] = ss;
  __syncthreads();
  const float tot = sm[4] + sm[5] + sm[6] + sm[7];
  w[(size_t)row * Sdim + tid] = f2b(ex / (tot + 1e-6f));
}
__global__ __launch_bounds__(256) void transp_k(const u16* __restrict__ kn, u16* __restrict__ knT){
  __shared__ u16 tile[64][65];
  const int b = blockIdx.z, h0 = blockIdx.x * 64, s0 = blockIdx.y * 64;
  const u16* src = kn  + (size_t)b * Sdim * Hdim;
  u16* dst       = knT + (size_t)b * Hdim * Sdim;
  for (int e = threadIdx.x; e < 4096; e += 256) {
    const int r = e >> 6, c = e & 63;
    tile[r][c] = src[(size_t)(s0 + r) * Hdim + h0 + c];
  }
  __syncthreads();
  for (int e = threadIdx.x; e < 4096; e += 256) {
    const int hr = e >> 6, scc = e & 63;
    dst[(size_t)(h0 + hr) * Sdim + s0 + scc] = tile[scc][hr];
  }
}

extern "C" void kernel_launch(void* const* d_in, const int* in_sizes, int n_in,
                              void* d_out, int out_size, void* d_ws, size_t ws_size,
                              hipStream_t stream) {
  const int*   input_ids = (const int*)d_in[0];
  const float* enc   = (const float*)d_in[1];
  const void*  pmask = d_in[2];
  const void*  amask = d_in[3];
  const float* tok  = (const float*)d_in[4];
  const float* pos  = (const float*)d_in[5];
  const float* w_ih = (const float*)d_in[6];
  const float* w_hh = (const float*)d_in[7];
  const float* b_ih = (const float*)d_in[8];
  const float* b_hh = (const float*)d_in[9];
  const float* wq = (const float*)d_in[10];
  const float* bq = (const float*)d_in[11];
  const float* wk = (const float*)d_in[12];
  const float* bk = (const float*)d_in[13];
  const float* wc = (const float*)d_in[14];
  const float* bc = (const float*)d_in[15];
  const float* wo = (const float*)d_in[16];
  const float* bo = (const float*)d_in[17];
  const float* g1  = (const float*)d_in[18];
  const float* be1 = (const float*)d_in[19];
  const float* g2  = (const float*)d_in[20];
  const float* be2 = (const float*)d_in[21];
  float* out = (float*)d_out;

  char* ws = (char*)d_ws;
  size_t off = 0;
  auto alloc = [&](size_t b){ size_t o = off; off += (b + 255) & ~(size_t)255; return o; };
  u16*   whhb  = (u16*)  (ws + alloc((size_t)4096 * 1024 * 2));
  float* biasf = (float*)(ws + alloc(4096 * 4));
  u16*   xbf   = (u16*)  (ws + alloc((size_t)1024 * 1024 * 2));
  u16*   encb  = (u16*)  (ws + alloc((size_t)2048 * 1024 * 2));
  u16*   xpre  = (u16*)  (ws + alloc((size_t)1024 * 4096 * 2));
  u16*   hpad  = (u16*)  (ws + alloc(16 * 1024 * 2));
  float* cbuf  = (float*)(ws + alloc(8 * 1024 * 4));
  u16*   cat   = (u16*)  (ws + alloc((size_t)1024 * 2048 * 2));
  float* qlin  = (float*)(ws + alloc((size_t)1024 * 1024 * 4));
  u16*   qn    = (u16*)  (ws + alloc((size_t)1024 * 1024 * 2));
  float* klin  = (float*)(ws + alloc((size_t)2048 * 1024 * 4));
  u16*   kn    = (u16*)  (ws + alloc((size_t)2048 * 1024 * 2));
  u16*   knT   = (u16*)  (ws + alloc((size_t)2048 * 1024 * 2));
  float* scores= (float*)(ws + alloc((size_t)8 * 128 * 256 * 4));
  u16*   attw  = (u16*)  (ws + alloc((size_t)8 * 128 * 256 * 2));
  float* hlin  = (float*)(ws + alloc((size_t)1024 * 1024 * 4));
  u16*   hid   = (u16*)  (ws + alloc((size_t)1024 * 1024 * 2));
  int*   bflag = (int*)  (ws + alloc(256));
  (void)ws_size; (void)in_sizes; (void)n_in; (void)out_size;

  detect_bool_k<<<1, 256, 0, stream>>>((const unsigned char*)pmask, bflag);
  conv_whh_perm<<<4096, 256, 0, stream>>>(w_hh, whhb);
  bias_fold_k<<<16, 256, 0, stream>>>(b_ih, b_hh, biasf);
  embed_k<<<1024, 256, 0, stream>>>(input_ids, tok, pos, xbf);
  cvt_bf16_k<<<2048, 256, 0, stream>>>(enc, encb);
  init_hc_k<<<64, 256, 0, stream>>>(hpad, cbuf);

  // x_pre = x @ w_ih_perm.T + (b_ih + b_hh)   -> bf16 (1024 x 4096)
  gemm_bt<u16, true, false, true><<<dim3(32, 8, 1), 256, 0, stream>>>(
      xbf, 1024, 0, w_ih, 1024, 0, xpre, 4096, 0, biasf, nullptr, nullptr, 1024, 1.f);

  for (int t = 0; t < Tdim; t++)
    lstm_step<<<64, 256, 0, stream>>>(xpre, whhb, hpad, cbuf, cat, t);

  // q = lstm_out @ wq.T + bq ; LN(g1,be1)
  gemm_bt<float, true, false, false><<<dim3(8, 8, 1), 256, 0, stream>>>(
      cat, 2048, 0, wq, 1024, 0, qlin, 1024, 0, bq, nullptr, nullptr, 1024, 1.f);
  ln_rows<<<1024, 256, 0, stream>>>(qlin, qn, g1, be1);
  // k = enc @ wk.T + bk ; LN(g1,be1)
  gemm_bt<float, true, false, false><<<dim3(8, 16, 1), 256, 0, stream>>>(
      encb, 1024, 0, wk, 1024, 0, klin, 1024, 0, bk, nullptr, nullptr, 1024, 1.f);
  ln_rows<<<2048, 256, 0, stream>>>(klin, kn, g1, be1);
  transp_k<<<dim3(16, 4, 8), 256, 0, stream>>>(kn, knT);

  // scores = qn @ kn^T * scale   (batched over 8)
  gemm_bt<float, false, false, false><<<dim3(2, 1, 8), 256, 0, stream>>>(
      qn, 1024, 131072, kn, 1024, 262144, scores, 256, 32768, nullptr, nullptr, nullptr, 1024, 0.015625f);
  softmax_k<<<1024, 256, 0, stream>>>(scores, amask, bflag, attw);
  // ctx = w @ kn  -> right half of cat   (batched)
  gemm_bt<u16, false, false, false><<<dim3(8, 1, 8), 256, 0, stream>>>(
      attw, 256, 32768, knT, 256, 262144, cat + 1024, 2048, 262144, nullptr, nullptr, nullptr, 256, 1.f);

  // hidden = LN( cat @ wc.T + bc ; g2,be2 )
  gemm_bt<float, true, false, false><<<dim3(8, 8, 1), 256, 0, stream>>>(
      cat, 2048, 0, wc, 2048, 0, hlin, 1024, 0, bc, nullptr, nullptr, 2048, 1.f);
  ln_rows<<<1024, 256, 0, stream>>>(hlin, hid, g2, be2);

  // logits = hidden @ wo.T + bo, masked
  gemm_bt<float, true, true, false><<<dim3(250, 8, 1), 256, 0, stream>>>(
      hid, 1024, 0, wo, 1024, 0, out, 32000, 0, bo, pmask, bflag, 1024, 1.f);
}

// Round 3
// 3115.844 us; speedup vs baseline: 1.0340x; 1.0340x over previous
//
#include <hip/hip_runtime.h>
#include <cstdint>
#include <cstddef>

#define Bdim 8
#define Tdim 128
#define Sdim 256
#define Hdim 1024
#define Vdim 32000
#define NBLK 128

typedef unsigned short u16;
typedef __attribute__((ext_vector_type(8))) short short8;
typedef __attribute__((ext_vector_type(4))) short short4v;
typedef __attribute__((ext_vector_type(4))) float f32x4;

union Frag { short8 v; short4v h[2]; };

__device__ __forceinline__ float bf2f(u16 u){
  union { unsigned int i; float f; } x; x.i = ((unsigned int)u) << 16; return x.f;
}
__device__ __forceinline__ u16 f2b(float f){
  union { float f; unsigned int u; } x; x.f = f;
  unsigned int r = x.u + 0x7FFFu + ((x.u >> 16) & 1u);  // RNE
  return (u16)(r >> 16);
}

__device__ __forceinline__ void gload16(const void* g, void* l){
  __builtin_amdgcn_global_load_lds((const __attribute__((address_space(1))) unsigned int*)g,
                                   (__attribute__((address_space(3))) unsigned int*)l, 16, 0, 0);
}

// 16B-cell swizzle for 64B-wide LDS tile rows (4 cells/row): spreads 16-row
// fragment reads over 8 banks (2-way = free, m136). Periodic-16 in r.
__device__ __forceinline__ int qsw(int r){ return (r + (r >> 2)) & 3; }

// Bool dtype detector: bool arrays may arrive as int32 or byte-sized.
__global__ __launch_bounds__(256) void detect_bool_k(const unsigned char* __restrict__ p, int* __restrict__ flag){
  __shared__ int s;
  if (threadIdx.x == 0) s = 0;
  __syncthreads();
  int loc = 0;
  for (int i = threadIdx.x; i < 65536; i += 256)
    if ((i & 3) && p[i]) loc = 1;
  if (loc) atomicOr(&s, 1);
  __syncthreads();
  if (threadIdx.x == 0) *flag = s;
}

__device__ __forceinline__ bool mask_at(const void* m, size_t idx, int byteflag){
  if (byteflag) return ((const unsigned char*)m)[idx] != 0;
  return ((const int*)m)[idx] != 0;
}

// ---------------- generic GEMM: C[m][n] = alpha*sum_k A[m][k]*Bt[n][k] + bias[n]
template<typename OutT, bool BF32, bool MASKED, bool PERMB>
__global__ __launch_bounds__(256) void gemm_bt(
    const u16* __restrict__ A, int lda, long sA,
    const void* __restrict__ Bp, int ldb, long sB,
    OutT* __restrict__ C, int ldc, long sC,
    const float* __restrict__ bias,
    const void* __restrict__ mask,
    const int* __restrict__ mflag,
    int K, float alpha)
{
  __shared__ alignas(16) char ldsA[8192];   // 128 x 32 bf16, cell-swizzled
  __shared__ alignas(16) char ldsB[8192];
  const int tid  = threadIdx.x;
  const int lane = tid & 63, wid = tid >> 6;
  const int lm = lane & 15, lg = lane >> 4;
  const int wm = wid >> 1, wn = wid & 1;            // 2x2 waves, 64x64 each
  const int m0 = blockIdx.y * 128, n0 = blockIdx.x * 128;
  const int z  = blockIdx.z;
  const char* Ab = (const char*)(A + (size_t)z * sA);

  f32x4 acc[4][4];
#pragma unroll
  for (int i = 0; i < 4; i++)
#pragma unroll
    for (int j = 0; j < 4; j++) acc[i][j] = (f32x4){0.f, 0.f, 0.f, 0.f};

  const int brow = tid >> 1, bhalf = tid & 1;
  int bsrow = n0 + brow;
  if (PERMB) bsrow = (bsrow & 3) * Hdim + (bsrow >> 2);
  const int qb_st = qsw(brow);

  for (int k0 = 0; k0 < K; k0 += 32) {
    {  // stage A: linear LDS dest, swizzled global source (rule #21)
      const char* ga = Ab + ((size_t)m0 * lda + k0) * 2;
      const int f0 = tid, f1 = tid + 256;
      const int r0 = f0 >> 2, r1 = f1 >> 2;
      gload16(ga + (size_t)r0 * (lda * 2) + ((f0 & 3) ^ qsw(r0)) * 16, ldsA + (f0 & ~63) * 16);
      gload16(ga + (size_t)r1 * (lda * 2) + ((f1 & 3) ^ qsw(r1)) * 16, ldsA + (f1 & ~63) * 16);
    }
    if (BF32) {
      const float* Bf = (const float*)Bp + (size_t)z * sB;
      const float4* src = (const float4*)(Bf + (size_t)bsrow * ldb + k0 + bhalf * 16);
      float4 v0 = src[0], v1 = src[1], v2 = src[2], v3 = src[3];
      union { short8 v; short s[8]; } p0, p1;
      p0.s[0]=(short)f2b(v0.x); p0.s[1]=(short)f2b(v0.y); p0.s[2]=(short)f2b(v0.z); p0.s[3]=(short)f2b(v0.w);
      p0.s[4]=(short)f2b(v1.x); p0.s[5]=(short)f2b(v1.y); p0.s[6]=(short)f2b(v1.z); p0.s[7]=(short)f2b(v1.w);
      p1.s[0]=(short)f2b(v2.x); p1.s[1]=(short)f2b(v2.y); p1.s[2]=(short)f2b(v2.z); p1.s[3]=(short)f2b(v2.w);
      p1.s[4]=(short)f2b(v3.x); p1.s[5]=(short)f2b(v3.y); p1.s[6]=(short)f2b(v3.z); p1.s[7]=(short)f2b(v3.w);
      char* base = ldsB + brow * 64;
      *(short8*)(base + (((bhalf * 2 + 0) ^ qb_st) * 16)) = p0.v;
      *(short8*)(base + (((bhalf * 2 + 1) ^ qb_st) * 16)) = p1.v;
    } else {
      const char* gb = (const char*)Bp + (size_t)z * sB * 2 + ((size_t)n0 * ldb + k0) * 2;
      const int f0 = tid, f1 = tid + 256;
      const int r0 = f0 >> 2, r1 = f1 >> 2;
      gload16(gb + (size_t)r0 * (ldb * 2) + ((f0 & 3) ^ qsw(r0)) * 16, ldsB + (f0 & ~63) * 16);
      gload16(gb + (size_t)r1 * (ldb * 2) + ((f1 & 3) ^ qsw(r1)) * 16, ldsB + (f1 & ~63) * 16);
    }
    __syncthreads();

    Frag a[4], b[4];
#pragma unroll
    for (int mi = 0; mi < 4; mi++) {
      const int rr = wm * 64 + mi * 16 + lm;
      const int q = qsw(rr);
      const char* p = ldsA + rr * 64 + (lg & 1) * 8;
      a[mi].h[0] = *(const short4v*)(p + (((lg >> 1) ^ q) * 16));
      a[mi].h[1] = *(const short4v*)(p + ((((lg >> 1) | 2) ^ q) * 16));
    }
#pragma unroll
    for (int ni = 0; ni < 4; ni++) {
      const int rr = wn * 64 + ni * 16 + lm;
      const int q = qsw(rr);
      const char* p = ldsB + rr * 64 + (lg & 1) * 8;
      b[ni].h[0] = *(const short4v*)(p + (((lg >> 1) ^ q) * 16));
      b[ni].h[1] = *(const short4v*)(p + ((((lg >> 1) | 2) ^ q) * 16));
    }
#pragma unroll
    for (int mi = 0; mi < 4; mi++)
#pragma unroll
      for (int ni = 0; ni < 4; ni++)
        acc[mi][ni] = __builtin_amdgcn_mfma_f32_16x16x32_bf16(a[mi].v, b[ni].v, acc[mi][ni], 0, 0, 0);
    __syncthreads();
  }

  const int bflag = MASKED ? *mflag : 0;
#pragma unroll
  for (int mi = 0; mi < 4; mi++) {
#pragma unroll
    for (int ni = 0; ni < 4; ni++) {
      const int row = m0 + wm * 64 + mi * 16 + lg * 4;
      const int col = n0 + wn * 64 + ni * 16 + lm;
      const float bb = bias ? bias[col] : 0.f;
#pragma unroll
      for (int j = 0; j < 4; j++) {
        float v = acc[mi][ni][j] * alpha + bb;
        if (MASKED) { if (!mask_at(mask, (size_t)(row + j) * ldc + col, bflag)) v = -10000.0f; }
        const size_t o = (size_t)z * sC + (size_t)(row + j) * ldc + col;
        if constexpr (sizeof(OutT) == 2) C[o] = (OutT)f2b(v); else C[o] = (OutT)v;
      }
    }
  }
}

// ---------------- persistent LSTM with manual grid barrier
__device__ __forceinline__ void gridbar(int* cnt, int* gen){
  __syncthreads();
  if (threadIdx.x == 0) {
    __threadfence();   // agent release: L2 writeback (cross-XCD visibility)
    const int g = __hip_atomic_load(gen, __ATOMIC_RELAXED, __HIP_MEMORY_SCOPE_AGENT);
    const int a = __hip_atomic_fetch_add(cnt, 1, __ATOMIC_ACQ_REL, __HIP_MEMORY_SCOPE_AGENT);
    if (a == NBLK - 1) {
      __hip_atomic_store(cnt, 0, __ATOMIC_RELAXED, __HIP_MEMORY_SCOPE_AGENT);
      __hip_atomic_fetch_add(gen, 1, __ATOMIC_ACQ_REL, __HIP_MEMORY_SCOPE_AGENT);
    } else {
      while (__hip_atomic_load(gen, __ATOMIC_ACQUIRE, __HIP_MEMORY_SCOPE_AGENT) == g)
        __builtin_amdgcn_s_sleep(2);
    }
    __threadfence();   // agent acquire: invalidate stale L1/L2 lines
  }
  __syncthreads();
}

// Block bx owns gate-cols [bx*32, bx*32+32) (8 hidden units). whh rows live in
// LDS for the whole sequence. h exchanged via double-buffered global hpad.
__global__ __launch_bounds__(128) void lstm_persist(
    const u16* __restrict__ xpre,   // (b*128+t, 4096) bf16, includes biases
    const u16* __restrict__ whh,    // (4096, 1024) bf16, gate-permuted rows
    u16* __restrict__ hpad,         // 2 x (8 x 1024) bf16 double buffer
    u16* __restrict__ cat,          // (1024, 2048) bf16; h -> left half
    int* __restrict__ bar)          // [0]=cnt [32]=gen (zeroed per launch)
{
  __shared__ alignas(16) u16 wlds[32 * 1024];  // 64KB, cell c^(r&7) swizzle
  __shared__ alignas(16) u16 hlds[8 * 1024];   // 16KB, cell c^r swizzle
  __shared__ float g_lds[2][8][17];
  const int tid = threadIdx.x, lane = tid & 63, wid = tid >> 6;
  const int lm = lane & 15, lg = lane >> 4;
  const int bx = blockIdx.x;
  const int gcol0 = bx * 32;

  // stage whh rows once (4096 cells of 16B), swizzled source -> linear LDS
  for (int q = tid; q < 4096; q += 128) {
    const int r = q >> 7, cc = q & 127;
    gload16(whh + (size_t)(gcol0 + r) * 1024 + (size_t)(cc ^ (r & 7)) * 8,
            (char*)wlds + (q & ~63) * 16);
  }

  float c_reg = 0.f;
  const int m_u = lane & 7, u_u = lane >> 3;
  const int rloc = wid * 16 + lm, swb = rloc & 7, swa = lm & 7;
  const u16* wl = wlds + rloc * 1024;
  const u16* hl = hlds + swa * 1024;

  for (int t = 0; t < Tdim; t++) {
    const u16* hsrc = hpad + (t & 1) * 8192;
    u16* hdst = hpad + ((t + 1) & 1) * 8192;
    // copy h(t-1) -> LDS (8 rows x 128 cells), swizzled source
    for (int q = tid; q < 1024; q += 128) {
      const int r = q >> 7, cc = q & 127;
      gload16(hsrc + (size_t)r * 1024 + (size_t)(cc ^ r) * 8,
              (char*)hlds + (q & ~63) * 16);
    }
    __syncthreads();

    f32x4 acc;
#pragma unroll
    for (int j = 0; j < 4; j++) {
      const int m = lg * 4 + j;
      acc[j] = (m < 8) ? bf2f(xpre[(size_t)(m * Tdim + t) * 4096 + gcol0 + wid * 16 + lm]) : 0.f;
    }
#pragma unroll 4
    for (int kk = 0; kk < 32; kk++) {
      const int c0 = kk * 4 + (lg >> 1);
      const int sub = (lg & 1) * 4;
      Frag a, b;
      a.h[0] = *(const short4v*)(hl + ((c0 ^ swa) << 3) + sub);
      a.h[1] = *(const short4v*)(hl + (((c0 + 2) ^ swa) << 3) + sub);
      b.h[0] = *(const short4v*)(wl + ((c0 ^ swb) << 3) + sub);
      b.h[1] = *(const short4v*)(wl + (((c0 + 2) ^ swb) << 3) + sub);
      acc = __builtin_amdgcn_mfma_f32_16x16x32_bf16(a.v, b.v, acc, 0, 0, 0);
    }
#pragma unroll
    for (int j = 0; j < 4; j++) {
      const int m = lg * 4 + j;
      if (m < 8) g_lds[wid][m][lm] = acc[j];
    }
    __syncthreads();
    if (lane < 32) {
      const float gi = g_lds[wid][m_u][u_u * 4 + 0];
      const float gf = g_lds[wid][m_u][u_u * 4 + 1];
      const float gg = g_lds[wid][m_u][u_u * 4 + 2];
      const float go = g_lds[wid][m_u][u_u * 4 + 3];
      const float si = 1.f / (1.f + __expf(-gi));
      const float sf = 1.f / (1.f + __expf(-gf));
      const float so = 1.f / (1.f + __expf(-go));
      const float cn = sf * c_reg + si * tanhf(gg);
      c_reg = cn;
      const float hn = so * tanhf(cn);
      const int hj = bx * 8 + wid * 4 + u_u;
      const u16 hb = f2b(hn);
      hdst[(size_t)m_u * 1024 + hj] = hb;
      cat[(size_t)(m_u * Tdim + t) * 2048 + hj] = hb;
    }
    __threadfence();
    gridbar(bar, bar + 32);
  }
}

// ---------------- small kernels
__global__ __launch_bounds__(256) void conv_whh_perm(const float* __restrict__ w, u16* __restrict__ o){
  const int n = blockIdx.x;
  const int p = (n & 3) * Hdim + (n >> 2);
  const int k0 = threadIdx.x * 4;
  const float4 v = *(const float4*)(w + (size_t)p * Hdim + k0);
  u16* op = o + (size_t)n * Hdim + k0;
  op[0] = f2b(v.x); op[1] = f2b(v.y); op[2] = f2b(v.z); op[3] = f2b(v.w);
}
__global__ __launch_bounds__(256) void bias_fold_k(const float* __restrict__ bi, const float* __restrict__ bh, float* __restrict__ o){
  const int n = blockIdx.x * 256 + threadIdx.x;
  const int p = (n & 3) * Hdim + (n >> 2);
  o[n] = bi[p] + bh[p];
}
__global__ __launch_bounds__(256) void embed_k(const int* __restrict__ ids, const float* __restrict__ tok,
                                               const float* __restrict__ pos, u16* __restrict__ x){
  const int row = blockIdx.x;
  const int t = row & (Tdim - 1);
  const int id = ids[row];
  const int h0 = threadIdx.x * 4;
  const float4 a = *(const float4*)(tok + (size_t)id * Hdim + h0);
  const float4 p = *(const float4*)(pos + (size_t)t * Hdim + h0);
  u16* op = x + (size_t)row * Hdim + h0;
  op[0] = f2b(a.x + p.x); op[1] = f2b(a.y + p.y); op[2] = f2b(a.z + p.z); op[3] = f2b(a.w + p.w);
}
__global__ __launch_bounds__(256) void cvt_bf16_k(const float* __restrict__ in, u16* __restrict__ out){
  const size_t i = ((size_t)blockIdx.x * 256 + threadIdx.x) * 4;
  const float4 v = *(const float4*)(in + i);
  out[i] = f2b(v.x); out[i+1] = f2b(v.y); out[i+2] = f2b(v.z); out[i+3] = f2b(v.w);
}
__global__ __launch_bounds__(256) void init_hc_k(u16* __restrict__ hpad, int* __restrict__ bar){
  const int i = blockIdx.x * 256 + threadIdx.x;
  if (i < 16384) hpad[i] = 0;
  if (i < 64) bar[i] = 0;
}
__global__ __launch_bounds__(256) void ln_rows(const float* __restrict__ in, u16* __restrict__ out,
                                               const float* __restrict__ g, const float* __restrict__ be){
  const int row = blockIdx.x, tid = threadIdx.x;
  const int lane = tid & 63, wid = tid >> 6;
  const float4 x = *(const float4*)(in + (size_t)row * Hdim + tid * 4);
  float s = x.x + x.y + x.z + x.w;
  float q = x.x * x.x + x.y * x.y + x.z * x.z + x.w * x.w;
  for (int o = 32; o; o >>= 1) { s += __shfl_down(s, o, 64); q += __shfl_down(q, o, 64); }
  __shared__ float sm[8];
  if (lane == 0) { sm[wid] = s; sm[4 + wid] = q; }
  __syncthreads();
  const float ts = sm[0] + sm[1] + sm[2] + sm[3];
  const float tq = sm[4] + sm[5] + sm[6] + sm[7];
  const float mean = ts * (1.f / Hdim);
  const float var  = tq * (1.f / Hdim) - mean * mean;
  const float r = rsqrtf(var + 1e-5f);
  const int h0 = tid * 4;
  const float4 gv = *(const float4*)(g + h0);
  const float4 bv = *(const float4*)(be + h0);
  u16* op = out + (size_t)row * Hdim + h0;
  op[0] = f2b((x.x - mean) * r * gv.x + bv.x);
  op[1] = f2b((x.y - mean) * r * gv.y + bv.y);
  op[2] = f2b((x.z - mean) * r * gv.z + bv.z);
  op[3] = f2b((x.w - mean) * r * gv.w + bv.w);
}
__global__ __launch_bounds__(256) void softmax_k(const float* __restrict__ sc, const void* __restrict__ am,
                                                 const int* __restrict__ mflag, u16* __restrict__ w){
  const int row = blockIdx.x, tid = threadIdx.x;
  const int lane = tid & 63, wid = tid >> 6;
  const int b = row >> 7;
  const int bflag = *mflag;
  const float v = sc[(size_t)row * Sdim + tid];
  const bool mk = mask_at(am, (size_t)b * Sdim + tid, bflag);
  const float vm = mk ? v : -10000.0f;
  float mx = vm;
  for (int o = 32; o; o >>= 1) mx = fmaxf(mx, __shfl_down(mx, o, 64));
  __shared__ float sm[8];
  if (lane == 0) sm[wid] = mx;
  __syncthreads();
  mx = fmaxf(fmaxf(sm[0], sm[1]), fmaxf(sm[2], sm[3]));
  const float ex = mk ? expf(vm - mx) : 0.f;
  float ss = ex;
  for (int o = 32; o; o >>= 1) ss += __shfl_down(ss, o, 64);
  if (lane == 0) sm[4 + wid] = ss;
  __syncthreads();
  const float tot = sm[4] + sm[5] + sm[6] + sm[7];
  w[(size_t)row * Sdim + tid] = f2b(ex / (tot + 1e-6f));
}
__global__ __launch_bounds__(256) void transp_k(const u16* __restrict__ kn, u16* __restrict__ knT){
  __shared__ u16 tile[64][65];
  const int b = blockIdx.z, h0 = blockIdx.x * 64, s0 = blockIdx.y * 64;
  const u16* src = kn  + (size_t)b * Sdim * Hdim;
  u16* dst       = knT + (size_t)b * Hdim * Sdim;
  for (int e = threadIdx.x; e < 4096; e += 256) {
    const int r = e >> 6, c = e & 63;
    tile[r][c] = src[(size_t)(s0 + r) * Hdim + h0 + c];
  }
  __syncthreads();
  for (int e = threadIdx.x; e < 4096; e += 256) {
    const int hr = e >> 6, scc = e & 63;
    dst[(size_t)(h0 + hr) * Sdim + s0 + scc] = tile[scc][hr];
  }
}

extern "C" void kernel_launch(void* const* d_in, const int* in_sizes, int n_in,
                              void* d_out, int out_size, void* d_ws, size_t ws_size,
                              hipStream_t stream) {
  const int*   input_ids = (const int*)d_in[0];
  const float* enc   = (const float*)d_in[1];
  const void*  pmask = d_in[2];
  const void*  amask = d_in[3];
  const float* tok  = (const float*)d_in[4];
  const float* pos  = (const float*)d_in[5];
  const float* w_ih = (const float*)d_in[6];
  const float* w_hh = (const float*)d_in[7];
  const float* b_ih = (const float*)d_in[8];
  const float* b_hh = (const float*)d_in[9];
  const float* wq = (const float*)d_in[10];
  const float* bq = (const float*)d_in[11];
  const float* wk = (const float*)d_in[12];
  const float* bk = (const float*)d_in[13];
  const float* wc = (const float*)d_in[14];
  const float* bc = (const float*)d_in[15];
  const float* wo = (const float*)d_in[16];
  const float* bo = (const float*)d_in[17];
  const float* g1  = (const float*)d_in[18];
  const float* be1 = (const float*)d_in[19];
  const float* g2  = (const float*)d_in[20];
  const float* be2 = (const float*)d_in[21];
  float* out = (float*)d_out;

  char* ws = (char*)d_ws;
  size_t off = 0;
  auto alloc = [&](size_t b){ size_t o = off; off += (b + 255) & ~(size_t)255; return o; };
  u16*   whhb  = (u16*)  (ws + alloc((size_t)4096 * 1024 * 2));
  float* biasf = (float*)(ws + alloc(4096 * 4));
  u16*   xbf   = (u16*)  (ws + alloc((size_t)1024 * 1024 * 2));
  u16*   encb  = (u16*)  (ws + alloc((size_t)2048 * 1024 * 2));
  u16*   xpre  = (u16*)  (ws + alloc((size_t)1024 * 4096 * 2));
  u16*   hpad  = (u16*)  (ws + alloc((size_t)2 * 8192 * 2));
  u16*   cat   = (u16*)  (ws + alloc((size_t)1024 * 2048 * 2));
  float* qlin  = (float*)(ws + alloc((size_t)1024 * 1024 * 4));
  u16*   qn    = (u16*)  (ws + alloc((size_t)1024 * 1024 * 2));
  float* klin  = (float*)(ws + alloc((size_t)2048 * 1024 * 4));
  u16*   kn    = (u16*)  (ws + alloc((size_t)2048 * 1024 * 2));
  u16*   knT   = (u16*)  (ws + alloc((size_t)2048 * 1024 * 2));
  float* scores= (float*)(ws + alloc((size_t)8 * 128 * 256 * 4));
  u16*   attw  = (u16*)  (ws + alloc((size_t)8 * 128 * 256 * 2));
  float* hlin  = (float*)(ws + alloc((size_t)1024 * 1024 * 4));
  u16*   hid   = (u16*)  (ws + alloc((size_t)1024 * 1024 * 2));
  int*   bflag = (int*)  (ws + alloc(256));
  int*   bar   = (int*)  (ws + alloc(256));
  (void)ws_size; (void)in_sizes; (void)n_in; (void)out_size;

  detect_bool_k<<<1, 256, 0, stream>>>((const unsigned char*)pmask, bflag);
  conv_whh_perm<<<4096, 256, 0, stream>>>(w_hh, whhb);
  bias_fold_k<<<16, 256, 0, stream>>>(b_ih, b_hh, biasf);
  embed_k<<<1024, 256, 0, stream>>>(input_ids, tok, pos, xbf);
  cvt_bf16_k<<<2048, 256, 0, stream>>>(enc, encb);
  init_hc_k<<<64, 256, 0, stream>>>(hpad, bar);

  // x_pre = x @ w_ih_perm.T + (b_ih + b_hh)   -> bf16 (1024 x 4096)
  gemm_bt<u16, true, false, true><<<dim3(32, 8, 1), 256, 0, stream>>>(
      xbf, 1024, 0, w_ih, 1024, 0, xpre, 4096, 0, biasf, nullptr, nullptr, 1024, 1.f);

  lstm_persist<<<NBLK, 128, 0, stream>>>(xpre, whhb, hpad, cat, bar);

  // q = lstm_out @ wq.T + bq ; LN(g1,be1)
  gemm_bt<float, true, false, false><<<dim3(8, 8, 1), 256, 0, stream>>>(
      cat, 2048, 0, wq, 1024, 0, qlin, 1024, 0, bq, nullptr, nullptr, 1024, 1.f);
  ln_rows<<<1024, 256, 0, stream>>>(qlin, qn, g1, be1);
  // k = enc @ wk.T + bk ; LN(g1,be1)
  gemm_bt<float, true, false, false><<<dim3(8, 16, 1), 256, 0, stream>>>(
      encb, 1024, 0, wk, 1024, 0, klin, 1024, 0, bk, nullptr, nullptr, 1024, 1.f);
  ln_rows<<<2048, 256, 0, stream>>>(klin, kn, g1, be1);
  transp_k<<<dim3(16, 4, 8), 256, 0, stream>>>(kn, knT);

  // scores = qn @ kn^T * scale   (batched over 8)
  gemm_bt<float, false, false, false><<<dim3(2, 1, 8), 256, 0, stream>>>(
      qn, 1024, 131072, kn, 1024, 262144, scores, 256, 32768, nullptr, nullptr, nullptr, 1024, 0.015625f);
  softmax_k<<<1024, 256, 0, stream>>>(scores, amask, bflag, attw);
  // ctx = w @ kn  -> right half of cat   (batched)
  gemm_bt<u16, false, false, false><<<dim3(8, 1, 8), 256, 0, stream>>>(
      attw, 256, 32768, knT, 256, 262144, cat + 1024, 2048, 262144, nullptr, nullptr, nullptr, 256, 1.f);

  // hidden = LN( cat @ wc.T + bc ; g2,be2 )
  gemm_bt<float, true, false, false><<<dim3(8, 8, 1), 256, 0, stream>>>(
      cat, 2048, 0, wc, 2048, 0, hlin, 1024, 0, bc, nullptr, nullptr, 2048, 1.f);
  ln_rows<<<1024, 256, 0, stream>>>(hlin, hid, g2, be2);

  // logits = hidden @ wo.T + bo, masked
  gemm_bt<float, true, true, false><<<dim3(250, 8, 1), 256, 0, stream>>>(
      hid, 1024, 0, wo, 1024, 0, out, 32000, 0, bo, pmask, bflag, 1024, 1.f);
}

// Round 4
// 1846.022 us; speedup vs baseline: 1.7452x; 1.6879x over previous
//
#include <hip/hip_runtime.h>
#include <cstdint>
#include <cstddef>

#define Bdim 8
#define Tdim 128
#define Sdim 256
#define Hdim 1024
#define Vdim 32000
#define NBLK 128

typedef unsigned short u16;
typedef unsigned long long u64;
typedef __attribute__((ext_vector_type(8))) short short8;
typedef __attribute__((ext_vector_type(4))) short short4v;
typedef __attribute__((ext_vector_type(4))) float f32x4;

union Frag { short8 v; short4v h[2]; };

__device__ __forceinline__ float bf2f(u16 u){
  union { unsigned int i; float f; } x; x.i = ((unsigned int)u) << 16; return x.f;
}
__device__ __forceinline__ u16 f2b(float f){
  union { float f; unsigned int u; } x; x.f = f;
  unsigned int r = x.u + 0x7FFFu + ((x.u >> 16) & 1u);  // RNE
  return (u16)(r >> 16);
}
__device__ __forceinline__ float ftanh(float x){
  x = fminf(10.f, fmaxf(-10.f, x));
  const float e = __expf(2.f * x);
  return (e - 1.f) / (e + 1.f);
}

__device__ __forceinline__ void gload16(const void* g, void* l){
  __builtin_amdgcn_global_load_lds((const __attribute__((address_space(1))) unsigned int*)g,
                                   (__attribute__((address_space(3))) unsigned int*)l, 16, 0, 0);
}

// 16B-cell swizzle for 64B-wide LDS tile rows (4 cells/row)
__device__ __forceinline__ int qsw(int r){ return (r + (r >> 2)) & 3; }

// Bool dtype detector: bool arrays may arrive as int32 or byte-sized.
__global__ __launch_bounds__(256) void detect_bool_k(const unsigned char* __restrict__ p, int* __restrict__ flag){
  __shared__ int s;
  if (threadIdx.x == 0) s = 0;
  __syncthreads();
  int loc = 0;
  for (int i = threadIdx.x; i < 65536; i += 256)
    if ((i & 3) && p[i]) loc = 1;
  if (loc) atomicOr(&s, 1);
  __syncthreads();
  if (threadIdx.x == 0) *flag = s;
}

__device__ __forceinline__ bool mask_at(const void* m, size_t idx, int byteflag){
  if (byteflag) return ((const unsigned char*)m)[idx] != 0;
  return ((const int*)m)[idx] != 0;
}

// ---------------- generic GEMM: C[m][n] = alpha*sum_k A[m][k]*Bt[n][k] + bias[n]
template<typename OutT, bool BF32, bool MASKED, bool PERMB>
__global__ __launch_bounds__(256) void gemm_bt(
    const u16* __restrict__ A, int lda, long sA,
    const void* __restrict__ Bp, int ldb, long sB,
    OutT* __restrict__ C, int ldc, long sC,
    const float* __restrict__ bias,
    const void* __restrict__ mask,
    const int* __restrict__ mflag,
    int K, float alpha)
{
  __shared__ alignas(16) char ldsA[8192];   // 128 x 32 bf16, cell-swizzled
  __shared__ alignas(16) char ldsB[8192];
  const int tid  = threadIdx.x;
  const int lane = tid & 63, wid = tid >> 6;
  const int lm = lane & 15, lg = lane >> 4;
  const int wm = wid >> 1, wn = wid & 1;            // 2x2 waves, 64x64 each
  const int m0 = blockIdx.y * 128, n0 = blockIdx.x * 128;
  const int z  = blockIdx.z;
  const char* Ab = (const char*)(A + (size_t)z * sA);

  f32x4 acc[4][4];
#pragma unroll
  for (int i = 0; i < 4; i++)
#pragma unroll
    for (int j = 0; j < 4; j++) acc[i][j] = (f32x4){0.f, 0.f, 0.f, 0.f};

  const int brow = tid >> 1, bhalf = tid & 1;
  int bsrow = n0 + brow;
  if (PERMB) bsrow = (bsrow & 3) * Hdim + (bsrow >> 2);
  const int qb_st = qsw(brow);

  for (int k0 = 0; k0 < K; k0 += 32) {
    {  // stage A: linear LDS dest, swizzled global source (rule #21)
      const char* ga = Ab + ((size_t)m0 * lda + k0) * 2;
      const int f0 = tid, f1 = tid + 256;
      const int r0 = f0 >> 2, r1 = f1 >> 2;
      gload16(ga + (size_t)r0 * (lda * 2) + ((f0 & 3) ^ qsw(r0)) * 16, ldsA + (f0 & ~63) * 16);
      gload16(ga + (size_t)r1 * (lda * 2) + ((f1 & 3) ^ qsw(r1)) * 16, ldsA + (f1 & ~63) * 16);
    }
    if (BF32) {
      const float* Bf = (const float*)Bp + (size_t)z * sB;
      const float4* src = (const float4*)(Bf + (size_t)bsrow * ldb + k0 + bhalf * 16);
      float4 v0 = src[0], v1 = src[1], v2 = src[2], v3 = src[3];
      union { short8 v; short s[8]; } p0, p1;
      p0.s[0]=(short)f2b(v0.x); p0.s[1]=(short)f2b(v0.y); p0.s[2]=(short)f2b(v0.z); p0.s[3]=(short)f2b(v0.w);
      p0.s[4]=(short)f2b(v1.x); p0.s[5]=(short)f2b(v1.y); p0.s[6]=(short)f2b(v1.z); p0.s[7]=(short)f2b(v1.w);
      p1.s[0]=(short)f2b(v2.x); p1.s[1]=(short)f2b(v2.y); p1.s[2]=(short)f2b(v2.z); p1.s[3]=(short)f2b(v2.w);
      p1.s[4]=(short)f2b(v3.x); p1.s[5]=(short)f2b(v3.y); p1.s[6]=(short)f2b(v3.z); p1.s[7]=(short)f2b(v3.w);
      char* base = ldsB + brow * 64;
      *(short8*)(base + (((bhalf * 2 + 0) ^ qb_st) * 16)) = p0.v;
      *(short8*)(base + (((bhalf * 2 + 1) ^ qb_st) * 16)) = p1.v;
    } else {
      const char* gb = (const char*)Bp + (size_t)z * sB * 2 + ((size_t)n0 * ldb + k0) * 2;
      const int f0 = tid, f1 = tid + 256;
      const int r0 = f0 >> 2, r1 = f1 >> 2;
      gload16(gb + (size_t)r0 * (ldb * 2) + ((f0 & 3) ^ qsw(r0)) * 16, ldsB + (f0 & ~63) * 16);
      gload16(gb + (size_t)r1 * (ldb * 2) + ((f1 & 3) ^ qsw(r1)) * 16, ldsB + (f1 & ~63) * 16);
    }
    __syncthreads();

    Frag a[4], b[4];
#pragma unroll
    for (int mi = 0; mi < 4; mi++) {
      const int rr = wm * 64 + mi * 16 + lm;
      const int q = qsw(rr);
      const char* p = ldsA + rr * 64 + (lg & 1) * 8;
      a[mi].h[0] = *(const short4v*)(p + (((lg >> 1) ^ q) * 16));
      a[mi].h[1] = *(const short4v*)(p + ((((lg >> 1) | 2) ^ q) * 16));
    }
#pragma unroll
    for (int ni = 0; ni < 4; ni++) {
      const int rr = wn * 64 + ni * 16 + lm;
      const int q = qsw(rr);
      const char* p = ldsB + rr * 64 + (lg & 1) * 8;
      b[ni].h[0] = *(const short4v*)(p + (((lg >> 1) ^ q) * 16));
      b[ni].h[1] = *(const short4v*)(p + ((((lg >> 1) | 2) ^ q) * 16));
    }
#pragma unroll
    for (int mi = 0; mi < 4; mi++)
#pragma unroll
      for (int ni = 0; ni < 4; ni++)
        acc[mi][ni] = __builtin_amdgcn_mfma_f32_16x16x32_bf16(a[mi].v, b[ni].v, acc[mi][ni], 0, 0, 0);
    __syncthreads();
  }

  const int bflag = MASKED ? *mflag : 0;
#pragma unroll
  for (int mi = 0; mi < 4; mi++) {
#pragma unroll
    for (int ni = 0; ni < 4; ni++) {
      const int row = m0 + wm * 64 + mi * 16 + lg * 4;
      const int col = n0 + wn * 64 + ni * 16 + lm;
      const float bb = bias ? bias[col] : 0.f;
#pragma unroll
      for (int j = 0; j < 4; j++) {
        float v = acc[mi][ni][j] * alpha + bb;
        if (MASKED) { if (!mask_at(mask, (size_t)(row + j) * ldc + col, bflag)) v = -10000.0f; }
        const size_t o = (size_t)z * sC + (size_t)(row + j) * ldc + col;
        if constexpr (sizeof(OutT) == 2) C[o] = (OutT)f2b(v); else C[o] = (OutT)v;
      }
    }
  }
}

// ---------------- persistent LSTM, dataflow-synced (no fences, no invalidates)
// Block bx owns gate-cols [bx*32, bx*32+32) (8 hidden units). whh slice lives in
// LDS for the whole sequence. h exchanged via write-through (agent-scope relaxed
// atomic) u64 stores/loads at the coherence point; per-(step,block) flags.
__global__ __launch_bounds__(128) void lstm_persist(
    const u16* __restrict__ xpre,   // (b*128+t, 4096) bf16, includes biases
    const u16* __restrict__ whh,    // (4096, 1024) bf16, gate-permuted rows
    u16* __restrict__ hpad,         // 2 x (8 x 1024) bf16 double buffer
    u16* __restrict__ cat,          // (1024, 2048) bf16; h -> left half
    int* __restrict__ flags)        // Tdim x NBLK, zeroed per launch
{
  __shared__ alignas(16) u16 wlds[32 * 1024];  // 64KB, cell c^(r&7) swizzle
  __shared__ alignas(16) u16 hlds[8 * 1024];   // 16KB, cell c^r swizzle
  __shared__ float g_lds[2][8][17];
  __shared__ alignas(16) u16 hout[8][8];
  const int tid = threadIdx.x, lane = tid & 63, wid = tid >> 6;
  const int lm = lane & 15, lg = lane >> 4;
  const int bx = blockIdx.x;
  const int gcol0 = bx * 32;

  // stage whh rows once (4096 cells of 16B), swizzled source -> linear LDS
  for (int q = tid; q < 4096; q += 128) {
    const int r = q >> 7, cc = q & 127;
    gload16(whh + (size_t)(gcol0 + r) * 1024 + (size_t)(cc ^ (r & 7)) * 8,
            (char*)wlds + (q & ~63) * 16);
  }

  float c_reg = 0.f;
  const int m_u = lane & 7, u_u = lane >> 3;
  const int rloc = wid * 16 + lm, swb = rloc & 7, swa = lm & 7;
  const u16* wl = wlds + rloc * 1024;
  const u16* hl = hlds + swa * 1024;
  const int hr = tid >> 4, hc = tid & 15;   // h staging coords (8 rows x 16 base cells)

  for (int t = 0; t < Tdim; t++) {
    if (t > 0 && tid < NBLK) {
      int* fl = flags + (t - 1) * NBLK + tid;
      while (__hip_atomic_load(fl, __ATOMIC_RELAXED, __HIP_MEMORY_SCOPE_AGENT) == 0)
        __builtin_amdgcn_s_sleep(1);
    }
    __syncthreads();   // S1: flags observed; prev-step LDS reads all done

    {  // h(t) -> LDS via coherence-point loads + swizzled ds_write
      u64* hs = (u64*)(hpad + (size_t)(t & 1) * 8192) + hr * 256;
#pragma unroll
      for (int i = 0; i < 8; i++) {
        const int c = hc + i * 16;
        const u64 v0 = __hip_atomic_load(hs + c * 2,     __ATOMIC_RELAXED, __HIP_MEMORY_SCOPE_AGENT);
        const u64 v1 = __hip_atomic_load(hs + c * 2 + 1, __ATOMIC_RELAXED, __HIP_MEMORY_SCOPE_AGENT);
        const int cs = c ^ hr;
        *(u64*)((char*)hlds + hr * 2048 + cs * 16)     = v0;
        *(u64*)((char*)hlds + hr * 2048 + cs * 16 + 8) = v1;
      }
    }
    f32x4 acc;
#pragma unroll
    for (int j = 0; j < 4; j++) {
      const int m = lg * 4 + j;
      acc[j] = (m < 8) ? bf2f(xpre[(size_t)(m * Tdim + t) * 4096 + gcol0 + wid * 16 + lm]) : 0.f;
    }
    __syncthreads();   // S2: hlds ready (waitcnt drains atomics + ds_writes)

#pragma unroll 4
    for (int kk = 0; kk < 32; kk++) {
      const int c0 = kk * 4 + (lg >> 1);
      const int sub = (lg & 1) * 4;
      Frag a, b;
      a.h[0] = *(const short4v*)(hl + ((c0 ^ swa) << 3) + sub);
      a.h[1] = *(const short4v*)(hl + (((c0 + 2) ^ swa) << 3) + sub);
      b.h[0] = *(const short4v*)(wl + ((c0 ^ swb) << 3) + sub);
      b.h[1] = *(const short4v*)(wl + (((c0 + 2) ^ swb) << 3) + sub);
      acc = __builtin_amdgcn_mfma_f32_16x16x32_bf16(a.v, b.v, acc, 0, 0, 0);
    }
#pragma unroll
    for (int j = 0; j < 4; j++) {
      const int m = lg * 4 + j;
      if (m < 8) g_lds[wid][m][lm] = acc[j];
    }
    __syncthreads();   // S3: gates ready
    if (lane < 32) {
      const float gi = g_lds[wid][m_u][u_u * 4 + 0];
      const float gf = g_lds[wid][m_u][u_u * 4 + 1];
      const float gg = g_lds[wid][m_u][u_u * 4 + 2];
      const float go = g_lds[wid][m_u][u_u * 4 + 3];
      const float si = 1.f / (1.f + __expf(-gi));
      const float sf = 1.f / (1.f + __expf(-gf));
      const float so = 1.f / (1.f + __expf(-go));
      const float cn = sf * c_reg + si * ftanh(gg);
      c_reg = cn;
      const float hn = so * ftanh(cn);
      const int u8 = wid * 4 + u_u;            // unit 0..7 within block
      const u16 hb = f2b(hn);
      hout[m_u][u8] = hb;
      cat[(size_t)(m_u * Tdim + t) * 2048 + gcol0 / 4 + u8] = hb;
    }
    __syncthreads();   // S4: hout ready
    if (tid < 8) {
      const u64 w0 = *(const u64*)&hout[tid][0];
      const u64 w1 = *(const u64*)&hout[tid][4];
      char* hd = (char*)hpad + (size_t)((t + 1) & 1) * 16384 + (size_t)tid * 2048 + (size_t)bx * 16;
      __hip_atomic_store((u64*)hd,       w0, __ATOMIC_RELAXED, __HIP_MEMORY_SCOPE_AGENT);
      __hip_atomic_store((u64*)(hd + 8), w1, __ATOMIC_RELAXED, __HIP_MEMORY_SCOPE_AGENT);
    }
    asm volatile("s_waitcnt vmcnt(0)" ::: "memory");  // wave0: h stores at coherence point
    if (tid == 0)
      __hip_atomic_store(flags + t * NBLK + bx, 1, __ATOMIC_RELAXED, __HIP_MEMORY_SCOPE_AGENT);
  }
}

// ---------------- small kernels
__global__ __launch_bounds__(256) void conv_whh_perm(const float* __restrict__ w, u16* __restrict__ o){
  const int n = blockIdx.x;
  const int p = (n & 3) * Hdim + (n >> 2);
  const int k0 = threadIdx.x * 4;
  const float4 v = *(const float4*)(w + (size_t)p * Hdim + k0);
  u16* op = o + (size_t)n * Hdim + k0;
  op[0] = f2b(v.x); op[1] = f2b(v.y); op[2] = f2b(v.z); op[3] = f2b(v.w);
}
__global__ __launch_bounds__(256) void bias_fold_k(const float* __restrict__ bi, const float* __restrict__ bh, float* __restrict__ o){
  const int n = blockIdx.x * 256 + threadIdx.x;
  const int p = (n & 3) * Hdim + (n >> 2);
  o[n] = bi[p] + bh[p];
}
__global__ __launch_bounds__(256) void embed_k(const int* __restrict__ ids, const float* __restrict__ tok,
                                               const float* __restrict__ pos, u16* __restrict__ x){
  const int row = blockIdx.x;
  const int t = row & (Tdim - 1);
  const int id = ids[row];
  const int h0 = threadIdx.x * 4;
  const float4 a = *(const float4*)(tok + (size_t)id * Hdim + h0);
  const float4 p = *(const float4*)(pos + (size_t)t * Hdim + h0);
  u16* op = x + (size_t)row * Hdim + h0;
  op[0] = f2b(a.x + p.x); op[1] = f2b(a.y + p.y); op[2] = f2b(a.z + p.z); op[3] = f2b(a.w + p.w);
}
__global__ __launch_bounds__(256) void cvt_bf16_k(const float* __restrict__ in, u16* __restrict__ out){
  const size_t i = ((size_t)blockIdx.x * 256 + threadIdx.x) * 4;
  const float4 v = *(const float4*)(in + i);
  out[i] = f2b(v.x); out[i+1] = f2b(v.y); out[i+2] = f2b(v.z); out[i+3] = f2b(v.w);
}
__global__ __launch_bounds__(256) void init_hc_k(u16* __restrict__ hpad, int* __restrict__ flags){
  const int i = blockIdx.x * 256 + threadIdx.x;
  if (i < 16384) { hpad[i] = 0; flags[i] = 0; }
}
__global__ __launch_bounds__(256) void ln_rows(const float* __restrict__ in, u16* __restrict__ out,
                                               const float* __restrict__ g, const float* __restrict__ be){
  const int row = blockIdx.x, tid = threadIdx.x;
  const int lane = tid & 63, wid = tid >> 6;
  const float4 x = *(const float4*)(in + (size_t)row * Hdim + tid * 4);
  float s = x.x + x.y + x.z + x.w;
  float q = x.x * x.x + x.y * x.y + x.z * x.z + x.w * x.w;
  for (int o = 32; o; o >>= 1) { s += __shfl_down(s, o, 64); q += __shfl_down(q, o, 64); }
  __shared__ float sm[8];
  if (lane == 0) { sm[wid] = s; sm[4 + wid] = q; }
  __syncthreads();
  const float ts = sm[0] + sm[1] + sm[2] + sm[3];
  const float tq = sm[4] + sm[5] + sm[6] + sm[7];
  const float mean = ts * (1.f / Hdim);
  const float var  = tq * (1.f / Hdim) - mean * mean;
  const float r = rsqrtf(var + 1e-5f);
  const int h0 = tid * 4;
  const float4 gv = *(const float4*)(g + h0);
  const float4 bv = *(const float4*)(be + h0);
  u16* op = out + (size_t)row * Hdim + h0;
  op[0] = f2b((x.x - mean) * r * gv.x + bv.x);
  op[1] = f2b((x.y - mean) * r * gv.y + bv.y);
  op[2] = f2b((x.z - mean) * r * gv.z + bv.z);
  op[3] = f2b((x.w - mean) * r * gv.w + bv.w);
}
__global__ __launch_bounds__(256) void softmax_k(const float* __restrict__ sc, const void* __restrict__ am,
                                                 const int* __restrict__ mflag, u16* __restrict__ w){
  const int row = blockIdx.x, tid = threadIdx.x;
  const int lane = tid & 63, wid = tid >> 6;
  const int b = row >> 7;
  const int bflag = *mflag;
  const float v = sc[(size_t)row * Sdim + tid];
  const bool mk = mask_at(am, (size_t)b * Sdim + tid, bflag);
  const float vm = mk ? v : -10000.0f;
  float mx = vm;
  for (int o = 32; o; o >>= 1) mx = fmaxf(mx, __shfl_down(mx, o, 64));
  __shared__ float sm[8];
  if (lane == 0) sm[wid] = mx;
  __syncthreads();
  mx = fmaxf(fmaxf(sm[0], sm[1]), fmaxf(sm[2], sm[3]));
  const float ex = mk ? expf(vm - mx) : 0.f;
  float ss = ex;
  for (int o = 32; o; o >>= 1) ss += __shfl_down(ss, o, 64);
  if (lane == 0) sm[4 + wid] = ss;
  __syncthreads();
  const float tot = sm[4] + sm[5] + sm[6] + sm[7];
  w[(size_t)row * Sdim + tid] = f2b(ex / (tot + 1e-6f));
}
__global__ __launch_bounds__(256) void transp_k(const u16* __restrict__ kn, u16* __restrict__ knT){
  __shared__ u16 tile[64][65];
  const int b = blockIdx.z, h0 = blockIdx.x * 64, s0 = blockIdx.y * 64;
  const u16* src = kn  + (size_t)b * Sdim * Hdim;
  u16* dst       = knT + (size_t)b * Hdim * Sdim;
  for (int e = threadIdx.x; e < 4096; e += 256) {
    const int r = e >> 6, c = e & 63;
    tile[r][c] = src[(size_t)(s0 + r) * Hdim + h0 + c];
  }
  __syncthreads();
  for (int e = threadIdx.x; e < 4096; e += 256) {
    const int hr = e >> 6, scc = e & 63;
    dst[(size_t)(h0 + hr) * Sdim + s0 + scc] = tile[scc][hr];
  }
}

extern "C" void kernel_launch(void* const* d_in, const int* in_sizes, int n_in,
                              void* d_out, int out_size, void* d_ws, size_t ws_size,
                              hipStream_t stream) {
  const int*   input_ids = (const int*)d_in[0];
  const float* enc   = (const float*)d_in[1];
  const void*  pmask = d_in[2];
  const void*  amask = d_in[3];
  const float* tok  = (const float*)d_in[4];
  const float* pos  = (const float*)d_in[5];
  const float* w_ih = (const float*)d_in[6];
  const float* w_hh = (const float*)d_in[7];
  const float* b_ih = (const float*)d_in[8];
  const float* b_hh = (const float*)d_in[9];
  const float* wq = (const float*)d_in[10];
  const float* bq = (const float*)d_in[11];
  const float* wk = (const float*)d_in[12];
  const float* bk = (const float*)d_in[13];
  const float* wc = (const float*)d_in[14];
  const float* bc = (const float*)d_in[15];
  const float* wo = (const float*)d_in[16];
  const float* bo = (const float*)d_in[17];
  const float* g1  = (const float*)d_in[18];
  const float* be1 = (const float*)d_in[19];
  const float* g2  = (const float*)d_in[20];
  const float* be2 = (const float*)d_in[21];
  float* out = (float*)d_out;

  char* ws = (char*)d_ws;
  size_t off = 0;
  auto alloc = [&](size_t b){ size_t o = off; off += (b + 255) & ~(size_t)255; return o; };
  u16*   whhb  = (u16*)  (ws + alloc((size_t)4096 * 1024 * 2));
  float* biasf = (float*)(ws + alloc(4096 * 4));
  u16*   xbf   = (u16*)  (ws + alloc((size_t)1024 * 1024 * 2));
  u16*   encb  = (u16*)  (ws + alloc((size_t)2048 * 1024 * 2));
  u16*   xpre  = (u16*)  (ws + alloc((size_t)1024 * 4096 * 2));
  u16*   hpad  = (u16*)  (ws + alloc((size_t)2 * 8192 * 2));
  u16*   cat   = (u16*)  (ws + alloc((size_t)1024 * 2048 * 2));
  float* qlin  = (float*)(ws + alloc((size_t)1024 * 1024 * 4));
  u16*   qn    = (u16*)  (ws + alloc((size_t)1024 * 1024 * 2));
  float* klin  = (float*)(ws + alloc((size_t)2048 * 1024 * 4));
  u16*   kn    = (u16*)  (ws + alloc((size_t)2048 * 1024 * 2));
  u16*   knT   = (u16*)  (ws + alloc((size_t)2048 * 1024 * 2));
  float* scores= (float*)(ws + alloc((size_t)8 * 128 * 256 * 4));
  u16*   attw  = (u16*)  (ws + alloc((size_t)8 * 128 * 256 * 2));
  float* hlin  = (float*)(ws + alloc((size_t)1024 * 1024 * 4));
  u16*   hid   = (u16*)  (ws + alloc((size_t)1024 * 1024 * 2));
  int*   bflag = (int*)  (ws + alloc(256));
  int*   flags = (int*)  (ws + alloc((size_t)Tdim * NBLK * 4));
  (void)ws_size; (void)in_sizes; (void)n_in; (void)out_size;

  detect_bool_k<<<1, 256, 0, stream>>>((const unsigned char*)pmask, bflag);
  conv_whh_perm<<<4096, 256, 0, stream>>>(w_hh, whhb);
  bias_fold_k<<<16, 256, 0, stream>>>(b_ih, b_hh, biasf);
  embed_k<<<1024, 256, 0, stream>>>(input_ids, tok, pos, xbf);
  cvt_bf16_k<<<2048, 256, 0, stream>>>(enc, encb);
  init_hc_k<<<64, 256, 0, stream>>>(hpad, flags);

  // x_pre = x @ w_ih_perm.T + (b_ih + b_hh)   -> bf16 (1024 x 4096)
  gemm_bt<u16, true, false, true><<<dim3(32, 8, 1), 256, 0, stream>>>(
      xbf, 1024, 0, w_ih, 1024, 0, xpre, 4096, 0, biasf, nullptr, nullptr, 1024, 1.f);

  lstm_persist<<<NBLK, 128, 0, stream>>>(xpre, whhb, hpad, cat, flags);

  // q = lstm_out @ wq.T + bq ; LN(g1,be1)
  gemm_bt<float, true, false, false><<<dim3(8, 8, 1), 256, 0, stream>>>(
      cat, 2048, 0, wq, 1024, 0, qlin, 1024, 0, bq, nullptr, nullptr, 1024, 1.f);
  ln_rows<<<1024, 256, 0, stream>>>(qlin, qn, g1, be1);
  // k = enc @ wk.T + bk ; LN(g1,be1)
  gemm_bt<float, true, false, false><<<dim3(8, 16, 1), 256, 0, stream>>>(
      encb, 1024, 0, wk, 1024, 0, klin, 1024, 0, bk, nullptr, nullptr, 1024, 1.f);
  ln_rows<<<2048, 256, 0, stream>>>(klin, kn, g1, be1);
  transp_k<<<dim3(16, 4, 8), 256, 0, stream>>>(kn, knT);

  // scores = qn @ kn^T * scale   (batched over 8)
  gemm_bt<float, false, false, false><<<dim3(2, 1, 8), 256, 0, stream>>>(
      qn, 1024, 131072, kn, 1024, 262144, scores, 256, 32768, nullptr, nullptr, nullptr, 1024, 0.015625f);
  softmax_k<<<1024, 256, 0, stream>>>(scores, amask, bflag, attw);
  // ctx = w @ kn  -> right half of cat   (batched)
  gemm_bt<u16, false, false, false><<<dim3(8, 1, 8), 256, 0, stream>>>(
      attw, 256, 32768, knT, 256, 262144, cat + 1024, 2048, 262144, nullptr, nullptr, nullptr, 256, 1.f);

  // hidden = LN( cat @ wc.T + bc ; g2,be2 )
  gemm_bt<float, true, false, false><<<dim3(8, 8, 1), 256, 0, stream>>>(
      cat, 2048, 0, wc, 2048, 0, hlin, 1024, 0, bc, nullptr, nullptr, 2048, 1.f);
  ln_rows<<<1024, 256, 0, stream>>>(hlin, hid, g2, be2);

  // logits = hidden @ wo.T + bo, masked
  gemm_bt<float, true, true, false><<<dim3(250, 8, 1), 256, 0, stream>>>(
      hid, 1024, 0, wo, 1024, 0, out, 32000, 0, bo, pmask, bflag, 1024, 1.f);
}

// Round 5
// 1535.925 us; speedup vs baseline: 2.0976x; 1.2019x over previous
//
#include <hip/hip_runtime.h>
#include <cstdint>
#include <cstddef>

#define Bdim 8
#define Tdim 128
#define Sdim 256
#define Hdim 1024
#define Vdim 32000
#define NBLK 64

typedef unsigned short u16;
typedef unsigned long long u64;
typedef __attribute__((ext_vector_type(8))) short short8;
typedef __attribute__((ext_vector_type(4))) short short4v;
typedef __attribute__((ext_vector_type(4))) float f32x4;
typedef __attribute__((ext_vector_type(2))) unsigned long long u64x2;

union Frag { short8 v; short4v h[2]; };

__device__ __forceinline__ float bf2f(u16 u){
  union { unsigned int i; float f; } x; x.i = ((unsigned int)u) << 16; return x.f;
}
__device__ __forceinline__ u16 f2b(float f){
  union { float f; unsigned int u; } x; x.f = f;
  unsigned int r = x.u + 0x7FFFu + ((x.u >> 16) & 1u);  // RNE
  return (u16)(r >> 16);
}
__device__ __forceinline__ float ftanh(float x){
  x = fminf(10.f, fmaxf(-10.f, x));
  const float e = __expf(2.f * x);
  return (e - 1.f) / (e + 1.f);
}

__device__ __forceinline__ void gload16(const void* g, void* l){
  __builtin_amdgcn_global_load_lds((const __attribute__((address_space(1))) unsigned int*)g,
                                   (__attribute__((address_space(3))) unsigned int*)l, 16, 0, 0);
}

// 16B-cell swizzle for 64B-wide LDS tile rows (4 cells/row)
__device__ __forceinline__ int qsw(int r){ return (r + (r >> 2)) & 3; }

// Bool dtype detector: bool arrays may arrive as int32 or byte-sized.
__global__ __launch_bounds__(256) void detect_bool_k(const unsigned char* __restrict__ p, int* __restrict__ flag){
  __shared__ int s;
  if (threadIdx.x == 0) s = 0;
  __syncthreads();
  int loc = 0;
  for (int i = threadIdx.x; i < 65536; i += 256)
    if ((i & 3) && p[i]) loc = 1;
  if (loc) atomicOr(&s, 1);
  __syncthreads();
  if (threadIdx.x == 0) { flag[0] = s; flag[1] = 1; }
}

__device__ __forceinline__ bool mask_at(const void* m, size_t idx, int byteflag){
  if (byteflag) return ((const unsigned char*)m)[idx] != 0;
  return ((const int*)m)[idx] != 0;
}

__global__ __launch_bounds__(256) void pack_mask_k(const void* __restrict__ pm, const int* __restrict__ bflag,
                                                   unsigned char* __restrict__ o){
  const size_t i = (size_t)blockIdx.x * 256 + threadIdx.x;
  o[i] = mask_at(pm, i, *bflag) ? 1 : 0;
}

// ---------------- generic GEMM: C[m][n] = alpha*sum_k A[m][k]*Bt[n][k] + bias[n]
template<typename OutT, bool BF32, bool MASKED, bool PERMB>
__global__ __launch_bounds__(256) void gemm_bt(
    const u16* __restrict__ A, int lda, long sA,
    const void* __restrict__ Bp, int ldb, long sB,
    OutT* __restrict__ C, int ldc, long sC,
    const float* __restrict__ bias,
    const void* __restrict__ mask,
    const int* __restrict__ mflag,
    int K, float alpha)
{
  __shared__ alignas(16) char ldsA[8192];   // 128 x 32 bf16, cell-swizzled
  __shared__ alignas(16) char ldsB[8192];
  const int tid  = threadIdx.x;
  const int lane = tid & 63, wid = tid >> 6;
  const int lm = lane & 15, lg = lane >> 4;
  const int wm = wid >> 1, wn = wid & 1;            // 2x2 waves, 64x64 each
  const int m0 = blockIdx.y * 128, n0 = blockIdx.x * 128;
  const int z  = blockIdx.z;
  const char* Ab = (const char*)(A + (size_t)z * sA);

  f32x4 acc[4][4];
#pragma unroll
  for (int i = 0; i < 4; i++)
#pragma unroll
    for (int j = 0; j < 4; j++) acc[i][j] = (f32x4){0.f, 0.f, 0.f, 0.f};

  const int brow = tid >> 1, bhalf = tid & 1;
  int bsrow = n0 + brow;
  if (PERMB) bsrow = (bsrow & 3) * Hdim + (bsrow >> 2);
  const int qb_st = qsw(brow);

  for (int k0 = 0; k0 < K; k0 += 32) {
    {  // stage A: linear LDS dest, swizzled global source (rule #21)
      const char* ga = Ab + ((size_t)m0 * lda + k0) * 2;
      const int f0 = tid, f1 = tid + 256;
      const int r0 = f0 >> 2, r1 = f1 >> 2;
      gload16(ga + (size_t)r0 * (lda * 2) + ((f0 & 3) ^ qsw(r0)) * 16, ldsA + (f0 & ~63) * 16);
      gload16(ga + (size_t)r1 * (lda * 2) + ((f1 & 3) ^ qsw(r1)) * 16, ldsA + (f1 & ~63) * 16);
    }
    if (BF32) {
      const float* Bf = (const float*)Bp + (size_t)z * sB;
      const float4* src = (const float4*)(Bf + (size_t)bsrow * ldb + k0 + bhalf * 16);
      float4 v0 = src[0], v1 = src[1], v2 = src[2], v3 = src[3];
      union { short8 v; short s[8]; } p0, p1;
      p0.s[0]=(short)f2b(v0.x); p0.s[1]=(short)f2b(v0.y); p0.s[2]=(short)f2b(v0.z); p0.s[3]=(short)f2b(v0.w);
      p0.s[4]=(short)f2b(v1.x); p0.s[5]=(short)f2b(v1.y); p0.s[6]=(short)f2b(v1.z); p0.s[7]=(short)f2b(v1.w);
      p1.s[0]=(short)f2b(v2.x); p1.s[1]=(short)f2b(v2.y); p1.s[2]=(short)f2b(v2.z); p1.s[3]=(short)f2b(v2.w);
      p1.s[4]=(short)f2b(v3.x); p1.s[5]=(short)f2b(v3.y); p1.s[6]=(short)f2b(v3.z); p1.s[7]=(short)f2b(v3.w);
      char* base = ldsB + brow * 64;
      *(short8*)(base + (((bhalf * 2 + 0) ^ qb_st) * 16)) = p0.v;
      *(short8*)(base + (((bhalf * 2 + 1) ^ qb_st) * 16)) = p1.v;
    } else {
      const char* gb = (const char*)Bp + (size_t)z * sB * 2 + ((size_t)n0 * ldb + k0) * 2;
      const int f0 = tid, f1 = tid + 256;
      const int r0 = f0 >> 2, r1 = f1 >> 2;
      gload16(gb + (size_t)r0 * (ldb * 2) + ((f0 & 3) ^ qsw(r0)) * 16, ldsB + (f0 & ~63) * 16);
      gload16(gb + (size_t)r1 * (ldb * 2) + ((f1 & 3) ^ qsw(r1)) * 16, ldsB + (f1 & ~63) * 16);
    }
    __syncthreads();

    Frag a[4], b[4];
#pragma unroll
    for (int mi = 0; mi < 4; mi++) {
      const int rr = wm * 64 + mi * 16 + lm;
      const int q = qsw(rr);
      const char* p = ldsA + rr * 64 + (lg & 1) * 8;
      a[mi].h[0] = *(const short4v*)(p + (((lg >> 1) ^ q) * 16));
      a[mi].h[1] = *(const short4v*)(p + ((((lg >> 1) | 2) ^ q) * 16));
    }
#pragma unroll
    for (int ni = 0; ni < 4; ni++) {
      const int rr = wn * 64 + ni * 16 + lm;
      const int q = qsw(rr);
      const char* p = ldsB + rr * 64 + (lg & 1) * 8;
      b[ni].h[0] = *(const short4v*)(p + (((lg >> 1) ^ q) * 16));
      b[ni].h[1] = *(const short4v*)(p + ((((lg >> 1) | 2) ^ q) * 16));
    }
#pragma unroll
    for (int mi = 0; mi < 4; mi++)
#pragma unroll
      for (int ni = 0; ni < 4; ni++)
        acc[mi][ni] = __builtin_amdgcn_mfma_f32_16x16x32_bf16(a[mi].v, b[ni].v, acc[mi][ni], 0, 0, 0);
    __syncthreads();
  }

  const int bflag = MASKED ? *mflag : 0;
#pragma unroll
  for (int mi = 0; mi < 4; mi++) {
#pragma unroll
    for (int ni = 0; ni < 4; ni++) {
      const int row = m0 + wm * 64 + mi * 16 + lg * 4;
      const int col = n0 + wn * 64 + ni * 16 + lm;
      const float bb = bias ? bias[col] : 0.f;
#pragma unroll
      for (int j = 0; j < 4; j++) {
        float v = acc[mi][ni][j] * alpha + bb;
        if (MASKED) { if (!mask_at(mask, (size_t)(row + j) * ldc + col, bflag)) v = -10000.0f; }
        const size_t o = (size_t)z * sC + (size_t)(row + j) * ldc + col;
        if constexpr (sizeof(OutT) == 2) C[o] = (OutT)f2b(v); else C[o] = (OutT)v;
      }
    }
  }
}

// ---------------- persistent LSTM, packetized dataflow sync
// 64 blocks x 256 thr. Block bx owns gate-cols [bx*64, bx*64+64) = 16 units.
// whh slice (128KB) lives in LDS. Per step each block emits one 256B packet
// (its 16 units x 8 batches) + a flag on a private cacheline; readers copy
// packets chunk-wise as their flags land.
__global__ __launch_bounds__(256) void lstm_df(
    const u16* __restrict__ xpre,   // (b*128+t, 4096) bf16, includes biases
    const u16* __restrict__ whh,    // (4096, 1024) bf16, gate-permuted rows
    u16* __restrict__ hbuf,         // Tdim x 64 x 128 u16 packets [m][u] layout
    u16* __restrict__ cat,          // (1024, 2048) bf16; h -> left half
    int* __restrict__ flags)        // Tdim x 64 x 16 ints (64B stride), zeroed
{
  __shared__ alignas(16) u16 wlds[64 * 1024];  // 128KB, cell c^(r&7) swizzle
  __shared__ alignas(16) u16 hlds[8 * 1024];   // 16KB,  cell c^m swizzle
  __shared__ float g_lds[4][8][17];
  __shared__ alignas(16) u16 hout[8][16];
  const int tid = threadIdx.x, lane = tid & 63, wid = tid >> 6;
  const int lm = lane & 15, lg = lane >> 4;
  const int bx = blockIdx.x;
  const int gcol0 = bx * 64;

  // stage whh slice once: 8192 cells of 16B, swizzled source -> linear LDS
  for (int q = tid; q < 8192; q += 256) {
    const int r = q >> 7, cc = q & 127;
    gload16(whh + (size_t)(gcol0 + r) * 1024 + (size_t)(cc ^ (r & 7)) * 8,
            (char*)wlds + (q & ~63) * 16);
  }

  float c_reg = 0.f;
  const int m_u = lane & 7, u_u = lane >> 3;        // epilogue coords (lane<32)
  const int rloc = wid * 16 + lm, swb = rloc & 7, swa = lm & 7;
  const u16* wl = wlds + rloc * 1024;
  const u16* hl = hlds + swa * 1024;
  const int gcol = gcol0 + wid * 16 + lm;

  for (int t = 0; t < Tdim; t++) {
    // xpre prefetch — independent of the flag wait, issue first
    u16 xv[4];
#pragma unroll
    for (int j = 0; j < 4; j++) {
      const int m = lg * 4 + j;
      xv[j] = (m < 8) ? xpre[(size_t)(m * Tdim + t) * 4096 + gcol] : (u16)0;
    }
    if (t > 0 && tid < 64) {
      int* fl = flags + ((size_t)(t - 1) * 64 + tid) * 16;
      while (__hip_atomic_load(fl, __ATOMIC_RELAXED, __HIP_MEMORY_SCOPE_AGENT) == 0)
        __builtin_amdgcn_s_sleep(1);
      const u64* ps = (const u64*)(hbuf + ((size_t)(t - 1) * 64 + tid) * 128);
#pragma unroll
      for (int m = 0; m < 8; m++) {
#pragma unroll
        for (int half = 0; half < 2; half++) {
          const u64 a = __hip_atomic_load(ps + m * 4 + half * 2,     __ATOMIC_RELAXED, __HIP_MEMORY_SCOPE_AGENT);
          const u64 b = __hip_atomic_load(ps + m * 4 + half * 2 + 1, __ATOMIC_RELAXED, __HIP_MEMORY_SCOPE_AGENT);
          const int cidx = tid * 2 + half;
          u64x2 v; v[0] = a; v[1] = b;
          *(u64x2*)((char*)hlds + m * 2048 + ((cidx ^ m) * 16)) = v;
        }
      }
    }
    __syncthreads();   // S2: hlds ready (wlds ready at t=0 via barrier drain)

    f32x4 acc;
#pragma unroll
    for (int j = 0; j < 4; j++) acc[j] = bf2f(xv[j]);

    if (t > 0) {
#pragma unroll 4
      for (int kk = 0; kk < 32; kk++) {
        const int c0 = kk * 4 + (lg >> 1);
        const int sub = (lg & 1) * 4;
        Frag a, b;
        a.h[0] = *(const short4v*)(hl + ((c0 ^ swa) << 3) + sub);
        a.h[1] = *(const short4v*)(hl + (((c0 + 2) ^ swa) << 3) + sub);
        b.h[0] = *(const short4v*)(wl + ((c0 ^ swb) << 3) + sub);
        b.h[1] = *(const short4v*)(wl + (((c0 + 2) ^ swb) << 3) + sub);
        acc = __builtin_amdgcn_mfma_f32_16x16x32_bf16(a.v, b.v, acc, 0, 0, 0);
      }
    }
#pragma unroll
    for (int j = 0; j < 4; j++) {
      const int m = lg * 4 + j;
      if (m < 8) g_lds[wid][m][lm] = acc[j];
    }
    __syncthreads();   // S3: gates ready
    u16 hb = 0; int ug = 0;
    if (lane < 32) {
      const float gi = g_lds[wid][m_u][u_u * 4 + 0];
      const float gf = g_lds[wid][m_u][u_u * 4 + 1];
      const float gg = g_lds[wid][m_u][u_u * 4 + 2];
      const float go = g_lds[wid][m_u][u_u * 4 + 3];
      const float si = 1.f / (1.f + __expf(-gi));
      const float sf = 1.f / (1.f + __expf(-gf));
      const float so = 1.f / (1.f + __expf(-go));
      const float cn = sf * c_reg + si * ftanh(gg);
      c_reg = cn;
      const float hn = so * ftanh(cn);
      ug = wid * 4 + u_u;                 // unit 0..15 within block
      hb = f2b(hn);
      hout[m_u][ug] = hb;
    }
    __syncthreads();   // S4: hout ready
    if (tid < 16) {
      const int m = tid >> 1, half = tid & 1;
      const u64* src = (const u64*)&hout[m][half * 8];
      u64* dst = (u64*)(hbuf + ((size_t)t * 64 + bx) * 128 + m * 16 + half * 8);
      __hip_atomic_store(dst,     src[0], __ATOMIC_RELAXED, __HIP_MEMORY_SCOPE_AGENT);
      __hip_atomic_store(dst + 1, src[1], __ATOMIC_RELAXED, __HIP_MEMORY_SCOPE_AGENT);
    }
    asm volatile("s_waitcnt vmcnt(0)" ::: "memory");  // only packet stores pending
    if (tid == 0)
      __hip_atomic_store(flags + ((size_t)t * 64 + bx) * 16, 1, __ATOMIC_RELAXED, __HIP_MEMORY_SCOPE_AGENT);
    if (lane < 32)   // cat store AFTER the flag — drains during next step's wait
      cat[(size_t)(m_u * Tdim + t) * 2048 + bx * 16 + ug] = hb;
  }
}

// ---------------- small kernels
__global__ __launch_bounds__(256) void conv_whh_perm(const float* __restrict__ w, u16* __restrict__ o){
  const int n = blockIdx.x;
  const int p = (n & 3) * Hdim + (n >> 2);
  const int k0 = threadIdx.x * 4;
  const float4 v = *(const float4*)(w + (size_t)p * Hdim + k0);
  u16* op = o + (size_t)n * Hdim + k0;
  op[0] = f2b(v.x); op[1] = f2b(v.y); op[2] = f2b(v.z); op[3] = f2b(v.w);
}
__global__ __launch_bounds__(256) void bias_fold_k(const float* __restrict__ bi, const float* __restrict__ bh, float* __restrict__ o){
  const int n = blockIdx.x * 256 + threadIdx.x;
  const int p = (n & 3) * Hdim + (n >> 2);
  o[n] = bi[p] + bh[p];
}
__global__ __launch_bounds__(256) void embed_k(const int* __restrict__ ids, const float* __restrict__ tok,
                                               const float* __restrict__ pos, u16* __restrict__ x){
  const int row = blockIdx.x;
  const int t = row & (Tdim - 1);
  const int id = ids[row];
  const int h0 = threadIdx.x * 4;
  const float4 a = *(const float4*)(tok + (size_t)id * Hdim + h0);
  const float4 p = *(const float4*)(pos + (size_t)t * Hdim + h0);
  u16* op = x + (size_t)row * Hdim + h0;
  op[0] = f2b(a.x + p.x); op[1] = f2b(a.y + p.y); op[2] = f2b(a.z + p.z); op[3] = f2b(a.w + p.w);
}
__global__ __launch_bounds__(256) void cvt_bf16_k(const float* __restrict__ in, u16* __restrict__ out){
  const size_t i = ((size_t)blockIdx.x * 256 + threadIdx.x) * 4;
  const float4 v = *(const float4*)(in + i);
  out[i] = f2b(v.x); out[i+1] = f2b(v.y); out[i+2] = f2b(v.z); out[i+3] = f2b(v.w);
}
__global__ __launch_bounds__(256) void init_flags_k(int* __restrict__ flags){
  const int i = blockIdx.x * 256 + threadIdx.x;
  flags[i] = 0;
}
__global__ __launch_bounds__(256) void ln_rows(const float* __restrict__ in, u16* __restrict__ out,
                                               const float* __restrict__ g, const float* __restrict__ be){
  const int row = blockIdx.x, tid = threadIdx.x;
  const int lane = tid & 63, wid = tid >> 6;
  const float4 x = *(const float4*)(in + (size_t)row * Hdim + tid * 4);
  float s = x.x + x.y + x.z + x.w;
  float q = x.x * x.x + x.y * x.y + x.z * x.z + x.w * x.w;
  for (int o = 32; o; o >>= 1) { s += __shfl_down(s, o, 64); q += __shfl_down(q, o, 64); }
  __shared__ float sm[8];
  if (lane == 0) { sm[wid] = s; sm[4 + wid] = q; }
  __syncthreads();
  const float ts = sm[0] + sm[1] + sm[2] + sm[3];
  const float tq = sm[4] + sm[5] + sm[6] + sm[7];
  const float mean = ts * (1.f / Hdim);
  const float var  = tq * (1.f / Hdim) - mean * mean;
  const float r = rsqrtf(var + 1e-5f);
  const int h0 = tid * 4;
  const float4 gv = *(const float4*)(g + h0);
  const float4 bv = *(const float4*)(be + h0);
  u16* op = out + (size_t)row * Hdim + h0;
  op[0] = f2b((x.x - mean) * r * gv.x + bv.x);
  op[1] = f2b((x.y - mean) * r * gv.y + bv.y);
  op[2] = f2b((x.z - mean) * r * gv.z + bv.z);
  op[3] = f2b((x.w - mean) * r * gv.w + bv.w);
}
__global__ __launch_bounds__(256) void softmax_k(const float* __restrict__ sc, const void* __restrict__ am,
                                                 const int* __restrict__ mflag, u16* __restrict__ w){
  const int row = blockIdx.x, tid = threadIdx.x;
  const int lane = tid & 63, wid = tid >> 6;
  const int b = row >> 7;
  const int bflag = *mflag;
  const float v = sc[(size_t)row * Sdim + tid];
  const bool mk = mask_at(am, (size_t)b * Sdim + tid, bflag);
  const float vm = mk ? v : -10000.0f;
  float mx = vm;
  for (int o = 32; o; o >>= 1) mx = fmaxf(mx, __shfl_down(mx, o, 64));
  __shared__ float sm[8];
  if (lane == 0) sm[wid] = mx;
  __syncthreads();
  mx = fmaxf(fmaxf(sm[0], sm[1]), fmaxf(sm[2], sm[3]));
  const float ex = mk ? expf(vm - mx) : 0.f;
  float ss = ex;
  for (int o = 32; o; o >>= 1) ss += __shfl_down(ss, o, 64);
  if (lane == 0) sm[4 + wid] = ss;
  __syncthreads();
  const float tot = sm[4] + sm[5] + sm[6] + sm[7];
  w[(size_t)row * Sdim + tid] = f2b(ex / (tot + 1e-6f));
}
__global__ __launch_bounds__(256) void transp_k(const u16* __restrict__ kn, u16* __restrict__ knT){
  __shared__ u16 tile[64][65];
  const int b = blockIdx.z, h0 = blockIdx.x * 64, s0 = blockIdx.y * 64;
  const u16* src = kn  + (size_t)b * Sdim * Hdim;
  u16* dst       = knT + (size_t)b * Hdim * Sdim;
  for (int e = threadIdx.x; e < 4096; e += 256) {
    const int r = e >> 6, c = e & 63;
    tile[r][c] = src[(size_t)(s0 + r) * Hdim + h0 + c];
  }
  __syncthreads();
  for (int e = threadIdx.x; e < 4096; e += 256) {
    const int hr = e >> 6, scc = e & 63;
    dst[(size_t)(h0 + hr) * Sdim + s0 + scc] = tile[scc][hr];
  }
}

extern "C" void kernel_launch(void* const* d_in, const int* in_sizes, int n_in,
                              void* d_out, int out_size, void* d_ws, size_t ws_size,
                              hipStream_t stream) {
  const int*   input_ids = (const int*)d_in[0];
  const float* enc   = (const float*)d_in[1];
  const void*  pmask = d_in[2];
  const void*  amask = d_in[3];
  const float* tok  = (const float*)d_in[4];
  const float* pos  = (const float*)d_in[5];
  const float* w_ih = (const float*)d_in[6];
  const float* w_hh = (const float*)d_in[7];
  const float* b_ih = (const float*)d_in[8];
  const float* b_hh = (const float*)d_in[9];
  const float* wq = (const float*)d_in[10];
  const float* bq = (const float*)d_in[11];
  const float* wk = (const float*)d_in[12];
  const float* bk = (const float*)d_in[13];
  const float* wc = (const float*)d_in[14];
  const float* bc = (const float*)d_in[15];
  const float* wo = (const float*)d_in[16];
  const float* bo = (const float*)d_in[17];
  const float* g1  = (const float*)d_in[18];
  const float* be1 = (const float*)d_in[19];
  const float* g2  = (const float*)d_in[20];
  const float* be2 = (const float*)d_in[21];
  float* out = (float*)d_out;

  char* ws = (char*)d_ws;
  size_t off = 0;
  auto alloc = [&](size_t b){ size_t o = off; off += (b + 255) & ~(size_t)255; return o; };
  u16*   whhb  = (u16*)  (ws + alloc((size_t)4096 * 1024 * 2));
  float* biasf = (float*)(ws + alloc(4096 * 4));
  u16*   xbf   = (u16*)  (ws + alloc((size_t)1024 * 1024 * 2));
  u16*   encb  = (u16*)  (ws + alloc((size_t)2048 * 1024 * 2));
  u16*   xpre  = (u16*)  (ws + alloc((size_t)1024 * 4096 * 2));
  u16*   hbuf  = (u16*)  (ws + alloc((size_t)Tdim * 64 * 128 * 2));
  u16*   cat   = (u16*)  (ws + alloc((size_t)1024 * 2048 * 2));
  float* qlin  = (float*)(ws + alloc((size_t)1024 * 1024 * 4));
  u16*   qn    = (u16*)  (ws + alloc((size_t)1024 * 1024 * 2));
  float* klin  = (float*)(ws + alloc((size_t)2048 * 1024 * 4));
  u16*   kn    = (u16*)  (ws + alloc((size_t)2048 * 1024 * 2));
  u16*   knT   = (u16*)  (ws + alloc((size_t)2048 * 1024 * 2));
  float* scores= (float*)(ws + alloc((size_t)8 * 128 * 256 * 4));
  u16*   attw  = (u16*)  (ws + alloc((size_t)8 * 128 * 256 * 2));
  float* hlin  = (float*)(ws + alloc((size_t)1024 * 1024 * 4));
  u16*   hid   = (u16*)  (ws + alloc((size_t)1024 * 1024 * 2));
  int*   bflag = (int*)  (ws + alloc(256));
  int*   flags = (int*)  (ws + alloc((size_t)Tdim * 64 * 16 * 4));
  unsigned char* pmaskb = (unsigned char*)(ws + alloc((size_t)Bdim * Tdim * Vdim));
  const bool havePak = off <= ws_size;
  u16*   wob   = (u16*)  (ws + alloc((size_t)Vdim * Hdim * 2));
  const bool haveWob = off <= ws_size;
  (void)in_sizes; (void)n_in; (void)out_size;

  detect_bool_k<<<1, 256, 0, stream>>>((const unsigned char*)pmask, bflag);
  conv_whh_perm<<<4096, 256, 0, stream>>>(w_hh, whhb);
  bias_fold_k<<<16, 256, 0, stream>>>(b_ih, b_hh, biasf);
  embed_k<<<1024, 256, 0, stream>>>(input_ids, tok, pos, xbf);
  cvt_bf16_k<<<2048, 256, 0, stream>>>(enc, encb);
  init_flags_k<<<512, 256, 0, stream>>>(flags);
  if (haveWob) cvt_bf16_k<<<Vdim, 256, 0, stream>>>(wo, wob);
  if (havePak) pack_mask_k<<<(Bdim * Tdim * Vdim) / 256, 256, 0, stream>>>(pmask, bflag, pmaskb);

  // x_pre = x @ w_ih_perm.T + (b_ih + b_hh)   -> bf16 (1024 x 4096)
  gemm_bt<u16, true, false, true><<<dim3(32, 8, 1), 256, 0, stream>>>(
      xbf, 1024, 0, w_ih, 1024, 0, xpre, 4096, 0, biasf, nullptr, nullptr, 1024, 1.f);

  lstm_df<<<NBLK, 256, 0, stream>>>(xpre, whhb, hbuf, cat, flags);

  // q = lstm_out @ wq.T + bq ; LN(g1,be1)
  gemm_bt<float, true, false, false><<<dim3(8, 8, 1), 256, 0, stream>>>(
      cat, 2048, 0, wq, 1024, 0, qlin, 1024, 0, bq, nullptr, nullptr, 1024, 1.f);
  ln_rows<<<1024, 256, 0, stream>>>(qlin, qn, g1, be1);
  // k = enc @ wk.T + bk ; LN(g1,be1)
  gemm_bt<float, true, false, false><<<dim3(8, 16, 1), 256, 0, stream>>>(
      encb, 1024, 0, wk, 1024, 0, klin, 1024, 0, bk, nullptr, nullptr, 1024, 1.f);
  ln_rows<<<2048, 256, 0, stream>>>(klin, kn, g1, be1);
  transp_k<<<dim3(16, 4, 8), 256, 0, stream>>>(kn, knT);

  // scores = qn @ kn^T * scale   (batched over 8)
  gemm_bt<float, false, false, false><<<dim3(2, 1, 8), 256, 0, stream>>>(
      qn, 1024, 131072, kn, 1024, 262144, scores, 256, 32768, nullptr, nullptr, nullptr, 1024, 0.015625f);
  softmax_k<<<1024, 256, 0, stream>>>(scores, amask, bflag, attw);
  // ctx = w @ kn  -> right half of cat   (batched)
  gemm_bt<u16, false, false, false><<<dim3(8, 1, 8), 256, 0, stream>>>(
      attw, 256, 32768, knT, 256, 262144, cat + 1024, 2048, 262144, nullptr, nullptr, nullptr, 256, 1.f);

  // hidden = LN( cat @ wc.T + bc ; g2,be2 )
  gemm_bt<float, true, false, false><<<dim3(8, 8, 1), 256, 0, stream>>>(
      cat, 2048, 0, wc, 2048, 0, hlin, 1024, 0, bc, nullptr, nullptr, 2048, 1.f);
  ln_rows<<<1024, 256, 0, stream>>>(hlin, hid, g2, be2);

  // logits = hidden @ wo.T + bo, masked
  const void* mptr = havePak ? (const void*)pmaskb : pmask;
  const int*  mfl  = havePak ? (bflag + 1) : bflag;
  if (haveWob)
    gemm_bt<float, false, true, false><<<dim3(250, 8, 1), 256, 0, stream>>>(
        hid, 1024, 0, wob, 1024, 0, out, 32000, 0, bo, mptr, mfl, 1024, 1.f);
  else
    gemm_bt<float, true, true, false><<<dim3(250, 8, 1), 256, 0, stream>>>(
        hid, 1024, 0, wo, 1024, 0, out, 32000, 0, bo, mptr, mfl, 1024, 1.f);
}

// Round 6
// 1245.641 us; speedup vs baseline: 2.5864x; 1.2330x over previous
//
#include <hip/hip_runtime.h>
#include <cstdint>
#include <cstddef>

#define Bdim 8
#define Tdim 128
#define Sdim 256
#define Hdim 1024
#define Vdim 32000
#define NBLK 64

typedef unsigned short u16;
typedef unsigned long long u64;
typedef __attribute__((ext_vector_type(8))) short short8;
typedef __attribute__((ext_vector_type(4))) short short4v;
typedef __attribute__((ext_vector_type(4))) float f32x4;
typedef __attribute__((ext_vector_type(2))) unsigned long long u64x2;

union Frag { short8 v; short4v h[2]; };

__device__ __forceinline__ float bf2f(u16 u){
  union { unsigned int i; float f; } x; x.i = ((unsigned int)u) << 16; return x.f;
}
__device__ __forceinline__ u16 f2b(float f){
  union { float f; unsigned int u; } x; x.f = f;
  unsigned int r = x.u + 0x7FFFu + ((x.u >> 16) & 1u);  // RNE
  return (u16)(r >> 16);
}
__device__ __forceinline__ float ftanh(float x){
  x = fminf(10.f, fmaxf(-10.f, x));
  const float e = __expf(2.f * x);
  return (e - 1.f) / (e + 1.f);
}

__device__ __forceinline__ void gload16(const void* g, void* l){
  __builtin_amdgcn_global_load_lds((const __attribute__((address_space(1))) unsigned int*)g,
                                   (__attribute__((address_space(3))) unsigned int*)l, 16, 0, 0);
}

// 16B-cell swizzle for 64B-wide LDS tile rows (4 cells/row)
__device__ __forceinline__ int qsw(int r){ return (r + (r >> 2)) & 3; }

// Bool dtype detector: bool arrays may arrive as int32 or byte-sized.
__global__ __launch_bounds__(256) void detect_bool_k(const unsigned char* __restrict__ p, int* __restrict__ flag){
  __shared__ int s;
  if (threadIdx.x == 0) s = 0;
  __syncthreads();
  int loc = 0;
  for (int i = threadIdx.x; i < 65536; i += 256)
    if ((i & 3) && p[i]) loc = 1;
  if (loc) atomicOr(&s, 1);
  __syncthreads();
  if (threadIdx.x == 0) { flag[0] = s; flag[1] = 1; }
}

__device__ __forceinline__ bool mask_at(const void* m, size_t idx, int byteflag){
  if (byteflag) return ((const unsigned char*)m)[idx] != 0;
  return ((const int*)m)[idx] != 0;
}

__global__ __launch_bounds__(256) void pack_mask_k(const void* __restrict__ pm, const int* __restrict__ bflag,
                                                   unsigned char* __restrict__ o){
  const size_t i = (size_t)blockIdx.x * 256 + threadIdx.x;
  o[i] = mask_at(pm, i, *bflag) ? 1 : 0;
}

// ---------------- generic GEMM: C[m][n] = alpha*sum_k A[m][k]*Bt[n][k] + bias[n]
// SWAP: m-tiles on blockIdx.x (dispatch-adjacent blocks share B-tile -> L2/IF reuse)
template<typename OutT, bool BF32, bool MASKED, bool PERMB, bool SWAP>
__global__ __launch_bounds__(256) void gemm_bt(
    const u16* __restrict__ A, int lda, long sA,
    const void* __restrict__ Bp, int ldb, long sB,
    OutT* __restrict__ C, int ldc, long sC,
    const float* __restrict__ bias,
    const void* __restrict__ mask,
    const int* __restrict__ mflag,
    int K, float alpha)
{
  __shared__ alignas(16) char ldsA[8192];   // 128 x 32 bf16, cell-swizzled
  __shared__ alignas(16) char ldsB[8192];
  const int tid  = threadIdx.x;
  const int lane = tid & 63, wid = tid >> 6;
  const int lm = lane & 15, lg = lane >> 4;
  const int wm = wid >> 1, wn = wid & 1;            // 2x2 waves, 64x64 each
  const int m0 = (SWAP ? blockIdx.x : blockIdx.y) * 128;
  const int n0 = (SWAP ? blockIdx.y : blockIdx.x) * 128;
  const int z  = blockIdx.z;
  const char* Ab = (const char*)(A + (size_t)z * sA);

  f32x4 acc[4][4];
#pragma unroll
  for (int i = 0; i < 4; i++)
#pragma unroll
    for (int j = 0; j < 4; j++) acc[i][j] = (f32x4){0.f, 0.f, 0.f, 0.f};

  const int brow = tid >> 1, bhalf = tid & 1;
  int bsrow = n0 + brow;
  if (PERMB) bsrow = (bsrow & 3) * Hdim + (bsrow >> 2);
  const int qb_st = qsw(brow);

  for (int k0 = 0; k0 < K; k0 += 32) {
    {  // stage A: linear LDS dest, swizzled global source (rule #21)
      const char* ga = Ab + ((size_t)m0 * lda + k0) * 2;
      const int f0 = tid, f1 = tid + 256;
      const int r0 = f0 >> 2, r1 = f1 >> 2;
      gload16(ga + (size_t)r0 * (lda * 2) + ((f0 & 3) ^ qsw(r0)) * 16, ldsA + (f0 & ~63) * 16);
      gload16(ga + (size_t)r1 * (lda * 2) + ((f1 & 3) ^ qsw(r1)) * 16, ldsA + (f1 & ~63) * 16);
    }
    if (BF32) {
      const float* Bf = (const float*)Bp + (size_t)z * sB;
      const float4* src = (const float4*)(Bf + (size_t)bsrow * ldb + k0 + bhalf * 16);
      float4 v0 = src[0], v1 = src[1], v2 = src[2], v3 = src[3];
      union { short8 v; short s[8]; } p0, p1;
      p0.s[0]=(short)f2b(v0.x); p0.s[1]=(short)f2b(v0.y); p0.s[2]=(short)f2b(v0.z); p0.s[3]=(short)f2b(v0.w);
      p0.s[4]=(short)f2b(v1.x); p0.s[5]=(short)f2b(v1.y); p0.s[6]=(short)f2b(v1.z); p0.s[7]=(short)f2b(v1.w);
      p1.s[0]=(short)f2b(v2.x); p1.s[1]=(short)f2b(v2.y); p1.s[2]=(short)f2b(v2.z); p1.s[3]=(short)f2b(v2.w);
      p1.s[4]=(short)f2b(v3.x); p1.s[5]=(short)f2b(v3.y); p1.s[6]=(short)f2b(v3.z); p1.s[7]=(short)f2b(v3.w);
      char* base = ldsB + brow * 64;
      *(short8*)(base + (((bhalf * 2 + 0) ^ qb_st) * 16)) = p0.v;
      *(short8*)(base + (((bhalf * 2 + 1) ^ qb_st) * 16)) = p1.v;
    } else {
      const char* gb = (const char*)Bp + (size_t)z * sB * 2 + ((size_t)n0 * ldb + k0) * 2;
      const int f0 = tid, f1 = tid + 256;
      const int r0 = f0 >> 2, r1 = f1 >> 2;
      gload16(gb + (size_t)r0 * (ldb * 2) + ((f0 & 3) ^ qsw(r0)) * 16, ldsB + (f0 & ~63) * 16);
      gload16(gb + (size_t)r1 * (ldb * 2) + ((f1 & 3) ^ qsw(r1)) * 16, ldsB + (f1 & ~63) * 16);
    }
    __syncthreads();

    Frag a[4], b[4];
#pragma unroll
    for (int mi = 0; mi < 4; mi++) {
      const int rr = wm * 64 + mi * 16 + lm;
      const int q = qsw(rr);
      const char* p = ldsA + rr * 64 + (lg & 1) * 8;
      a[mi].h[0] = *(const short4v*)(p + (((lg >> 1) ^ q) * 16));
      a[mi].h[1] = *(const short4v*)(p + ((((lg >> 1) | 2) ^ q) * 16));
    }
#pragma unroll
    for (int ni = 0; ni < 4; ni++) {
      const int rr = wn * 64 + ni * 16 + lm;
      const int q = qsw(rr);
      const char* p = ldsB + rr * 64 + (lg & 1) * 8;
      b[ni].h[0] = *(const short4v*)(p + (((lg >> 1) ^ q) * 16));
      b[ni].h[1] = *(const short4v*)(p + ((((lg >> 1) | 2) ^ q) * 16));
    }
#pragma unroll
    for (int mi = 0; mi < 4; mi++)
#pragma unroll
      for (int ni = 0; ni < 4; ni++)
        acc[mi][ni] = __builtin_amdgcn_mfma_f32_16x16x32_bf16(a[mi].v, b[ni].v, acc[mi][ni], 0, 0, 0);
    __syncthreads();
  }

  const int bflag = MASKED ? *mflag : 0;
#pragma unroll
  for (int mi = 0; mi < 4; mi++) {
#pragma unroll
    for (int ni = 0; ni < 4; ni++) {
      const int row = m0 + wm * 64 + mi * 16 + lg * 4;
      const int col = n0 + wn * 64 + ni * 16 + lm;
      const float bb = bias ? bias[col] : 0.f;
#pragma unroll
      for (int j = 0; j < 4; j++) {
        float v = acc[mi][ni][j] * alpha + bb;
        if (MASKED) { if (!mask_at(mask, (size_t)(row + j) * ldc + col, bflag)) v = -10000.0f; }
        const size_t o = (size_t)z * sC + (size_t)(row + j) * ldc + col;
        if constexpr (sizeof(OutT) == 2) C[o] = (OutT)f2b(v); else C[o] = (OutT)v;
      }
    }
  }
}

// ---------------- persistent LSTM, packetized dataflow sync
// 64 blocks x 256 thr. Block bx owns gate-cols [bx*64, bx*64+64) = 16 units.
// whh slice (128KB) lives in LDS. Per step each block emits one 256B packet
// + a flag on a private cacheline. Consumers: 4 threads per packet (all 256
// threads) poll + copy as flags land. No cat stores in-loop (hbuf keeps all t).
__global__ __launch_bounds__(256) void lstm_df(
    const u16* __restrict__ xpre,   // (b*128+t, 4096) bf16, includes biases
    const u16* __restrict__ whh,    // (4096, 1024) bf16, gate-permuted rows
    u16* __restrict__ hbuf,         // Tdim x 64 x (8m x 16u) u16 packets
    int* __restrict__ flags)        // Tdim x 64 x 16 ints (64B stride), zeroed
{
  __shared__ alignas(16) u16 wlds[64 * 1024];  // 128KB, cell c^(r&7) swizzle
  __shared__ alignas(16) u16 hlds[8 * 1024];   // 16KB,  cell c^m swizzle
  __shared__ float g_lds[4][8][17];
  __shared__ alignas(16) u16 hout[8][16];
  const int tid = threadIdx.x, lane = tid & 63, wid = tid >> 6;
  const int lm = lane & 15, lg = lane >> 4;
  const int bx = blockIdx.x;
  const int gcol0 = bx * 64;

  // stage whh slice once: 8192 cells of 16B, swizzled source -> linear LDS
  for (int q = tid; q < 8192; q += 256) {
    const int r = q >> 7, cc = q & 127;
    gload16(whh + (size_t)(gcol0 + r) * 1024 + (size_t)(cc ^ (r & 7)) * 8,
            (char*)wlds + (q & ~63) * 16);
  }

  float c_reg = 0.f;
  const int m_u = lane & 7, u_u = lane >> 3;        // epilogue coords (lane<32)
  const int rloc = wid * 16 + lm, swb = rloc & 7, swa = lm & 7;
  const u16* wl = wlds + rloc * 1024;
  const u16* hl = hlds + swa * 1024;
  const int gcol = gcol0 + wid * 16 + lm;
  const int pk = tid >> 2, qq = tid & 3;            // consumer: packet, quarter

  for (int t = 0; t < Tdim; t++) {
    // xpre prefetch — independent of the flag wait, issue first
    u16 xv[4];
#pragma unroll
    for (int j = 0; j < 4; j++) {
      const int m = lg * 4 + j;
      xv[j] = (m < 8) ? xpre[(size_t)(m * Tdim + t) * 4096 + gcol] : (u16)0;
    }
    if (t > 0) {
      int* fl = flags + ((size_t)(t - 1) * 64 + pk) * 16;
      while (__hip_atomic_load(fl, __ATOMIC_RELAXED, __HIP_MEMORY_SCOPE_AGENT) == 0)
        __builtin_amdgcn_s_sleep(1);
      const u64* ps = (const u64*)(hbuf + ((size_t)(t - 1) * 64 + pk) * 128);
#pragma unroll
      for (int mm = 0; mm < 2; mm++) {
        const int m = qq * 2 + mm;
        const u64 v0 = __hip_atomic_load(ps + m * 4 + 0, __ATOMIC_RELAXED, __HIP_MEMORY_SCOPE_AGENT);
        const u64 v1 = __hip_atomic_load(ps + m * 4 + 1, __ATOMIC_RELAXED, __HIP_MEMORY_SCOPE_AGENT);
        const u64 v2 = __hip_atomic_load(ps + m * 4 + 2, __ATOMIC_RELAXED, __HIP_MEMORY_SCOPE_AGENT);
        const u64 v3 = __hip_atomic_load(ps + m * 4 + 3, __ATOMIC_RELAXED, __HIP_MEMORY_SCOPE_AGENT);
        u64x2 a; a[0] = v0; a[1] = v1;
        u64x2 b; b[0] = v2; b[1] = v3;
        *(u64x2*)((char*)hlds + m * 2048 + (((pk * 2 + 0) ^ m) * 16)) = a;
        *(u64x2*)((char*)hlds + m * 2048 + (((pk * 2 + 1) ^ m) * 16)) = b;
      }
    }
    __syncthreads();   // S2: hlds ready (wlds ready at t=0 via barrier drain)

    f32x4 acc;
#pragma unroll
    for (int j = 0; j < 4; j++) acc[j] = bf2f(xv[j]);

    if (t > 0) {
#pragma unroll 4
      for (int kk = 0; kk < 32; kk++) {
        const int c0 = kk * 4 + (lg >> 1);
        const int sub = (lg & 1) * 4;
        Frag a, b;
        a.h[0] = *(const short4v*)(hl + ((c0 ^ swa) << 3) + sub);
        a.h[1] = *(const short4v*)(hl + (((c0 + 2) ^ swa) << 3) + sub);
        b.h[0] = *(const short4v*)(wl + ((c0 ^ swb) << 3) + sub);
        b.h[1] = *(const short4v*)(wl + (((c0 + 2) ^ swb) << 3) + sub);
        acc = __builtin_amdgcn_mfma_f32_16x16x32_bf16(a.v, b.v, acc, 0, 0, 0);
      }
    }
#pragma unroll
    for (int j = 0; j < 4; j++) {
      const int m = lg * 4 + j;
      if (m < 8) g_lds[wid][m][lm] = acc[j];
    }
    __syncthreads();   // S3: gates ready
    if (lane < 32) {
      const float gi = g_lds[wid][m_u][u_u * 4 + 0];
      const float gf = g_lds[wid][m_u][u_u * 4 + 1];
      const float gg = g_lds[wid][m_u][u_u * 4 + 2];
      const float go = g_lds[wid][m_u][u_u * 4 + 3];
      const float si = 1.f / (1.f + __expf(-gi));
      const float sf = 1.f / (1.f + __expf(-gf));
      const float so = 1.f / (1.f + __expf(-go));
      const float cn = sf * c_reg + si * ftanh(gg);
      c_reg = cn;
      const float hn = so * ftanh(cn);
      hout[m_u][wid * 4 + u_u] = f2b(hn);
    }
    __syncthreads();   // S4: hout ready
    if (tid < 16) {
      const int m = tid >> 1, half = tid & 1;
      const u64* src = (const u64*)&hout[m][half * 8];
      u64* dst = (u64*)(hbuf + ((size_t)t * 64 + bx) * 128 + m * 16 + half * 8);
      __hip_atomic_store(dst,     src[0], __ATOMIC_RELAXED, __HIP_MEMORY_SCOPE_AGENT);
      __hip_atomic_store(dst + 1, src[1], __ATOMIC_RELAXED, __HIP_MEMORY_SCOPE_AGENT);
    }
    asm volatile("s_waitcnt vmcnt(0)" ::: "memory");  // only packet stores pending
    if (tid == 0)
      __hip_atomic_store(flags + ((size_t)t * 64 + bx) * 16, 1, __ATOMIC_RELAXED, __HIP_MEMORY_SCOPE_AGENT);
  }
}

// hbuf [t][p][m][u16x16] -> cat rows (m*Tdim+t), cols p*16+u (left half of 2048)
__global__ __launch_bounds__(256) void hbuf_cat_k(const u16* __restrict__ hbuf, u16* __restrict__ cat){
  const int t = blockIdx.x, tid = threadIdx.x;
  const int p = tid >> 2, q = tid & 3;
  const u64* src = (const u64*)(hbuf + ((size_t)t * 64 + p) * 128);
#pragma unroll
  for (int m = 0; m < 8; m++) {
    const u64 v = src[m * 4 + q];
    *(u64*)(cat + (size_t)(m * Tdim + t) * 2048 + p * 16 + q * 4) = v;
  }
}

// ---------------- small kernels
__global__ __launch_bounds__(256) void conv_whh_perm(const float* __restrict__ w, u16* __restrict__ o){
  const int n = blockIdx.x;
  const int p = (n & 3) * Hdim + (n >> 2);
  const int k0 = threadIdx.x * 4;
  const float4 v = *(const float4*)(w + (size_t)p * Hdim + k0);
  u16* op = o + (size_t)n * Hdim + k0;
  op[0] = f2b(v.x); op[1] = f2b(v.y); op[2] = f2b(v.z); op[3] = f2b(v.w);
}
__global__ __launch_bounds__(256) void bias_fold_k(const float* __restrict__ bi, const float* __restrict__ bh, float* __restrict__ o){
  const int n = blockIdx.x * 256 + threadIdx.x;
  const int p = (n & 3) * Hdim + (n >> 2);
  o[n] = bi[p] + bh[p];
}
__global__ __launch_bounds__(256) void embed_k(const int* __restrict__ ids, const float* __restrict__ tok,
                                               const float* __restrict__ pos, u16* __restrict__ x){
  const int row = blockIdx.x;
  const int t = row & (Tdim - 1);
  const int id = ids[row];
  const int h0 = threadIdx.x * 4;
  const float4 a = *(const float4*)(tok + (size_t)id * Hdim + h0);
  const float4 p = *(const float4*)(pos + (size_t)t * Hdim + h0);
  u16* op = x + (size_t)row * Hdim + h0;
  op[0] = f2b(a.x + p.x); op[1] = f2b(a.y + p.y); op[2] = f2b(a.z + p.z); op[3] = f2b(a.w + p.w);
}
__global__ __launch_bounds__(256) void cvt_bf16_k(const float* __restrict__ in, u16* __restrict__ out){
  const size_t i = ((size_t)blockIdx.x * 256 + threadIdx.x) * 4;
  const float4 v = *(const float4*)(in + i);
  out[i] = f2b(v.x); out[i+1] = f2b(v.y); out[i+2] = f2b(v.z); out[i+3] = f2b(v.w);
}
__global__ __launch_bounds__(256) void init_flags_k(int* __restrict__ flags){
  const int i = blockIdx.x * 256 + threadIdx.x;
  flags[i] = 0;
}
__global__ __launch_bounds__(256) void ln_rows(const float* __restrict__ in, u16* __restrict__ out,
                                               const float* __restrict__ g, const float* __restrict__ be){
  const int row = blockIdx.x, tid = threadIdx.x;
  const int lane = tid & 63, wid = tid >> 6;
  const float4 x = *(const float4*)(in + (size_t)row * Hdim + tid * 4);
  float s = x.x + x.y + x.z + x.w;
  float q = x.x * x.x + x.y * x.y + x.z * x.z + x.w * x.w;
  for (int o = 32; o; o >>= 1) { s += __shfl_down(s, o, 64); q += __shfl_down(q, o, 64); }
  __shared__ float sm[8];
  if (lane == 0) { sm[wid] = s; sm[4 + wid] = q; }
  __syncthreads();
  const float ts = sm[0] + sm[1] + sm[2] + sm[3];
  const float tq = sm[4] + sm[5] + sm[6] + sm[7];
  const float mean = ts * (1.f / Hdim);
  const float var  = tq * (1.f / Hdim) - mean * mean;
  const float r = rsqrtf(var + 1e-5f);
  const int h0 = tid * 4;
  const float4 gv = *(const float4*)(g + h0);
  const float4 bv = *(const float4*)(be + h0);
  u16* op = out + (size_t)row * Hdim + h0;
  op[0] = f2b((x.x - mean) * r * gv.x + bv.x);
  op[1] = f2b((x.y - mean) * r * gv.y + bv.y);
  op[2] = f2b((x.z - mean) * r * gv.z + bv.z);
  op[3] = f2b((x.w - mean) * r * gv.w + bv.w);
}
__global__ __launch_bounds__(256) void softmax_k(const float* __restrict__ sc, const void* __restrict__ am,
                                                 const int* __restrict__ mflag, u16* __restrict__ w){
  const int row = blockIdx.x, tid = threadIdx.x;
  const int lane = tid & 63, wid = tid >> 6;
  const int b = row >> 7;
  const int bflag = *mflag;
  const float v = sc[(size_t)row * Sdim + tid];
  const bool mk = mask_at(am, (size_t)b * Sdim + tid, bflag);
  const float vm = mk ? v : -10000.0f;
  float mx = vm;
  for (int o = 32; o; o >>= 1) mx = fmaxf(mx, __shfl_down(mx, o, 64));
  __shared__ float sm[8];
  if (lane == 0) sm[wid] = mx;
  __syncthreads();
  mx = fmaxf(fmaxf(sm[0], sm[1]), fmaxf(sm[2], sm[3]));
  const float ex = mk ? expf(vm - mx) : 0.f;
  float ss = ex;
  for (int o = 32; o; o >>= 1) ss += __shfl_down(ss, o, 64);
  if (lane == 0) sm[4 + wid] = ss;
  __syncthreads();
  const float tot = sm[4] + sm[5] + sm[6] + sm[7];
  w[(size_t)row * Sdim + tid] = f2b(ex / (tot + 1e-6f));
}
__global__ __launch_bounds__(256) void transp_k(const u16* __restrict__ kn, u16* __restrict__ knT){
  __shared__ u16 tile[64][65];
  const int b = blockIdx.z, h0 = blockIdx.x * 64, s0 = blockIdx.y * 64;
  const u16* src = kn  + (size_t)b * Sdim * Hdim;
  u16* dst       = knT + (size_t)b * Hdim * Sdim;
  for (int e = threadIdx.x; e < 4096; e += 256) {
    const int r = e >> 6, c = e & 63;
    tile[r][c] = src[(size_t)(s0 + r) * Hdim + h0 + c];
  }
  __syncthreads();
  for (int e = threadIdx.x; e < 4096; e += 256) {
    const int hr = e >> 6, scc = e & 63;
    dst[(size_t)(h0 + hr) * Sdim + s0 + scc] = tile[scc][hr];
  }
}

extern "C" void kernel_launch(void* const* d_in, const int* in_sizes, int n_in,
                              void* d_out, int out_size, void* d_ws, size_t ws_size,
                              hipStream_t stream) {
  const int*   input_ids = (const int*)d_in[0];
  const float* enc   = (const float*)d_in[1];
  const void*  pmask = d_in[2];
  const void*  amask = d_in[3];
  const float* tok  = (const float*)d_in[4];
  const float* pos  = (const float*)d_in[5];
  const float* w_ih = (const float*)d_in[6];
  const float* w_hh = (const float*)d_in[7];
  const float* b_ih = (const float*)d_in[8];
  const float* b_hh = (const float*)d_in[9];
  const float* wq = (const float*)d_in[10];
  const float* bq = (const float*)d_in[11];
  const float* wk = (const float*)d_in[12];
  const float* bk = (const float*)d_in[13];
  const float* wc = (const float*)d_in[14];
  const float* bc = (const float*)d_in[15];
  const float* wo = (const float*)d_in[16];
  const float* bo = (const float*)d_in[17];
  const float* g1  = (const float*)d_in[18];
  const float* be1 = (const float*)d_in[19];
  const float* g2  = (const float*)d_in[20];
  const float* be2 = (const float*)d_in[21];
  float* out = (float*)d_out;

  char* ws = (char*)d_ws;
  size_t off = 0;
  auto alloc = [&](size_t b){ size_t o = off; off += (b + 255) & ~(size_t)255; return o; };
  u16*   whhb  = (u16*)  (ws + alloc((size_t)4096 * 1024 * 2));
  float* biasf = (float*)(ws + alloc(4096 * 4));
  u16*   xbf   = (u16*)  (ws + alloc((size_t)1024 * 1024 * 2));
  u16*   encb  = (u16*)  (ws + alloc((size_t)2048 * 1024 * 2));
  u16*   xpre  = (u16*)  (ws + alloc((size_t)1024 * 4096 * 2));
  u16*   hbuf  = (u16*)  (ws + alloc((size_t)Tdim * 64 * 128 * 2));
  u16*   cat   = (u16*)  (ws + alloc((size_t)1024 * 2048 * 2));
  float* qlin  = (float*)(ws + alloc((size_t)1024 * 1024 * 4));
  u16*   qn    = (u16*)  (ws + alloc((size_t)1024 * 1024 * 2));
  float* klin  = (float*)(ws + alloc((size_t)2048 * 1024 * 4));
  u16*   kn    = (u16*)  (ws + alloc((size_t)2048 * 1024 * 2));
  u16*   knT   = (u16*)  (ws + alloc((size_t)2048 * 1024 * 2));
  float* scores= (float*)(ws + alloc((size_t)8 * 128 * 256 * 4));
  u16*   attw  = (u16*)  (ws + alloc((size_t)8 * 128 * 256 * 2));
  float* hlin  = (float*)(ws + alloc((size_t)1024 * 1024 * 4));
  u16*   hid   = (u16*)  (ws + alloc((size_t)1024 * 1024 * 2));
  int*   bflag = (int*)  (ws + alloc(256));
  int*   flags = (int*)  (ws + alloc((size_t)Tdim * 64 * 16 * 4));
  unsigned char* pmaskb = (unsigned char*)(ws + alloc((size_t)Bdim * Tdim * Vdim));
  const bool havePak = off <= ws_size;
  u16*   wob   = (u16*)  (ws + alloc((size_t)Vdim * Hdim * 2));
  const bool haveWob = off <= ws_size;
  (void)in_sizes; (void)n_in; (void)out_size;

  detect_bool_k<<<1, 256, 0, stream>>>((const unsigned char*)pmask, bflag);
  conv_whh_perm<<<4096, 256, 0, stream>>>(w_hh, whhb);
  bias_fold_k<<<16, 256, 0, stream>>>(b_ih, b_hh, biasf);
  embed_k<<<1024, 256, 0, stream>>>(input_ids, tok, pos, xbf);
  cvt_bf16_k<<<2048, 256, 0, stream>>>(enc, encb);
  init_flags_k<<<512, 256, 0, stream>>>(flags);
  if (haveWob) cvt_bf16_k<<<Vdim, 256, 0, stream>>>(wo, wob);
  if (havePak) pack_mask_k<<<(Bdim * Tdim * Vdim) / 256, 256, 0, stream>>>(pmask, bflag, pmaskb);

  // x_pre = x @ w_ih_perm.T + (b_ih + b_hh)   -> bf16 (1024 x 4096)
  gemm_bt<u16, true, false, true, false><<<dim3(32, 8, 1), 256, 0, stream>>>(
      xbf, 1024, 0, w_ih, 1024, 0, xpre, 4096, 0, biasf, nullptr, nullptr, 1024, 1.f);

  lstm_df<<<NBLK, 256, 0, stream>>>(xpre, whhb, hbuf, flags);
  hbuf_cat_k<<<Tdim, 256, 0, stream>>>(hbuf, cat);

  // q = lstm_out @ wq.T + bq ; LN(g1,be1)
  gemm_bt<float, true, false, false, false><<<dim3(8, 8, 1), 256, 0, stream>>>(
      cat, 2048, 0, wq, 1024, 0, qlin, 1024, 0, bq, nullptr, nullptr, 1024, 1.f);
  ln_rows<<<1024, 256, 0, stream>>>(qlin, qn, g1, be1);
  // k = enc @ wk.T + bk ; LN(g1,be1)
  gemm_bt<float, true, false, false, false><<<dim3(8, 16, 1), 256, 0, stream>>>(
      encb, 1024, 0, wk, 1024, 0, klin, 1024, 0, bk, nullptr, nullptr, 1024, 1.f);
  ln_rows<<<2048, 256, 0, stream>>>(klin, kn, g1, be1);
  transp_k<<<dim3(16, 4, 8), 256, 0, stream>>>(kn, knT);

  // scores = qn @ kn^T * scale   (batched over 8)
  gemm_bt<float, false, false, false, false><<<dim3(2, 1, 8), 256, 0, stream>>>(
      qn, 1024, 131072, kn, 1024, 262144, scores, 256, 32768, nullptr, nullptr, nullptr, 1024, 0.015625f);
  softmax_k<<<1024, 256, 0, stream>>>(scores, amask, bflag, attw);
  // ctx = w @ kn  -> right half of cat   (batched)
  gemm_bt<u16, false, false, false, false><<<dim3(8, 1, 8), 256, 0, stream>>>(
      attw, 256, 32768, knT, 256, 262144, cat + 1024, 2048, 262144, nullptr, nullptr, nullptr, 256, 1.f);

  // hidden = LN( cat @ wc.T + bc ; g2,be2 )
  gemm_bt<float, true, false, false, false><<<dim3(8, 8, 1), 256, 0, stream>>>(
      cat, 2048, 0, wc, 2048, 0, hlin, 1024, 0, bc, nullptr, nullptr, 2048, 1.f);
  ln_rows<<<1024, 256, 0, stream>>>(hlin, hid, g2, be2);

  // logits = hidden @ wo.T + bo, masked — SWAP grid: co-resident blocks share B-tile
  const void* mptr = havePak ? (const void*)pmaskb : pmask;
  const int*  mfl  = havePak ? (bflag + 1) : bflag;
  if (haveWob)
    gemm_bt<float, false, true, false, true><<<dim3(8, 250, 1), 256, 0, stream>>>(
        hid, 1024, 0, wob, 1024, 0, out, 32000, 0, bo, mptr, mfl, 1024, 1.f);
  else
    gemm_bt<float, true, true, false, true><<<dim3(8, 250, 1), 256, 0, stream>>>(
        hid, 1024, 0, wo, 1024, 0, out, 32000, 0, bo, mptr, mfl, 1024, 1.f);
}

// Round 7
// 1025.907 us; speedup vs baseline: 3.1403x; 1.2142x over previous
//
#include <hip/hip_runtime.h>
#include <cstdint>
#include <cstddef>

#define Bdim 8
#define Tdim 128
#define Sdim 256
#define Hdim 1024
#define Vdim 32000

typedef unsigned short u16;
typedef unsigned long long u64;
typedef __attribute__((ext_vector_type(8))) short short8;
typedef __attribute__((ext_vector_type(4))) short short4v;
typedef __attribute__((ext_vector_type(4))) float f32x4;
typedef __attribute__((ext_vector_type(2))) unsigned long long u64x2;

union Frag { short8 v; short4v h[2]; };

__device__ __forceinline__ float bf2f(u16 u){
  union { unsigned int i; float f; } x; x.i = ((unsigned int)u) << 16; return x.f;
}
__device__ __forceinline__ u16 f2b(float f){
  union { float f; unsigned int u; } x; x.f = f;
  unsigned int r = x.u + 0x7FFFu + ((x.u >> 16) & 1u);  // RNE
  return (u16)(r >> 16);
}
__device__ __forceinline__ float ftanh(float x){
  x = fminf(10.f, fmaxf(-10.f, x));
  const float e = __expf(2.f * x);
  return (e - 1.f) / (e + 1.f);
}

__device__ __forceinline__ void gload16(const void* g, void* l){
  __builtin_amdgcn_global_load_lds((const __attribute__((address_space(1))) unsigned int*)g,
                                   (__attribute__((address_space(3))) unsigned int*)l, 16, 0, 0);
}

// 16B-cell swizzle for 64B-wide LDS tile rows (4 cells/row)
__device__ __forceinline__ int qsw(int r){ return (r + (r >> 2)) & 3; }

__global__ __launch_bounds__(256) void detect_bool_k(const unsigned char* __restrict__ p, int* __restrict__ flag){
  __shared__ int s;
  if (threadIdx.x == 0) s = 0;
  __syncthreads();
  int loc = 0;
  for (int i = threadIdx.x; i < 65536; i += 256)
    if ((i & 3) && p[i]) loc = 1;
  if (loc) atomicOr(&s, 1);
  __syncthreads();
  if (threadIdx.x == 0) flag[0] = s;
}

__device__ __forceinline__ bool mask_at(const void* m, size_t idx, int byteflag){
  if (byteflag) return ((const unsigned char*)m)[idx] != 0;
  return ((const int*)m)[idx] != 0;
}

// ---------------- 2-phase double-buffered GEMM core
// C[m][n] = alpha*sum_k A[m][k]*Bt[n][k] + bias[n].  A bf16 staged via
// global_load_lds (swizzled source, linear LDS). B bf16 same (BF32=false) or
// fp32 reg-staged load-early/convert-late (BF32=true, logits fallback only).
template<typename OutT, bool BF32, bool MASKED>
__device__ __forceinline__ void gemm_core(
    char* ldsA0, char* ldsB0, char* ldsA1, char* ldsB1,
    int m0, int n0, int z,
    const u16* __restrict__ A, int lda, long sA,
    const void* __restrict__ Bp, int ldb, long sB,
    OutT* __restrict__ C, int ldc, long sC,
    const float* __restrict__ bias,
    const void* __restrict__ mask,
    const int* __restrict__ mflag,
    int K, float alpha)
{
  const int tid  = threadIdx.x;
  const int lane = tid & 63, wid = tid >> 6;
  const int lm = lane & 15, lg = lane >> 4;
  const int wm = wid >> 1, wn = wid & 1;            // 2x2 waves, 64x64 each
  const char* Ab = (const char*)(A + (size_t)z * sA);

  f32x4 acc[4][4];
#pragma unroll
  for (int i = 0; i < 4; i++)
#pragma unroll
    for (int j = 0; j < 4; j++) acc[i][j] = (f32x4){0.f, 0.f, 0.f, 0.f};

  const int brow = tid >> 1, bhalf = tid & 1;       // BF32 staging coords
  const int qb_st = qsw(brow);

  auto stageA = [&](char* dst, int k0){
    const char* ga = Ab + ((size_t)m0 * lda + k0) * 2;
    const int f0 = tid, f1 = tid + 256;
    const int r0 = f0 >> 2, r1 = f1 >> 2;
    gload16(ga + (size_t)r0 * (lda * 2) + ((f0 & 3) ^ qsw(r0)) * 16, dst + (f0 & ~63) * 16);
    gload16(ga + (size_t)r1 * (lda * 2) + ((f1 & 3) ^ qsw(r1)) * 16, dst + (f1 & ~63) * 16);
  };
  auto stageB16 = [&](char* dst, int k0){
    const char* gb = (const char*)((const u16*)Bp + (size_t)z * sB) + ((size_t)n0 * ldb + k0) * 2;
    const int f0 = tid, f1 = tid + 256;
    const int r0 = f0 >> 2, r1 = f1 >> 2;
    gload16(gb + (size_t)r0 * (ldb * 2) + ((f0 & 3) ^ qsw(r0)) * 16, dst + (f0 & ~63) * 16);
    gload16(gb + (size_t)r1 * (ldb * 2) + ((f1 & 3) ^ qsw(r1)) * 16, dst + (f1 & ~63) * 16);
  };

  float4 nv0, nv1, nv2, nv3;                        // BF32 in-flight tile
  auto loadB32 = [&](int k0){
    const float* Bf = (const float*)Bp + (size_t)z * sB;
    const float4* src = (const float4*)(Bf + (size_t)(n0 + brow) * ldb + k0 + bhalf * 16);
    nv0 = src[0]; nv1 = src[1]; nv2 = src[2]; nv3 = src[3];
  };
  auto writeB32 = [&](char* dst){
    union { short8 v; short s[8]; } p0, p1;
    p0.s[0]=(short)f2b(nv0.x); p0.s[1]=(short)f2b(nv0.y); p0.s[2]=(short)f2b(nv0.z); p0.s[3]=(short)f2b(nv0.w);
    p0.s[4]=(short)f2b(nv1.x); p0.s[5]=(short)f2b(nv1.y); p0.s[6]=(short)f2b(nv1.z); p0.s[7]=(short)f2b(nv1.w);
    p1.s[0]=(short)f2b(nv2.x); p1.s[1]=(short)f2b(nv2.y); p1.s[2]=(short)f2b(nv2.z); p1.s[3]=(short)f2b(nv2.w);
    p1.s[4]=(short)f2b(nv3.x); p1.s[5]=(short)f2b(nv3.y); p1.s[6]=(short)f2b(nv3.z); p1.s[7]=(short)f2b(nv3.w);
    char* base = dst + brow * 64;
    *(short8*)(base + (((bhalf * 2 + 0) ^ qb_st) * 16)) = p0.v;
    *(short8*)(base + (((bhalf * 2 + 1) ^ qb_st) * 16)) = p1.v;
  };

  // prologue: fill buffer 0
  stageA(ldsA0, 0);
  if (BF32) { loadB32(0); writeB32(ldsB0); }
  else stageB16(ldsB0, 0);
  __syncthreads();

  char *cA = ldsA0, *cB = ldsB0, *nA = ldsA1, *nB = ldsB1;
  const int nk = K >> 5;
  for (int i = 0; i < nk; i++) {
    const bool more = (i + 1) < nk;
    if (more) {               // issue next-tile loads before compute (T3/T14)
      stageA(nA, (i + 1) << 5);
      if (BF32) loadB32((i + 1) << 5);
      else stageB16(nB, (i + 1) << 5);
    }
    Frag a[4], b[4];
#pragma unroll
    for (int mi = 0; mi < 4; mi++) {
      const int rr = wm * 64 + mi * 16 + lm;
      const int q = qsw(rr);
      const char* p = cA + rr * 64 + (lg & 1) * 8;
      a[mi].h[0] = *(const short4v*)(p + (((lg >> 1) ^ q) * 16));
      a[mi].h[1] = *(const short4v*)(p + ((((lg >> 1) | 2) ^ q) * 16));
    }
#pragma unroll
    for (int ni = 0; ni < 4; ni++) {
      const int rr = wn * 64 + ni * 16 + lm;
      const int q = qsw(rr);
      const char* p = cB + rr * 64 + (lg & 1) * 8;
      b[ni].h[0] = *(const short4v*)(p + (((lg >> 1) ^ q) * 16));
      b[ni].h[1] = *(const short4v*)(p + ((((lg >> 1) | 2) ^ q) * 16));
    }
#pragma unroll
    for (int mi = 0; mi < 4; mi++)
#pragma unroll
      for (int ni = 0; ni < 4; ni++)
        acc[mi][ni] = __builtin_amdgcn_mfma_f32_16x16x32_bf16(a[mi].v, b[ni].v, acc[mi][ni], 0, 0, 0);
    if (BF32 && more) writeB32(nB);    // convert-late: loads had MFMA time to land
    __syncthreads();                   // implicit vmcnt(0)+lgkmcnt(0): next buf ready
    char* t;
    t = cA; cA = nA; nA = t;
    t = cB; cB = nB; nB = t;
  }

  const int bflag = MASKED ? *mflag : 0;
#pragma unroll
  for (int mi = 0; mi < 4; mi++) {
#pragma unroll
    for (int ni = 0; ni < 4; ni++) {
      const int row = m0 + wm * 64 + mi * 16 + lg * 4;
      const int col = n0 + wn * 64 + ni * 16 + lm;
      const float bb = bias ? bias[col] : 0.f;
#pragma unroll
      for (int j = 0; j < 4; j++) {
        float v = acc[mi][ni][j] * alpha + bb;
        if (MASKED) { if (!mask_at(mask, (size_t)(row + j) * ldc + col, bflag)) v = -10000.0f; }
        const size_t o = (size_t)z * sC + (size_t)(row + j) * ldc + col;
        if constexpr (sizeof(OutT) == 2) C[o] = (OutT)f2b(v); else C[o] = (OutT)v;
      }
    }
  }
}

template<typename OutT, bool BF32, bool MASKED, bool SWAP>
__global__ __launch_bounds__(256) void gemm_bt(
    const u16* __restrict__ A, int lda, long sA,
    const void* __restrict__ Bp, int ldb, long sB,
    OutT* __restrict__ C, int ldc, long sC,
    const float* __restrict__ bias,
    const void* __restrict__ mask,
    const int* __restrict__ mflag,
    int K, float alpha)
{
  __shared__ alignas(16) char lds[32768];
  const int m0 = (SWAP ? blockIdx.x : blockIdx.y) * 128;
  const int n0 = (SWAP ? blockIdx.y : blockIdx.x) * 128;
  gemm_core<OutT, BF32, MASKED>(lds, lds + 8192, lds + 16384, lds + 24576,
      m0, n0, blockIdx.z, A, lda, sA, Bp, ldb, sB, C, ldc, sC,
      bias, mask, mflag, K, alpha);
}

// ---------------- persistent LSTM body (r6 structure, smem carved)
__device__ void lstm_body(char* smem,
    const u16* __restrict__ xpre, const u16* __restrict__ whh,
    u16* __restrict__ hbuf, int* __restrict__ flags, int bx)
{
  u16* wlds = (u16*)smem;                       // 64x1024, cell c^(r&7) swizzle
  u16* hlds = (u16*)(smem + 131072);            // 8x1024,  cell c^m swizzle
  float* g_lds = (float*)(smem + 147456);       // [4][8][17]
  u16* hout = (u16*)(smem + 149632);            // [8][16]
  const int tid = threadIdx.x, lane = tid & 63, wid = tid >> 6;
  const int lm = lane & 15, lg = lane >> 4;
  const int gcol0 = bx * 64;

  for (int q = tid; q < 8192; q += 256) {
    const int r = q >> 7, cc = q & 127;
    gload16(whh + (size_t)(gcol0 + r) * 1024 + (size_t)(cc ^ (r & 7)) * 8,
            (char*)wlds + (q & ~63) * 16);
  }

  float c_reg = 0.f;
  const int m_u = lane & 7, u_u = lane >> 3;
  const int rloc = wid * 16 + lm, swb = rloc & 7, swa = lm & 7;
  const u16* wl = wlds + rloc * 1024;
  const u16* hl = hlds + swa * 1024;
  const int gcol = gcol0 + wid * 16 + lm;
  const int pk = tid >> 2, qq = tid & 3;

  for (int t = 0; t < Tdim; t++) {
    u16 xv[4];
#pragma unroll
    for (int j = 0; j < 4; j++) {
      const int m = lg * 4 + j;
      xv[j] = (m < 8) ? xpre[(size_t)(m * Tdim + t) * 4096 + gcol] : (u16)0;
    }
    if (t > 0) {
      int* fl = flags + ((size_t)(t - 1) * 64 + pk) * 16;
      while (__hip_atomic_load(fl, __ATOMIC_RELAXED, __HIP_MEMORY_SCOPE_AGENT) == 0)
        __builtin_amdgcn_s_sleep(1);
      const u64* ps = (const u64*)(hbuf + ((size_t)(t - 1) * 64 + pk) * 128);
#pragma unroll
      for (int mm = 0; mm < 2; mm++) {
        const int m = qq * 2 + mm;
        const u64 v0 = __hip_atomic_load(ps + m * 4 + 0, __ATOMIC_RELAXED, __HIP_MEMORY_SCOPE_AGENT);
        const u64 v1 = __hip_atomic_load(ps + m * 4 + 1, __ATOMIC_RELAXED, __HIP_MEMORY_SCOPE_AGENT);
        const u64 v2 = __hip_atomic_load(ps + m * 4 + 2, __ATOMIC_RELAXED, __HIP_MEMORY_SCOPE_AGENT);
        const u64 v3 = __hip_atomic_load(ps + m * 4 + 3, __ATOMIC_RELAXED, __HIP_MEMORY_SCOPE_AGENT);
        u64x2 a; a[0] = v0; a[1] = v1;
        u64x2 b; b[0] = v2; b[1] = v3;
        *(u64x2*)((char*)hlds + m * 2048 + (((pk * 2 + 0) ^ m) * 16)) = a;
        *(u64x2*)((char*)hlds + m * 2048 + (((pk * 2 + 1) ^ m) * 16)) = b;
      }
    }
    __syncthreads();   // S2: hlds ready (wlds ready at t=0 via barrier drain)

    f32x4 acc;
#pragma unroll
    for (int j = 0; j < 4; j++) acc[j] = bf2f(xv[j]);

    if (t > 0) {
#pragma unroll 4
      for (int kk = 0; kk < 32; kk++) {
        const int c0 = kk * 4 + (lg >> 1);
        const int sub = (lg & 1) * 4;
        Frag a, b;
        a.h[0] = *(const short4v*)(hl + ((c0 ^ swa) << 3) + sub);
        a.h[1] = *(const short4v*)(hl + (((c0 + 2) ^ swa) << 3) + sub);
        b.h[0] = *(const short4v*)(wl + ((c0 ^ swb) << 3) + sub);
        b.h[1] = *(const short4v*)(wl + (((c0 + 2) ^ swb) << 3) + sub);
        acc = __builtin_amdgcn_mfma_f32_16x16x32_bf16(a.v, b.v, acc, 0, 0, 0);
      }
    }
#pragma unroll
    for (int j = 0; j < 4; j++) {
      const int m = lg * 4 + j;
      if (m < 8) g_lds[(wid * 8 + m) * 17 + lm] = acc[j];
    }
    __syncthreads();   // S3: gates ready
    if (lane < 32) {
      const float gi = g_lds[(wid * 8 + m_u) * 17 + u_u * 4 + 0];
      const float gf = g_lds[(wid * 8 + m_u) * 17 + u_u * 4 + 1];
      const float gg = g_lds[(wid * 8 + m_u) * 17 + u_u * 4 + 2];
      const float go = g_lds[(wid * 8 + m_u) * 17 + u_u * 4 + 3];
      const float si = 1.f / (1.f + __expf(-gi));
      const float sf = 1.f / (1.f + __expf(-gf));
      const float so = 1.f / (1.f + __expf(-go));
      const float cn = sf * c_reg + si * ftanh(gg);
      c_reg = cn;
      const float hn = so * ftanh(cn);
      hout[m_u * 16 + wid * 4 + u_u] = f2b(hn);
    }
    __syncthreads();   // S4: hout ready
    if (tid < 16) {
      const int m = tid >> 1, half = tid & 1;
      const u64* src = (const u64*)(hout + m * 16 + half * 8);
      u64* dst = (u64*)(hbuf + ((size_t)t * 64 + bx) * 128 + m * 16 + half * 8);
      __hip_atomic_store(dst,     src[0], __ATOMIC_RELAXED, __HIP_MEMORY_SCOPE_AGENT);
      __hip_atomic_store(dst + 1, src[1], __ATOMIC_RELAXED, __HIP_MEMORY_SCOPE_AGENT);
    }
    asm volatile("s_waitcnt vmcnt(0)" ::: "memory");
    if (tid == 0)
      __hip_atomic_store(flags + ((size_t)t * 64 + bx) * 16, 1, __ATOMIC_RELAXED, __HIP_MEMORY_SCOPE_AGENT);
  }
}

// blocks 0..63: LSTM; blocks 64..191: k = enc @ wk.T + bk (hidden under LSTM)
__global__ __launch_bounds__(256) void lstm_plus(
    const u16* __restrict__ xpre, const u16* __restrict__ whh,
    u16* __restrict__ hbuf, int* __restrict__ flags,
    const u16* __restrict__ encb, const u16* __restrict__ wkb,
    float* __restrict__ klin, const float* __restrict__ bk)
{
  __shared__ alignas(16) char smem[149888];
  if (blockIdx.x < 64) {
    lstm_body(smem, xpre, whh, hbuf, flags, blockIdx.x);
  } else {
    const int idx = blockIdx.x - 64;               // 16 m-tiles x 8 n-tiles
    gemm_core<float, false, false>(smem, smem + 8192, smem + 16384, smem + 24576,
        (idx >> 3) * 128, (idx & 7) * 128, 0,
        encb, 1024, 0, wkb, 1024, 0, klin, 1024, 0, bk, nullptr, nullptr, 1024, 1.f);
  }
}

// hbuf [t][p][m][u16x16] -> cat rows (m*Tdim+t), cols p*16.. (left half of 2048)
__global__ __launch_bounds__(256) void hbuf_cat_k(const u16* __restrict__ hbuf, u16* __restrict__ cat){
  const int t = blockIdx.x, tid = threadIdx.x;
  const int p = tid >> 2, q = tid & 3;
  const u64* src = (const u64*)(hbuf + ((size_t)t * 64 + p) * 128);
#pragma unroll
  for (int m = 0; m < 8; m++) {
    const u64 v = src[m * 4 + q];
    *(u64*)(cat + (size_t)(m * Tdim + t) * 2048 + p * 16 + q * 4) = v;
  }
}

// ---------------- fused prep: all weight/activation converts + embed + flags
__global__ __launch_bounds__(256) void prep_k(
    const float* __restrict__ w_hh, const float* __restrict__ w_ih,
    const float* __restrict__ wo,   const float* __restrict__ wq,
    const float* __restrict__ wk,   const float* __restrict__ wc,
    const float* __restrict__ enc,  const int* __restrict__ ids,
    const float* __restrict__ tok,  const float* __restrict__ pos,
    const float* __restrict__ b_ih, const float* __restrict__ b_hh,
    u16* __restrict__ whhb, u16* __restrict__ wihb, u16* __restrict__ wob,
    u16* __restrict__ wqb,  u16* __restrict__ wkb,  u16* __restrict__ wcb,
    u16* __restrict__ encb, u16* __restrict__ xbf,
    float* __restrict__ biasf, int* __restrict__ flags)
{
  const int b = blockIdx.x, tid = threadIdx.x;
  if (b < 8192) {                        // gate-permuted whh / w_ih rows
    const bool ih = b >= 4096;
    const int r = b & 4095;
    const int p = (r & 3) * Hdim + (r >> 2);
    const float4 v = *(const float4*)((ih ? w_ih : w_hh) + (size_t)p * Hdim + tid * 4);
    u16* op = (ih ? wihb : whhb) + (size_t)r * Hdim + tid * 4;
    op[0] = f2b(v.x); op[1] = f2b(v.y); op[2] = f2b(v.z); op[3] = f2b(v.w);
  } else if (b < 40192) {                // wo (skipped if wob == null)
    if (wob) {
      const size_t i = (size_t)(b - 8192) * 1024 + tid * 4;
      const float4 v = *(const float4*)(wo + i);
      u16* op = wob + i;
      op[0] = f2b(v.x); op[1] = f2b(v.y); op[2] = f2b(v.z); op[3] = f2b(v.w);
    }
  } else if (b < 41216) {
    const size_t i = (size_t)(b - 40192) * 1024 + tid * 4;
    const float4 v = *(const float4*)(wq + i);
    u16* op = wqb + i;
    op[0] = f2b(v.x); op[1] = f2b(v.y); op[2] = f2b(v.z); op[3] = f2b(v.w);
  } else if (b < 42240) {
    const size_t i = (size_t)(b - 41216) * 1024 + tid * 4;
    const float4 v = *(const float4*)(wk + i);
    u16* op = wkb + i;
    op[0] = f2b(v.x); op[1] = f2b(v.y); op[2] = f2b(v.z); op[3] = f2b(v.w);
  } else if (b < 44288) {
    const size_t i = (size_t)(b - 42240) * 1024 + tid * 4;
    const float4 v = *(const float4*)(wc + i);
    u16* op = wcb + i;
    op[0] = f2b(v.x); op[1] = f2b(v.y); op[2] = f2b(v.z); op[3] = f2b(v.w);
  } else if (b < 46336) {
    const size_t i = (size_t)(b - 44288) * 1024 + tid * 4;
    const float4 v = *(const float4*)(enc + i);
    u16* op = encb + i;
    op[0] = f2b(v.x); op[1] = f2b(v.y); op[2] = f2b(v.z); op[3] = f2b(v.w);
  } else if (b < 47360) {                // embed
    const int row = b - 46336;
    const int t = row & (Tdim - 1);
    const int id = ids[row];
    const int h0 = tid * 4;
    const float4 a = *(const float4*)(tok + (size_t)id * Hdim + h0);
    const float4 p = *(const float4*)(pos + (size_t)t * Hdim + h0);
    u16* op = xbf + (size_t)row * Hdim + h0;
    op[0] = f2b(a.x + p.x); op[1] = f2b(a.y + p.y); op[2] = f2b(a.z + p.z); op[3] = f2b(a.w + p.w);
  } else if (b < 47364) {                // bias fold (gate-permuted)
    const int n0 = (b - 47360) * 1024 + tid * 4;
#pragma unroll
    for (int j = 0; j < 4; j++) {
      const int n = n0 + j;
      const int p = (n & 3) * Hdim + (n >> 2);
      biasf[n] = b_ih[p] + b_hh[p];
    }
  } else {                               // flags zero (128 blocks x 1024 ints)
    const int i = (b - 47364) * 1024 + tid * 4;
    int4 z; z.x = 0; z.y = 0; z.z = 0; z.w = 0;
    *(int4*)(flags + i) = z;
  }
}

// ---------------- small kernels (unchanged)
__global__ __launch_bounds__(256) void ln_rows(const float* __restrict__ in, u16* __restrict__ out,
                                               const float* __restrict__ g, const float* __restrict__ be){
  const int row = blockIdx.x, tid = threadIdx.x;
  const int lane = tid & 63, wid = tid >> 6;
  const float4 x = *(const float4*)(in + (size_t)row * Hdim + tid * 4);
  float s = x.x + x.y + x.z + x.w;
  float q = x.x * x.x + x.y * x.y + x.z * x.z + x.w * x.w;
  for (int o = 32; o; o >>= 1) { s += __shfl_down(s, o, 64); q += __shfl_down(q, o, 64); }
  __shared__ float sm[8];
  if (lane == 0) { sm[wid] = s; sm[4 + wid] = q; }
  __syncthreads();
  const float ts = sm[0] + sm[1] + sm[2] + sm[3];
  const float tq = sm[4] + sm[5] + sm[6] + sm[7];
  const float mean = ts * (1.f / Hdim);
  const float var  = tq * (1.f / Hdim) - mean * mean;
  const float r = rsqrtf(var + 1e-5f);
  const int h0 = tid * 4;
  const float4 gv = *(const float4*)(g + h0);
  const float4 bv = *(const float4*)(be + h0);
  u16* op = out + (size_t)row * Hdim + h0;
  op[0] = f2b((x.x - mean) * r * gv.x + bv.x);
  op[1] = f2b((x.y - mean) * r * gv.y + bv.y);
  op[2] = f2b((x.z - mean) * r * gv.z + bv.z);
  op[3] = f2b((x.w - mean) * r * gv.w + bv.w);
}
__global__ __launch_bounds__(256) void softmax_k(const float* __restrict__ sc, const void* __restrict__ am,
                                                 const int* __restrict__ mflag, u16* __restrict__ w){
  const int row = blockIdx.x, tid = threadIdx.x;
  const int lane = tid & 63, wid = tid >> 6;
  const int b = row >> 7;
  const int bflag = *mflag;
  const float v = sc[(size_t)row * Sdim + tid];
  const bool mk = mask_at(am, (size_t)b * Sdim + tid, bflag);
  const float vm = mk ? v : -10000.0f;
  float mx = vm;
  for (int o = 32; o; o >>= 1) mx = fmaxf(mx, __shfl_down(mx, o, 64));
  __shared__ float sm[8];
  if (lane == 0) sm[wid] = mx;
  __syncthreads();
  mx = fmaxf(fmaxf(sm[0], sm[1]), fmaxf(sm[2], sm[3]));
  const float ex = mk ? expf(vm - mx) : 0.f;
  float ss = ex;
  for (int o = 32; o; o >>= 1) ss += __shfl_down(ss, o, 64);
  if (lane == 0) sm[4 + wid] = ss;
  __syncthreads();
  const float tot = sm[4] + sm[5] + sm[6] + sm[7];
  w[(size_t)row * Sdim + tid] = f2b(ex / (tot + 1e-6f));
}
__global__ __launch_bounds__(256) void transp_k(const u16* __restrict__ kn, u16* __restrict__ knT){
  __shared__ u16 tile[64][65];
  const int b = blockIdx.z, h0 = blockIdx.x * 64, s0 = blockIdx.y * 64;
  const u16* src = kn  + (size_t)b * Sdim * Hdim;
  u16* dst       = knT + (size_t)b * Hdim * Sdim;
  for (int e = threadIdx.x; e < 4096; e += 256) {
    const int r = e >> 6, c = e & 63;
    tile[r][c] = src[(size_t)(s0 + r) * Hdim + h0 + c];
  }
  __syncthreads();
  for (int e = threadIdx.x; e < 4096; e += 256) {
    const int hr = e >> 6, scc = e & 63;
    dst[(size_t)(h0 + hr) * Sdim + s0 + scc] = tile[scc][hr];
  }
}

extern "C" void kernel_launch(void* const* d_in, const int* in_sizes, int n_in,
                              void* d_out, int out_size, void* d_ws, size_t ws_size,
                              hipStream_t stream) {
  const int*   input_ids = (const int*)d_in[0];
  const float* enc   = (const float*)d_in[1];
  const void*  pmask = d_in[2];
  const void*  amask = d_in[3];
  const float* tok  = (const float*)d_in[4];
  const float* pos  = (const float*)d_in[5];
  const float* w_ih = (const float*)d_in[6];
  const float* w_hh = (const float*)d_in[7];
  const float* b_ih = (const float*)d_in[8];
  const float* b_hh = (const float*)d_in[9];
  const float* wq = (const float*)d_in[10];
  const float* bq = (const float*)d_in[11];
  const float* wk = (const float*)d_in[12];
  const float* bk = (const float*)d_in[13];
  const float* wc = (const float*)d_in[14];
  const float* bc = (const float*)d_in[15];
  const float* wo = (const float*)d_in[16];
  const float* bo = (const float*)d_in[17];
  const float* g1  = (const float*)d_in[18];
  const float* be1 = (const float*)d_in[19];
  const float* g2  = (const float*)d_in[20];
  const float* be2 = (const float*)d_in[21];
  float* out = (float*)d_out;

  char* ws = (char*)d_ws;
  size_t off = 0;
  auto alloc = [&](size_t b){ size_t o = off; off += (b + 255) & ~(size_t)255; return o; };
  u16*   whhb  = (u16*)  (ws + alloc((size_t)4096 * 1024 * 2));
  u16*   wihb  = (u16*)  (ws + alloc((size_t)4096 * 1024 * 2));
  u16*   wqb   = (u16*)  (ws + alloc((size_t)1024 * 1024 * 2));
  u16*   wkb   = (u16*)  (ws + alloc((size_t)1024 * 1024 * 2));
  u16*   wcb   = (u16*)  (ws + alloc((size_t)1024 * 2048 * 2));
  float* biasf = (float*)(ws + alloc(4096 * 4));
  u16*   xbf   = (u16*)  (ws + alloc((size_t)1024 * 1024 * 2));
  u16*   encb  = (u16*)  (ws + alloc((size_t)2048 * 1024 * 2));
  u16*   xpre  = (u16*)  (ws + alloc((size_t)1024 * 4096 * 2));
  u16*   hbuf  = (u16*)  (ws + alloc((size_t)Tdim * 64 * 128 * 2));
  u16*   cat   = (u16*)  (ws + alloc((size_t)1024 * 2048 * 2));
  float* qlin  = (float*)(ws + alloc((size_t)1024 * 1024 * 4));
  u16*   qn    = (u16*)  (ws + alloc((size_t)1024 * 1024 * 2));
  float* klin  = (float*)(ws + alloc((size_t)2048 * 1024 * 4));
  u16*   kn    = (u16*)  (ws + alloc((size_t)2048 * 1024 * 2));
  u16*   knT   = (u16*)  (ws + alloc((size_t)2048 * 1024 * 2));
  float* scores= (float*)(ws + alloc((size_t)8 * 128 * 256 * 4));
  u16*   attw  = (u16*)  (ws + alloc((size_t)8 * 128 * 256 * 2));
  float* hlin  = (float*)(ws + alloc((size_t)1024 * 1024 * 4));
  u16*   hid   = (u16*)  (ws + alloc((size_t)1024 * 1024 * 2));
  int*   bflag = (int*)  (ws + alloc(256));
  int*   flags = (int*)  (ws + alloc((size_t)Tdim * 64 * 16 * 4));
  u16*   wob   = (u16*)  (ws + alloc((size_t)Vdim * Hdim * 2));
  const bool haveWob = off <= ws_size;
  if (!haveWob) wob = nullptr;
  (void)in_sizes; (void)n_in; (void)out_size;

  detect_bool_k<<<1, 256, 0, stream>>>((const unsigned char*)pmask, bflag);
  prep_k<<<47492, 256, 0, stream>>>(w_hh, w_ih, wo, wq, wk, wc, enc, input_ids,
      tok, pos, b_ih, b_hh, whhb, wihb, wob, wqb, wkb, wcb, encb, xbf, biasf, flags);

  // x_pre = x @ w_ih_perm.T + (b_ih + b_hh)   -> bf16 (1024 x 4096)
  gemm_bt<u16, false, false, false><<<dim3(32, 8, 1), 256, 0, stream>>>(
      xbf, 1024, 0, wihb, 1024, 0, xpre, 4096, 0, biasf, nullptr, nullptr, 1024, 1.f);

  // LSTM (blocks 0-63) + k-projection (blocks 64-191) in one launch
  lstm_plus<<<192, 256, 0, stream>>>(xpre, whhb, hbuf, flags, encb, wkb, klin, bk);
  hbuf_cat_k<<<Tdim, 256, 0, stream>>>(hbuf, cat);

  // q = lstm_out @ wq.T + bq ; LN(g1,be1)
  gemm_bt<float, false, false, false><<<dim3(8, 8, 1), 256, 0, stream>>>(
      cat, 2048, 0, wqb, 1024, 0, qlin, 1024, 0, bq, nullptr, nullptr, 1024, 1.f);
  ln_rows<<<1024, 256, 0, stream>>>(qlin, qn, g1, be1);
  ln_rows<<<2048, 256, 0, stream>>>(klin, kn, g1, be1);
  transp_k<<<dim3(16, 4, 8), 256, 0, stream>>>(kn, knT);

  // scores = qn @ kn^T * scale   (batched over 8)
  gemm_bt<float, false, false, false><<<dim3(2, 1, 8), 256, 0, stream>>>(
      qn, 1024, 131072, kn, 1024, 262144, scores, 256, 32768, nullptr, nullptr, nullptr, 1024, 0.015625f);
  softmax_k<<<1024, 256, 0, stream>>>(scores, amask, bflag, attw);
  // ctx = w @ kn  -> right half of cat   (batched)
  gemm_bt<u16, false, false, false><<<dim3(8, 1, 8), 256, 0, stream>>>(
      attw, 256, 32768, knT, 256, 262144, cat + 1024, 2048, 262144, nullptr, nullptr, nullptr, 256, 1.f);

  // hidden = LN( cat @ wc.T + bc ; g2,be2 )
  gemm_bt<float, false, false, false><<<dim3(8, 8, 1), 256, 0, stream>>>(
      cat, 2048, 0, wcb, 2048, 0, hlin, 1024, 0, bc, nullptr, nullptr, 2048, 1.f);
  ln_rows<<<1024, 256, 0, stream>>>(hlin, hid, g2, be2);

  // logits = hidden @ wo.T + bo, masked — SWAP grid: co-resident blocks share B-tile
  if (wob)
    gemm_bt<float, false, true, true><<<dim3(8, 250, 1), 256, 0, stream>>>(
        hid, 1024, 0, wob, 1024, 0, out, 32000, 0, bo, pmask, bflag, 1024, 1.f);
  else
    gemm_bt<float, true, true, true><<<dim3(8, 250, 1), 256, 0, stream>>>(
        hid, 1024, 0, wo, 1024, 0, out, 32000, 0, bo, pmask, bflag, 1024, 1.f);
}

// Round 8
// 957.791 us; speedup vs baseline: 3.3637x; 1.0711x over previous
//
#include <hip/hip_runtime.h>
#include <cstdint>
#include <cstddef>

#define Bdim 8
#define Tdim 128
#define Sdim 256
#define Hdim 1024
#define Vdim 32000
#define SENT 0xFFFFFFFFFFFFFFFFULL

typedef unsigned short u16;
typedef unsigned long long u64;
typedef __attribute__((ext_vector_type(8))) short short8;
typedef __attribute__((ext_vector_type(4))) short short4v;
typedef __attribute__((ext_vector_type(4))) float f32x4;
typedef __attribute__((ext_vector_type(2))) unsigned long long u64x2;

union Frag { short8 v; short4v h[2]; };

__device__ __forceinline__ float bf2f(u16 u){
  union { unsigned int i; float f; } x; x.i = ((unsigned int)u) << 16; return x.f;
}
__device__ __forceinline__ u16 f2b(float f){
  union { float f; unsigned int u; } x; x.f = f;
  unsigned int r = x.u + 0x7FFFu + ((x.u >> 16) & 1u);  // RNE
  return (u16)(r >> 16);
}
__device__ __forceinline__ float ftanh(float x){
  x = fminf(10.f, fmaxf(-10.f, x));
  const float e = __expf(2.f * x);
  return (e - 1.f) / (e + 1.f);
}

__device__ __forceinline__ void gload16(const void* g, void* l){
  __builtin_amdgcn_global_load_lds((const __attribute__((address_space(1))) unsigned int*)g,
                                   (__attribute__((address_space(3))) unsigned int*)l, 16, 0, 0);
}

// 16B-cell swizzle for 64B-wide LDS tile rows (4 cells/row)
__device__ __forceinline__ int qsw(int r){ return (r + (r >> 2)) & 3; }

__device__ __forceinline__ u64 aload(const u64* p){
  return __hip_atomic_load(p, __ATOMIC_RELAXED, __HIP_MEMORY_SCOPE_AGENT);
}
__device__ __forceinline__ void astore(u64* p, u64 v){
  __hip_atomic_store(p, v, __ATOMIC_RELAXED, __HIP_MEMORY_SCOPE_AGENT);
}

__global__ __launch_bounds__(256) void detect_bool_k(const unsigned char* __restrict__ p, int* __restrict__ flag){
  __shared__ int s;
  if (threadIdx.x == 0) s = 0;
  __syncthreads();
  int loc = 0;
  for (int i = threadIdx.x; i < 65536; i += 256)
    if ((i & 3) && p[i]) loc = 1;
  if (loc) atomicOr(&s, 1);
  __syncthreads();
  if (threadIdx.x == 0) flag[0] = s;
}

__device__ __forceinline__ bool mask_at(const void* m, size_t idx, int byteflag){
  if (byteflag) return ((const unsigned char*)m)[idx] != 0;
  return ((const int*)m)[idx] != 0;
}

// ---------------- 2-phase double-buffered GEMM core
// MASK: 0 none, 1 runtime-dtype mask via mflag, 2 byte mask.
template<typename OutT, bool BF32, int MASK>
__device__ __forceinline__ void gemm_core(
    char* ldsA0, char* ldsB0, char* ldsA1, char* ldsB1,
    int m0, int n0, int z,
    const u16* __restrict__ A, int lda, long sA,
    const void* __restrict__ Bp, int ldb, long sB,
    OutT* __restrict__ C, int ldc, long sC,
    const float* __restrict__ bias,
    const void* __restrict__ mask,
    const int* __restrict__ mflag,
    int K, float alpha)
{
  const int tid  = threadIdx.x;
  const int lane = tid & 63, wid = tid >> 6;
  const int lm = lane & 15, lg = lane >> 4;
  const int wm = wid >> 1, wn = wid & 1;            // 2x2 waves, 64x64 each
  const char* Ab = (const char*)(A + (size_t)z * sA);

  f32x4 acc[4][4];
#pragma unroll
  for (int i = 0; i < 4; i++)
#pragma unroll
    for (int j = 0; j < 4; j++) acc[i][j] = (f32x4){0.f, 0.f, 0.f, 0.f};

  const int brow = tid >> 1, bhalf = tid & 1;       // BF32 staging coords
  const int qb_st = qsw(brow);

  auto stageA = [&](char* dst, int k0){
    const char* ga = Ab + ((size_t)m0 * lda + k0) * 2;
    const int f0 = tid, f1 = tid + 256;
    const int r0 = f0 >> 2, r1 = f1 >> 2;
    gload16(ga + (size_t)r0 * (lda * 2) + ((f0 & 3) ^ qsw(r0)) * 16, dst + (f0 & ~63) * 16);
    gload16(ga + (size_t)r1 * (lda * 2) + ((f1 & 3) ^ qsw(r1)) * 16, dst + (f1 & ~63) * 16);
  };
  auto stageB16 = [&](char* dst, int k0){
    const char* gb = (const char*)((const u16*)Bp + (size_t)z * sB) + ((size_t)n0 * ldb + k0) * 2;
    const int f0 = tid, f1 = tid + 256;
    const int r0 = f0 >> 2, r1 = f1 >> 2;
    gload16(gb + (size_t)r0 * (ldb * 2) + ((f0 & 3) ^ qsw(r0)) * 16, dst + (f0 & ~63) * 16);
    gload16(gb + (size_t)r1 * (ldb * 2) + ((f1 & 3) ^ qsw(r1)) * 16, dst + (f1 & ~63) * 16);
  };

  float4 nv0, nv1, nv2, nv3;                        // BF32 in-flight tile
  auto loadB32 = [&](int k0){
    const float* Bf = (const float*)Bp + (size_t)z * sB;
    const float4* src = (const float4*)(Bf + (size_t)(n0 + brow) * ldb + k0 + bhalf * 16);
    nv0 = src[0]; nv1 = src[1]; nv2 = src[2]; nv3 = src[3];
  };
  auto writeB32 = [&](char* dst){
    union { short8 v; short s[8]; } p0, p1;
    p0.s[0]=(short)f2b(nv0.x); p0.s[1]=(short)f2b(nv0.y); p0.s[2]=(short)f2b(nv0.z); p0.s[3]=(short)f2b(nv0.w);
    p0.s[4]=(short)f2b(nv1.x); p0.s[5]=(short)f2b(nv1.y); p0.s[6]=(short)f2b(nv1.z); p0.s[7]=(short)f2b(nv1.w);
    p1.s[0]=(short)f2b(nv2.x); p1.s[1]=(short)f2b(nv2.y); p1.s[2]=(short)f2b(nv2.z); p1.s[3]=(short)f2b(nv2.w);
    p1.s[4]=(short)f2b(nv3.x); p1.s[5]=(short)f2b(nv3.y); p1.s[6]=(short)f2b(nv3.z); p1.s[7]=(short)f2b(nv3.w);
    char* base = dst + brow * 64;
    *(short8*)(base + (((bhalf * 2 + 0) ^ qb_st) * 16)) = p0.v;
    *(short8*)(base + (((bhalf * 2 + 1) ^ qb_st) * 16)) = p1.v;
  };

  stageA(ldsA0, 0);
  if (BF32) { loadB32(0); writeB32(ldsB0); }
  else stageB16(ldsB0, 0);
  __syncthreads();

  char *cA = ldsA0, *cB = ldsB0, *nA = ldsA1, *nB = ldsB1;
  const int nk = K >> 5;
  for (int i = 0; i < nk; i++) {
    const bool more = (i + 1) < nk;
    if (more) {               // issue next-tile loads before compute (T3/T14)
      stageA(nA, (i + 1) << 5);
      if (BF32) loadB32((i + 1) << 5);
      else stageB16(nB, (i + 1) << 5);
    }
    Frag a[4], b[4];
#pragma unroll
    for (int mi = 0; mi < 4; mi++) {
      const int rr = wm * 64 + mi * 16 + lm;
      const int q = qsw(rr);
      const char* p = cA + rr * 64 + (lg & 1) * 8;
      a[mi].h[0] = *(const short4v*)(p + (((lg >> 1) ^ q) * 16));
      a[mi].h[1] = *(const short4v*)(p + ((((lg >> 1) | 2) ^ q) * 16));
    }
#pragma unroll
    for (int ni = 0; ni < 4; ni++) {
      const int rr = wn * 64 + ni * 16 + lm;
      const int q = qsw(rr);
      const char* p = cB + rr * 64 + (lg & 1) * 8;
      b[ni].h[0] = *(const short4v*)(p + (((lg >> 1) ^ q) * 16));
      b[ni].h[1] = *(const short4v*)(p + ((((lg >> 1) | 2) ^ q) * 16));
    }
#pragma unroll
    for (int mi = 0; mi < 4; mi++)
#pragma unroll
      for (int ni = 0; ni < 4; ni++)
        acc[mi][ni] = __builtin_amdgcn_mfma_f32_16x16x32_bf16(a[mi].v, b[ni].v, acc[mi][ni], 0, 0, 0);
    if (BF32 && more) writeB32(nB);    // convert-late
    __syncthreads();
    char* t;
    t = cA; cA = nA; nA = t;
    t = cB; cB = nB; nB = t;
  }

  const int bflag = (MASK == 1) ? *mflag : 0;
#pragma unroll
  for (int mi = 0; mi < 4; mi++) {
#pragma unroll
    for (int ni = 0; ni < 4; ni++) {
      const int row = m0 + wm * 64 + mi * 16 + lg * 4;
      const int col = n0 + wn * 64 + ni * 16 + lm;
      const float bb = bias ? bias[col] : 0.f;
#pragma unroll
      for (int j = 0; j < 4; j++) {
        float v = acc[mi][ni][j] * alpha + bb;
        const size_t midx = (size_t)(row + j) * ldc + col;
        if (MASK == 1) { if (!mask_at(mask, midx, bflag)) v = -10000.0f; }
        if (MASK == 2) { if (!((const unsigned char*)mask)[midx]) v = -10000.0f; }
        const size_t o = (size_t)z * sC + midx;
        if constexpr (sizeof(OutT) == 2) C[o] = (OutT)f2b(v); else C[o] = (OutT)v;
      }
    }
  }
}

template<typename OutT, bool BF32, int MASK, bool SWAP>
__global__ __launch_bounds__(256) void gemm_bt(
    const u16* __restrict__ A, int lda, long sA,
    const void* __restrict__ Bp, int ldb, long sB,
    OutT* __restrict__ C, int ldc, long sC,
    const float* __restrict__ bias,
    const void* __restrict__ mask,
    const int* __restrict__ mflag,
    int K, float alpha)
{
  __shared__ alignas(16) char lds[32768];
  const int m0 = (SWAP ? blockIdx.x : blockIdx.y) * 128;
  const int n0 = (SWAP ? blockIdx.y : blockIdx.x) * 128;
  gemm_core<OutT, BF32, MASK>(lds, lds + 8192, lds + 16384, lds + 24576,
      m0, n0, blockIdx.z, A, lda, sA, Bp, ldb, sB, C, ldc, sC,
      bias, mask, mflag, K, alpha);
}

// ---------------- persistent LSTM body: value-polled dataflow sync
// hbuf pre-filled with SENT. Producers store packets (no fence, no flag);
// consumers atomic-load packet words until != SENT — detect == data arrival.
// h = so*tanh(cn) of finite gates is always finite -> f2b never yields 0xFFFF.
__device__ void lstm_body(char* smem,
    const u16* __restrict__ xpre, const u16* __restrict__ whh,
    u16* __restrict__ hbuf, int bx)
{
  u16* wlds = (u16*)smem;                       // 64x1024, cell c^(r&7) swizzle
  u16* hlds = (u16*)(smem + 131072);            // 8x1024,  cell c^m swizzle
  float* g_lds = (float*)(smem + 147456);       // [4][8][17]
  u16* hout = (u16*)(smem + 149632);            // [8][16]
  const int tid = threadIdx.x, lane = tid & 63, wid = tid >> 6;
  const int lm = lane & 15, lg = lane >> 4;
  const int gcol0 = bx * 64;

  for (int q = tid; q < 8192; q += 256) {
    const int r = q >> 7, cc = q & 127;
    gload16(whh + (size_t)(gcol0 + r) * 1024 + (size_t)(cc ^ (r & 7)) * 8,
            (char*)wlds + (q & ~63) * 16);
  }

  float c_reg = 0.f;
  const int m_u = lane & 7, u_u = lane >> 3;
  const int rloc = wid * 16 + lm, swb = rloc & 7, swa = lm & 7;
  const u16* wl = wlds + rloc * 1024;
  const u16* hl = hlds + swa * 1024;
  const int gcol = gcol0 + wid * 16 + lm;
  const int pk = tid >> 2, qq = tid & 3;            // consumer: packet, quarter

  for (int t = 0; t < Tdim; t++) {
    u16 xv[4];
#pragma unroll
    for (int j = 0; j < 4; j++) {
      const int m = lg * 4 + j;
      xv[j] = (m < 8) ? xpre[(size_t)(m * Tdim + t) * 4096 + gcol] : (u16)0;
    }
    if (t > 0) {
      const u64* ps = (const u64*)(hbuf + ((size_t)(t - 1) * 64 + pk) * 128) + qq * 8;
      u64 w0=SENT,w1=SENT,w2=SENT,w3=SENT,w4=SENT,w5=SENT,w6=SENT,w7=SENT;
      for (;;) {
        if (w0 == SENT) w0 = aload(ps + 0);
        if (w1 == SENT) w1 = aload(ps + 1);
        if (w2 == SENT) w2 = aload(ps + 2);
        if (w3 == SENT) w3 = aload(ps + 3);
        if (w4 == SENT) w4 = aload(ps + 4);
        if (w5 == SENT) w5 = aload(ps + 5);
        if (w6 == SENT) w6 = aload(ps + 6);
        if (w7 == SENT) w7 = aload(ps + 7);
        if (w0 != SENT && w1 != SENT && w2 != SENT && w3 != SENT &&
            w4 != SENT && w5 != SENT && w6 != SENT && w7 != SENT) break;
        __builtin_amdgcn_s_sleep(1);
      }
      {
        const int m = qq * 2;
        u64x2 a; a[0] = w0; a[1] = w1;
        u64x2 b; b[0] = w2; b[1] = w3;
        *(u64x2*)((char*)hlds + m * 2048 + (((pk * 2 + 0) ^ m) * 16)) = a;
        *(u64x2*)((char*)hlds + m * 2048 + (((pk * 2 + 1) ^ m) * 16)) = b;
      }
      {
        const int m = qq * 2 + 1;
        u64x2 a; a[0] = w4; a[1] = w5;
        u64x2 b; b[0] = w6; b[1] = w7;
        *(u64x2*)((char*)hlds + m * 2048 + (((pk * 2 + 0) ^ m) * 16)) = a;
        *(u64x2*)((char*)hlds + m * 2048 + (((pk * 2 + 1) ^ m) * 16)) = b;
      }
    }
    __syncthreads();   // S2: hlds ready

    f32x4 acc;
#pragma unroll
    for (int j = 0; j < 4; j++) acc[j] = bf2f(xv[j]);

    if (t > 0) {
#pragma unroll 4
      for (int kk = 0; kk < 32; kk++) {
        const int c0 = kk * 4 + (lg >> 1);
        const int sub = (lg & 1) * 4;
        Frag a, b;
        a.h[0] = *(const short4v*)(hl + ((c0 ^ swa) << 3) + sub);
        a.h[1] = *(const short4v*)(hl + (((c0 + 2) ^ swa) << 3) + sub);
        b.h[0] = *(const short4v*)(wl + ((c0 ^ swb) << 3) + sub);
        b.h[1] = *(const short4v*)(wl + (((c0 + 2) ^ swb) << 3) + sub);
        acc = __builtin_amdgcn_mfma_f32_16x16x32_bf16(a.v, b.v, acc, 0, 0, 0);
      }
    }
#pragma unroll
    for (int j = 0; j < 4; j++) {
      const int m = lg * 4 + j;
      if (m < 8) g_lds[(wid * 8 + m) * 17 + lm] = acc[j];
    }
    __syncthreads();   // S3: gates ready
    if (lane < 32) {
      const float gi = g_lds[(wid * 8 + m_u) * 17 + u_u * 4 + 0];
      const float gf = g_lds[(wid * 8 + m_u) * 17 + u_u * 4 + 1];
      const float gg = g_lds[(wid * 8 + m_u) * 17 + u_u * 4 + 2];
      const float go = g_lds[(wid * 8 + m_u) * 17 + u_u * 4 + 3];
      const float si = 1.f / (1.f + __expf(-gi));
      const float sf = 1.f / (1.f + __expf(-gf));
      const float so = 1.f / (1.f + __expf(-go));
      const float cn = sf * c_reg + si * ftanh(gg);
      c_reg = cn;
      const float hn = so * ftanh(cn);
      hout[m_u * 16 + wid * 4 + u_u] = f2b(hn);
    }
    __syncthreads();   // S4: hout ready
    if (tid < 16) {
      const int m = tid >> 1, half = tid & 1;
      const u64* src = (const u64*)(hout + m * 16 + half * 8);
      u64* dst = (u64*)(hbuf + ((size_t)t * 64 + bx) * 128 + m * 16 + half * 8);
      astore(dst, src[0]);
      astore(dst + 1, src[1]);
    }
    // no vmcnt, no flag: consumers detect the data itself
  }
}

// blocks 0..63: LSTM; 64..191: k-projection GEMM; 192..255: streamers
// (wo fp32->bf16 convert + pattern_mask byte-pack) hidden under the LSTM.
__global__ __launch_bounds__(256) void lstm_plus(
    const u16* __restrict__ xpre, const u16* __restrict__ whh,
    u16* __restrict__ hbuf,
    const u16* __restrict__ encb, const u16* __restrict__ wkb,
    float* __restrict__ klin, const float* __restrict__ bk,
    const float* __restrict__ wo, u16* __restrict__ wob,
    const void* __restrict__ pmask, unsigned char* __restrict__ pmaskb,
    const int* __restrict__ bflag)
{
  __shared__ alignas(16) char smem[149888];
  const int bx = blockIdx.x;
  if (bx < 64) {
    lstm_body(smem, xpre, whh, hbuf, bx);
  } else if (bx < 192) {
    const int idx = bx - 64;               // 16 m-tiles x 8 n-tiles
    gemm_core<float, false, 0>(smem, smem + 8192, smem + 16384, smem + 24576,
        (idx >> 3) * 128, (idx & 7) * 128, 0,
        encb, 1024, 0, wkb, 1024, 0, klin, 1024, 0, bk, nullptr, nullptr, 1024, 1.f);
  } else {
    const int s = bx - 192;                // 0..63
    const int tid = threadIdx.x;
    if (wob) {
      for (int r = s; r < Vdim; r += 64) {
        const size_t i = (size_t)r * 1024 + tid * 4;
        const float4 v = *(const float4*)(wo + i);
        u16* op = wob + i;
        op[0] = f2b(v.x); op[1] = f2b(v.y); op[2] = f2b(v.z); op[3] = f2b(v.w);
      }
    }
    if (pmaskb) {
      const int bfl = *bflag;
      const size_t total = (size_t)Bdim * Tdim * Vdim;       // 32,768,000
      const size_t nthr = 64 * 256;
      if (bfl == 0) {     // int32 bools -> bytes
        for (size_t i = ((size_t)s * 256 + tid) * 4; i < total; i += nthr * 4) {
          const int4 v = *(const int4*)((const int*)pmask + i);
          uchar4 o;
          o.x = v.x ? 1 : 0; o.y = v.y ? 1 : 0; o.z = v.z ? 1 : 0; o.w = v.w ? 1 : 0;
          *(uchar4*)(pmaskb + i) = o;
        }
      } else {            // already bytes -> copy 16B
        for (size_t i = ((size_t)s * 256 + tid) * 16; i < total; i += nthr * 16) {
          *(int4*)(pmaskb + i) = *(const int4*)((const unsigned char*)pmask + i);
        }
      }
    }
  }
}

// hbuf [t][p][m][u16x16] -> cat rows (m*Tdim+t), cols p*16.. (left half of 2048)
__global__ __launch_bounds__(256) void hbuf_cat_k(const u16* __restrict__ hbuf, u16* __restrict__ cat){
  const int t = blockIdx.x, tid = threadIdx.x;
  const int p = tid >> 2, q = tid & 3;
  const u64* src = (const u64*)(hbuf + ((size_t)t * 64 + p) * 128);
#pragma unroll
  for (int m = 0; m < 8; m++) {
    const u64 v = src[m * 4 + q];
    *(u64*)(cat + (size_t)(m * Tdim + t) * 2048 + p * 16 + q * 4) = v;
  }
}

// ---------------- fused prep: weight converts + embed + bias + hbuf sentinel
__global__ __launch_bounds__(256) void prep_k(
    const float* __restrict__ w_hh, const float* __restrict__ w_ih,
    const float* __restrict__ wq,   const float* __restrict__ wk,
    const float* __restrict__ wc,   const float* __restrict__ enc,
    const int* __restrict__ ids,
    const float* __restrict__ tok,  const float* __restrict__ pos,
    const float* __restrict__ b_ih, const float* __restrict__ b_hh,
    u16* __restrict__ whhb, u16* __restrict__ wihb,
    u16* __restrict__ wqb,  u16* __restrict__ wkb,  u16* __restrict__ wcb,
    u16* __restrict__ encb, u16* __restrict__ xbf,
    float* __restrict__ biasf, u64* __restrict__ hbuf)
{
  const int b = blockIdx.x, tid = threadIdx.x;
  if (b < 8192) {                        // gate-permuted whh / w_ih rows
    const bool ih = b >= 4096;
    const int r = b & 4095;
    const int p = (r & 3) * Hdim + (r >> 2);
    const float4 v = *(const float4*)((ih ? w_ih : w_hh) + (size_t)p * Hdim + tid * 4);
    u16* op = (ih ? wihb : whhb) + (size_t)r * Hdim + tid * 4;
    op[0] = f2b(v.x); op[1] = f2b(v.y); op[2] = f2b(v.z); op[3] = f2b(v.w);
  } else if (b < 9216) {
    const size_t i = (size_t)(b - 8192) * 1024 + tid * 4;
    const float4 v = *(const float4*)(wq + i);
    u16* op = wqb + i;
    op[0] = f2b(v.x); op[1] = f2b(v.y); op[2] = f2b(v.z); op[3] = f2b(v.w);
  } else if (b < 10240) {
    const size_t i = (size_t)(b - 9216) * 1024 + tid * 4;
    const float4 v = *(const float4*)(wk + i);
    u16* op = wkb + i;
    op[0] = f2b(v.x); op[1] = f2b(v.y); op[2] = f2b(v.z); op[3] = f2b(v.w);
  } else if (b < 12288) {
    const size_t i = (size_t)(b - 10240) * 1024 + tid * 4;
    const float4 v = *(const float4*)(wc + i);
    u16* op = wcb + i;
    op[0] = f2b(v.x); op[1] = f2b(v.y); op[2] = f2b(v.z); op[3] = f2b(v.w);
  } else if (b < 14336) {
    const size_t i = (size_t)(b - 12288) * 1024 + tid * 4;
    const float4 v = *(const float4*)(enc + i);
    u16* op = encb + i;
    op[0] = f2b(v.x); op[1] = f2b(v.y); op[2] = f2b(v.z); op[3] = f2b(v.w);
  } else if (b < 15360) {                // embed
    const int row = b - 14336;
    const int t = row & (Tdim - 1);
    const int id = ids[row];
    const int h0 = tid * 4;
    const float4 a = *(const float4*)(tok + (size_t)id * Hdim + h0);
    const float4 p = *(const float4*)(pos + (size_t)t * Hdim + h0);
    u16* op = xbf + (size_t)row * Hdim + h0;
    op[0] = f2b(a.x + p.x); op[1] = f2b(a.y + p.y); op[2] = f2b(a.z + p.z); op[3] = f2b(a.w + p.w);
  } else if (b < 15364) {                // bias fold (gate-permuted)
    const int n0 = (b - 15360) * 1024 + tid * 4;
#pragma unroll
    for (int j = 0; j < 4; j++) {
      const int n = n0 + j;
      const int p = (n & 3) * Hdim + (n >> 2);
      biasf[n] = b_ih[p] + b_hh[p];
    }
  } else {                               // hbuf sentinel: 256 blocks x 256 thr x 4 u64
    const size_t i = ((size_t)(b - 15364) * 256 + tid) * 4;
    u64x2 s2; s2[0] = SENT; s2[1] = SENT;
    *(u64x2*)(hbuf + i)     = s2;
    *(u64x2*)(hbuf + i + 2) = s2;
  }
}

// ---------------- small kernels
__global__ __launch_bounds__(256) void ln_rows(const float* __restrict__ in, u16* __restrict__ out,
                                               const float* __restrict__ g, const float* __restrict__ be){
  const int row = blockIdx.x, tid = threadIdx.x;
  const int lane = tid & 63, wid = tid >> 6;
  const float4 x = *(const float4*)(in + (size_t)row * Hdim + tid * 4);
  float s = x.x + x.y + x.z + x.w;
  float q = x.x * x.x + x.y * x.y + x.z * x.z + x.w * x.w;
  for (int o = 32; o; o >>= 1) { s += __shfl_down(s, o, 64); q += __shfl_down(q, o, 64); }
  __shared__ float sm[8];
  if (lane == 0) { sm[wid] = s; sm[4 + wid] = q; }
  __syncthreads();
  const float ts = sm[0] + sm[1] + sm[2] + sm[3];
  const float tq = sm[4] + sm[5] + sm[6] + sm[7];
  const float mean = ts * (1.f / Hdim);
  const float var  = tq * (1.f / Hdim) - mean * mean;
  const float r = rsqrtf(var + 1e-5f);
  const int h0 = tid * 4;
  const float4 gv = *(const float4*)(g + h0);
  const float4 bv = *(const float4*)(be + h0);
  u16* op = out + (size_t)row * Hdim + h0;
  op[0] = f2b((x.x - mean) * r * gv.x + bv.x);
  op[1] = f2b((x.y - mean) * r * gv.y + bv.y);
  op[2] = f2b((x.z - mean) * r * gv.z + bv.z);
  op[3] = f2b((x.w - mean) * r * gv.w + bv.w);
}
__global__ __launch_bounds__(256) void softmax_k(const float* __restrict__ sc, const void* __restrict__ am,
                                                 const int* __restrict__ mflag, u16* __restrict__ w){
  const int row = blockIdx.x, tid = threadIdx.x;
  const int lane = tid & 63, wid = tid >> 6;
  const int b = row >> 7;
  const int bflag = *mflag;
  const float v = sc[(size_t)row * Sdim + tid];
  const bool mk = mask_at(am, (size_t)b * Sdim + tid, bflag);
  const float vm = mk ? v : -10000.0f;
  float mx = vm;
  for (int o = 32; o; o >>= 1) mx = fmaxf(mx, __shfl_down(mx, o, 64));
  __shared__ float sm[8];
  if (lane == 0) sm[wid] = mx;
  __syncthreads();
  mx = fmaxf(fmaxf(sm[0], sm[1]), fmaxf(sm[2], sm[3]));
  const float ex = mk ? expf(vm - mx) : 0.f;
  float ss = ex;
  for (int o = 32; o; o >>= 1) ss += __shfl_down(ss, o, 64);
  if (lane == 0) sm[4 + wid] = ss;
  __syncthreads();
  const float tot = sm[4] + sm[5] + sm[6] + sm[7];
  w[(size_t)row * Sdim + tid] = f2b(ex / (tot + 1e-6f));
}
__global__ __launch_bounds__(256) void transp_k(const u16* __restrict__ kn, u16* __restrict__ knT){
  __shared__ u16 tile[64][65];
  const int b = blockIdx.z, h0 = blockIdx.x * 64, s0 = blockIdx.y * 64;
  const u16* src = kn  + (size_t)b * Sdim * Hdim;
  u16* dst       = knT + (size_t)b * Hdim * Sdim;
  for (int e = threadIdx.x; e < 4096; e += 256) {
    const int r = e >> 6, c = e & 63;
    tile[r][c] = src[(size_t)(s0 + r) * Hdim + h0 + c];
  }
  __syncthreads();
  for (int e = threadIdx.x; e < 4096; e += 256) {
    const int hr = e >> 6, scc = e & 63;
    dst[(size_t)(h0 + hr) * Sdim + s0 + scc] = tile[scc][hr];
  }
}

extern "C" void kernel_launch(void* const* d_in, const int* in_sizes, int n_in,
                              void* d_out, int out_size, void* d_ws, size_t ws_size,
                              hipStream_t stream) {
  const int*   input_ids = (const int*)d_in[0];
  const float* enc   = (const float*)d_in[1];
  const void*  pmask = d_in[2];
  const void*  amask = d_in[3];
  const float* tok  = (const float*)d_in[4];
  const float* pos  = (const float*)d_in[5];
  const float* w_ih = (const float*)d_in[6];
  const float* w_hh = (const float*)d_in[7];
  const float* b_ih = (const float*)d_in[8];
  const float* b_hh = (const float*)d_in[9];
  const float* wq = (const float*)d_in[10];
  const float* bq = (const float*)d_in[11];
  const float* wk = (const float*)d_in[12];
  const float* bk = (const float*)d_in[13];
  const float* wc = (const float*)d_in[14];
  const float* bc = (const float*)d_in[15];
  const float* wo = (const float*)d_in[16];
  const float* bo = (const float*)d_in[17];
  const float* g1  = (const float*)d_in[18];
  const float* be1 = (const float*)d_in[19];
  const float* g2  = (const float*)d_in[20];
  const float* be2 = (const float*)d_in[21];
  float* out = (float*)d_out;

  char* ws = (char*)d_ws;
  size_t off = 0;
  auto alloc = [&](size_t b){ size_t o = off; off += (b + 255) & ~(size_t)255; return o; };
  u16*   whhb  = (u16*)  (ws + alloc((size_t)4096 * 1024 * 2));
  u16*   wihb  = (u16*)  (ws + alloc((size_t)4096 * 1024 * 2));
  u16*   wqb   = (u16*)  (ws + alloc((size_t)1024 * 1024 * 2));
  u16*   wkb   = (u16*)  (ws + alloc((size_t)1024 * 1024 * 2));
  u16*   wcb   = (u16*)  (ws + alloc((size_t)1024 * 2048 * 2));
  float* biasf = (float*)(ws + alloc(4096 * 4));
  u16*   xbf   = (u16*)  (ws + alloc((size_t)1024 * 1024 * 2));
  u16*   encb  = (u16*)  (ws + alloc((size_t)2048 * 1024 * 2));
  u16*   xpre  = (u16*)  (ws + alloc((size_t)1024 * 4096 * 2));
  u16*   hbuf  = (u16*)  (ws + alloc((size_t)Tdim * 64 * 128 * 2));
  u16*   cat   = (u16*)  (ws + alloc((size_t)1024 * 2048 * 2));
  float* qlin  = (float*)(ws + alloc((size_t)1024 * 1024 * 4));
  u16*   qn    = (u16*)  (ws + alloc((size_t)1024 * 1024 * 2));
  float* klin  = (float*)(ws + alloc((size_t)2048 * 1024 * 4));
  u16*   kn    = (u16*)  (ws + alloc((size_t)2048 * 1024 * 2));
  u16*   knT   = (u16*)  (ws + alloc((size_t)2048 * 1024 * 2));
  float* scores= (float*)(ws + alloc((size_t)8 * 128 * 256 * 4));
  u16*   attw  = (u16*)  (ws + alloc((size_t)8 * 128 * 256 * 2));
  float* hlin  = (float*)(ws + alloc((size_t)1024 * 1024 * 4));
  u16*   hid   = (u16*)  (ws + alloc((size_t)1024 * 1024 * 2));
  int*   bflag = (int*)  (ws + alloc(256));
  unsigned char* pmaskb = (unsigned char*)(ws + alloc((size_t)Bdim * Tdim * Vdim));
  const bool havePak = off <= ws_size;
  u16*   wob   = (u16*)  (ws + alloc((size_t)Vdim * Hdim * 2));
  const bool haveWob = off <= ws_size;
  if (!havePak) pmaskb = nullptr;
  if (!haveWob) wob = nullptr;
  (void)in_sizes; (void)n_in; (void)out_size;

  detect_bool_k<<<1, 256, 0, stream>>>((const unsigned char*)pmask, bflag);
  prep_k<<<15620, 256, 0, stream>>>(w_hh, w_ih, wq, wk, wc, enc, input_ids,
      tok, pos, b_ih, b_hh, whhb, wihb, wqb, wkb, wcb, encb, xbf, biasf, (u64*)hbuf);

  // x_pre = x @ w_ih_perm.T + (b_ih + b_hh)   -> bf16 (1024 x 4096)
  gemm_bt<u16, false, 0, false><<<dim3(32, 8, 1), 256, 0, stream>>>(
      xbf, 1024, 0, wihb, 1024, 0, xpre, 4096, 0, biasf, nullptr, nullptr, 1024, 1.f);

  // LSTM (0-63) + k-projection (64-191) + wo/mask streamers (192-255)
  lstm_plus<<<256, 256, 0, stream>>>(xpre, whhb, hbuf, encb, wkb, klin, bk,
                                     wo, wob, pmask, pmaskb, bflag);
  hbuf_cat_k<<<Tdim, 256, 0, stream>>>(hbuf, cat);

  // q = lstm_out @ wq.T + bq ; LN(g1,be1)
  gemm_bt<float, false, 0, false><<<dim3(8, 8, 1), 256, 0, stream>>>(
      cat, 2048, 0, wqb, 1024, 0, qlin, 1024, 0, bq, nullptr, nullptr, 1024, 1.f);
  ln_rows<<<1024, 256, 0, stream>>>(qlin, qn, g1, be1);
  ln_rows<<<2048, 256, 0, stream>>>(klin, kn, g1, be1);
  transp_k<<<dim3(16, 4, 8), 256, 0, stream>>>(kn, knT);

  // scores = qn @ kn^T * scale   (batched over 8)
  gemm_bt<float, false, 0, false><<<dim3(2, 1, 8), 256, 0, stream>>>(
      qn, 1024, 131072, kn, 1024, 262144, scores, 256, 32768, nullptr, nullptr, nullptr, 1024, 0.015625f);
  softmax_k<<<1024, 256, 0, stream>>>(scores, amask, bflag, attw);
  // ctx = w @ kn  -> right half of cat   (batched)
  gemm_bt<u16, false, 0, false><<<dim3(8, 1, 8), 256, 0, stream>>>(
      attw, 256, 32768, knT, 256, 262144, cat + 1024, 2048, 262144, nullptr, nullptr, nullptr, 256, 1.f);

  // hidden = LN( cat @ wc.T + bc ; g2,be2 )
  gemm_bt<float, false, 0, false><<<dim3(8, 8, 1), 256, 0, stream>>>(
      cat, 2048, 0, wcb, 2048, 0, hlin, 1024, 0, bc, nullptr, nullptr, 2048, 1.f);
  ln_rows<<<1024, 256, 0, stream>>>(hlin, hid, g2, be2);

  // logits = hidden @ wo.T + bo, masked — SWAP grid for B-tile reuse
  if (wob && pmaskb)
    gemm_bt<float, false, 2, true><<<dim3(8, 250, 1), 256, 0, stream>>>(
        hid, 1024, 0, wob, 1024, 0, out, 32000, 0, bo, pmaskb, nullptr, 1024, 1.f);
  else if (wob)
    gemm_bt<float, false, 1, true><<<dim3(8, 250, 1), 256, 0, stream>>>(
        hid, 1024, 0, wob, 1024, 0, out, 32000, 0, bo, pmask, bflag, 1024, 1.f);
  else
    gemm_bt<float, true, 1, true><<<dim3(8, 250, 1), 256, 0, stream>>>(
        hid, 1024, 0, wo, 1024, 0, out, 32000, 0, bo, pmask, bflag, 1024, 1.f);
}

// Round 9
// 801.726 us; speedup vs baseline: 4.0184x; 1.1947x over previous
//
#include <hip/hip_runtime.h>
#include <cstdint>
#include <cstddef>

#define Bdim 8
#define Tdim 128
#define Sdim 256
#define Hdim 1024
#define Vdim 32000
#define SENT 0xFFFFFFFFFFFFFFFFULL

typedef unsigned short u16;
typedef unsigned long long u64;
typedef __attribute__((ext_vector_type(8))) short short8;
typedef __attribute__((ext_vector_type(4))) short short4v;
typedef __attribute__((ext_vector_type(4))) float f32x4;
typedef __attribute__((ext_vector_type(2))) unsigned long long u64x2;

union Frag { short8 v; short4v h[2]; };

__device__ __forceinline__ float bf2f(u16 u){
  union { unsigned int i; float f; } x; x.i = ((unsigned int)u) << 16; return x.f;
}
__device__ __forceinline__ u16 f2b(float f){
  union { float f; unsigned int u; } x; x.f = f;
  unsigned int r = x.u + 0x7FFFu + ((x.u >> 16) & 1u);  // RNE
  return (u16)(r >> 16);
}
__device__ __forceinline__ float ftanh(float x){
  x = fminf(10.f, fmaxf(-10.f, x));
  const float e = __expf(2.f * x);
  return (e - 1.f) / (e + 1.f);
}

__device__ __forceinline__ void gload16(const void* g, void* l){
  __builtin_amdgcn_global_load_lds((const __attribute__((address_space(1))) unsigned int*)g,
                                   (__attribute__((address_space(3))) unsigned int*)l, 16, 0, 0);
}

// 16B-cell swizzle for 64B-wide LDS tile rows (4 cells/row)
__device__ __forceinline__ int qsw(int r){ return (r + (r >> 2)) & 3; }

__device__ __forceinline__ u64 aload(const u64* p){
  return __hip_atomic_load(p, __ATOMIC_RELAXED, __HIP_MEMORY_SCOPE_AGENT);
}
__device__ __forceinline__ void astore(u64* p, u64 v){
  __hip_atomic_store(p, v, __ATOMIC_RELAXED, __HIP_MEMORY_SCOPE_AGENT);
}

__global__ __launch_bounds__(256) void detect_bool_k(const unsigned char* __restrict__ p, int* __restrict__ flag){
  __shared__ int s;
  if (threadIdx.x == 0) s = 0;
  __syncthreads();
  int loc = 0;
  for (int i = threadIdx.x; i < 65536; i += 256)
    if ((i & 3) && p[i]) loc = 1;
  if (loc) atomicOr(&s, 1);
  __syncthreads();
  if (threadIdx.x == 0) flag[0] = s;
}

__device__ __forceinline__ bool mask_at(const void* m, size_t idx, int byteflag){
  if (byteflag) return ((const unsigned char*)m)[idx] != 0;
  return ((const int*)m)[idx] != 0;
}

// ---------------- 2-phase double-buffered GEMM core
// MASK: 0 none, 1 runtime-dtype mask via mflag, 2 byte mask.
template<typename OutT, bool BF32, int MASK>
__device__ __forceinline__ void gemm_core(
    char* ldsA0, char* ldsB0, char* ldsA1, char* ldsB1,
    int m0, int n0, int z,
    const u16* __restrict__ A, int lda, long sA,
    const void* __restrict__ Bp, int ldb, long sB,
    OutT* __restrict__ C, int ldc, long sC,
    const float* __restrict__ bias,
    const void* __restrict__ mask,
    const int* __restrict__ mflag,
    int K, float alpha)
{
  const int tid  = threadIdx.x;
  const int lane = tid & 63, wid = tid >> 6;
  const int lm = lane & 15, lg = lane >> 4;
  const int wm = wid >> 1, wn = wid & 1;            // 2x2 waves, 64x64 each
  const char* Ab = (const char*)(A + (size_t)z * sA);

  f32x4 acc[4][4];
#pragma unroll
  for (int i = 0; i < 4; i++)
#pragma unroll
    for (int j = 0; j < 4; j++) acc[i][j] = (f32x4){0.f, 0.f, 0.f, 0.f};

  const int brow = tid >> 1, bhalf = tid & 1;       // BF32 staging coords
  const int qb_st = qsw(brow);

  auto stageA = [&](char* dst, int k0){
    const char* ga = Ab + ((size_t)m0 * lda + k0) * 2;
    const int f0 = tid, f1 = tid + 256;
    const int r0 = f0 >> 2, r1 = f1 >> 2;
    gload16(ga + (size_t)r0 * (lda * 2) + ((f0 & 3) ^ qsw(r0)) * 16, dst + (f0 & ~63) * 16);
    gload16(ga + (size_t)r1 * (lda * 2) + ((f1 & 3) ^ qsw(r1)) * 16, dst + (f1 & ~63) * 16);
  };
  auto stageB16 = [&](char* dst, int k0){
    const char* gb = (const char*)((const u16*)Bp + (size_t)z * sB) + ((size_t)n0 * ldb + k0) * 2;
    const int f0 = tid, f1 = tid + 256;
    const int r0 = f0 >> 2, r1 = f1 >> 2;
    gload16(gb + (size_t)r0 * (ldb * 2) + ((f0 & 3) ^ qsw(r0)) * 16, dst + (f0 & ~63) * 16);
    gload16(gb + (size_t)r1 * (ldb * 2) + ((f1 & 3) ^ qsw(r1)) * 16, dst + (f1 & ~63) * 16);
  };

  float4 nv0, nv1, nv2, nv3;                        // BF32 in-flight tile
  auto loadB32 = [&](int k0){
    const float* Bf = (const float*)Bp + (size_t)z * sB;
    const float4* src = (const float4*)(Bf + (size_t)(n0 + brow) * ldb + k0 + bhalf * 16);
    nv0 = src[0]; nv1 = src[1]; nv2 = src[2]; nv3 = src[3];
  };
  auto writeB32 = [&](char* dst){
    union { short8 v; short s[8]; } p0, p1;
    p0.s[0]=(short)f2b(nv0.x); p0.s[1]=(short)f2b(nv0.y); p0.s[2]=(short)f2b(nv0.z); p0.s[3]=(short)f2b(nv0.w);
    p0.s[4]=(short)f2b(nv1.x); p0.s[5]=(short)f2b(nv1.y); p0.s[6]=(short)f2b(nv1.z); p0.s[7]=(short)f2b(nv1.w);
    p1.s[0]=(short)f2b(nv2.x); p1.s[1]=(short)f2b(nv2.y); p1.s[2]=(short)f2b(nv2.z); p1.s[3]=(short)f2b(nv2.w);
    p1.s[4]=(short)f2b(nv3.x); p1.s[5]=(short)f2b(nv3.y); p1.s[6]=(short)f2b(nv3.z); p1.s[7]=(short)f2b(nv3.w);
    char* base = dst + brow * 64;
    *(short8*)(base + (((bhalf * 2 + 0) ^ qb_st) * 16)) = p0.v;
    *(short8*)(base + (((bhalf * 2 + 1) ^ qb_st) * 16)) = p1.v;
  };

  stageA(ldsA0, 0);
  if (BF32) { loadB32(0); writeB32(ldsB0); }
  else stageB16(ldsB0, 0);
  __syncthreads();

  char *cA = ldsA0, *cB = ldsB0, *nA = ldsA1, *nB = ldsB1;
  const int nk = K >> 5;
  for (int i = 0; i < nk; i++) {
    const bool more = (i + 1) < nk;
    if (more) {               // issue next-tile loads before compute (T3/T14)
      stageA(nA, (i + 1) << 5);
      if (BF32) loadB32((i + 1) << 5);
      else stageB16(nB, (i + 1) << 5);
    }
    Frag a[4], b[4];
#pragma unroll
    for (int mi = 0; mi < 4; mi++) {
      const int rr = wm * 64 + mi * 16 + lm;
      const int q = qsw(rr);
      const char* p = cA + rr * 64 + (lg & 1) * 8;
      a[mi].h[0] = *(const short4v*)(p + (((lg >> 1) ^ q) * 16));
      a[mi].h[1] = *(const short4v*)(p + ((((lg >> 1) | 2) ^ q) * 16));
    }
#pragma unroll
    for (int ni = 0; ni < 4; ni++) {
      const int rr = wn * 64 + ni * 16 + lm;
      const int q = qsw(rr);
      const char* p = cB + rr * 64 + (lg & 1) * 8;
      b[ni].h[0] = *(const short4v*)(p + (((lg >> 1) ^ q) * 16));
      b[ni].h[1] = *(const short4v*)(p + ((((lg >> 1) | 2) ^ q) * 16));
    }
#pragma unroll
    for (int mi = 0; mi < 4; mi++)
#pragma unroll
      for (int ni = 0; ni < 4; ni++)
        acc[mi][ni] = __builtin_amdgcn_mfma_f32_16x16x32_bf16(a[mi].v, b[ni].v, acc[mi][ni], 0, 0, 0);
    if (BF32 && more) writeB32(nB);    // convert-late
    __syncthreads();
    char* t;
    t = cA; cA = nA; nA = t;
    t = cB; cB = nB; nB = t;
  }

  const int bflag = (MASK == 1) ? *mflag : 0;
#pragma unroll
  for (int mi = 0; mi < 4; mi++) {
#pragma unroll
    for (int ni = 0; ni < 4; ni++) {
      const int row = m0 + wm * 64 + mi * 16 + lg * 4;
      const int col = n0 + wn * 64 + ni * 16 + lm;
      const float bb = bias ? bias[col] : 0.f;
#pragma unroll
      for (int j = 0; j < 4; j++) {
        float v = acc[mi][ni][j] * alpha + bb;
        const size_t midx = (size_t)(row + j) * ldc + col;
        if (MASK == 1) { if (!mask_at(mask, midx, bflag)) v = -10000.0f; }
        if (MASK == 2) { if (!((const unsigned char*)mask)[midx]) v = -10000.0f; }
        const size_t o = (size_t)z * sC + midx;
        if constexpr (sizeof(OutT) == 2) C[o] = (OutT)f2b(v); else C[o] = (OutT)v;
      }
    }
  }
}

template<typename OutT, bool BF32, int MASK, bool SWAP>
__global__ __launch_bounds__(256) void gemm_bt(
    const u16* __restrict__ A, int lda, long sA,
    const void* __restrict__ Bp, int ldb, long sB,
    OutT* __restrict__ C, int ldc, long sC,
    const float* __restrict__ bias,
    const void* __restrict__ mask,
    const int* __restrict__ mflag,
    int K, float alpha)
{
  __shared__ alignas(16) char lds[32768];
  const int m0 = (SWAP ? blockIdx.x : blockIdx.y) * 128;
  const int n0 = (SWAP ? blockIdx.y : blockIdx.x) * 128;
  gemm_core<OutT, BF32, MASK>(lds, lds + 8192, lds + 16384, lds + 24576,
      m0, n0, blockIdx.z, A, lda, sA, Bp, ldb, sB, C, ldc, sC,
      bias, mask, mflag, K, alpha);
}

// ---------------- persistent LSTM body: value-polled sync, swapped-operand MFMA
// mfma(whh_frag, h_frag, acc): D row = gate col (lg*4+j), D col = batch (lm).
// With gate-interleaved perm, lane (lg,lm) holds acc[j]=(i,f,g,o) of unit
// wid*4+lg, batch lm — cell update needs NO transpose, no g_lds, no hout.
// h gathered via 3 shfl and stored u64/lane directly to the packet.
__device__ void lstm_body(char* smem,
    const u16* __restrict__ xpre, const u16* __restrict__ whh,
    u16* __restrict__ hbuf, int bx)
{
  u16* wlds = (u16*)smem;                       // 64x1024, cell c^(r&7) swizzle
  u16* hlds = (u16*)(smem + 131072);            // 8x1024,  cell c^m swizzle
  const int tid = threadIdx.x, lane = tid & 63, wid = tid >> 6;
  const int lm = lane & 15, lg = lane >> 4;
  const int gcol0 = bx * 64;

  for (int q = tid; q < 8192; q += 256) {
    const int r = q >> 7, cc = q & 127;
    gload16(whh + (size_t)(gcol0 + r) * 1024 + (size_t)(cc ^ (r & 7)) * 8,
            (char*)wlds + (q & ~63) * 16);
  }

  float c_reg = 0.f;
  const int rloc = wid * 16 + lm, swb = rloc & 7, swa = lm & 7;
  const u16* wl = wlds + rloc * 1024;
  const u16* hl = hlds + swa * 1024;
  const int pk = tid >> 2, qq = tid & 3;            // consumer: packet, quarter
  // xpre: lane loads 4 consecutive gate cols (unit wid*4+lg) for batch lm
  const u16* xp = xpre + (size_t)(lm * Tdim) * 4096 + gcol0 + wid * 16 + lg * 4;

  for (int t = 0; t < Tdim; t++) {
    u64 xw = 0;
    if (lm < 8) xw = *(const u64*)(xp + (size_t)t * 4096);
    if (t > 0) {
      const u64* ps = (const u64*)(hbuf + ((size_t)(t - 1) * 64 + pk) * 128) + qq * 8;
      u64 w0=SENT,w1=SENT,w2=SENT,w3=SENT,w4=SENT,w5=SENT,w6=SENT,w7=SENT;
      for (;;) {
        if (w0 == SENT) w0 = aload(ps + 0);
        if (w1 == SENT) w1 = aload(ps + 1);
        if (w2 == SENT) w2 = aload(ps + 2);
        if (w3 == SENT) w3 = aload(ps + 3);
        if (w4 == SENT) w4 = aload(ps + 4);
        if (w5 == SENT) w5 = aload(ps + 5);
        if (w6 == SENT) w6 = aload(ps + 6);
        if (w7 == SENT) w7 = aload(ps + 7);
        if (w0 != SENT && w1 != SENT && w2 != SENT && w3 != SENT &&
            w4 != SENT && w5 != SENT && w6 != SENT && w7 != SENT) break;
        __builtin_amdgcn_s_sleep(1);
      }
      {
        const int m = qq * 2;
        u64x2 a; a[0] = w0; a[1] = w1;
        u64x2 b; b[0] = w2; b[1] = w3;
        *(u64x2*)((char*)hlds + m * 2048 + (((pk * 2 + 0) ^ m) * 16)) = a;
        *(u64x2*)((char*)hlds + m * 2048 + (((pk * 2 + 1) ^ m) * 16)) = b;
      }
      {
        const int m = qq * 2 + 1;
        u64x2 a; a[0] = w4; a[1] = w5;
        u64x2 b; b[0] = w6; b[1] = w7;
        *(u64x2*)((char*)hlds + m * 2048 + (((pk * 2 + 0) ^ m) * 16)) = a;
        *(u64x2*)((char*)hlds + m * 2048 + (((pk * 2 + 1) ^ m) * 16)) = b;
      }
    }
    __syncthreads();   // S2: hlds ready

    f32x4 acc0, acc1, acc2, acc3;
    {
      union { u64 w; u16 s[4]; } xu; xu.w = xw;
      acc0[0] = bf2f(xu.s[0]); acc0[1] = bf2f(xu.s[1]);
      acc0[2] = bf2f(xu.s[2]); acc0[3] = bf2f(xu.s[3]);
    }
    acc1 = (f32x4){0.f,0.f,0.f,0.f};
    acc2 = (f32x4){0.f,0.f,0.f,0.f};
    acc3 = (f32x4){0.f,0.f,0.f,0.f};

    if (t > 0) {
#pragma unroll
      for (int kk = 0; kk < 32; kk++) {
        const int c0 = kk * 4 + (lg >> 1);
        const int sub = (lg & 1) * 4;
        Frag aw, bh;
        aw.h[0] = *(const short4v*)(wl + ((c0 ^ swb) << 3) + sub);
        aw.h[1] = *(const short4v*)(wl + (((c0 + 2) ^ swb) << 3) + sub);
        bh.h[0] = *(const short4v*)(hl + ((c0 ^ swa) << 3) + sub);
        bh.h[1] = *(const short4v*)(hl + (((c0 + 2) ^ swa) << 3) + sub);
        if ((kk & 3) == 0)      acc0 = __builtin_amdgcn_mfma_f32_16x16x32_bf16(aw.v, bh.v, acc0, 0, 0, 0);
        else if ((kk & 3) == 1) acc1 = __builtin_amdgcn_mfma_f32_16x16x32_bf16(aw.v, bh.v, acc1, 0, 0, 0);
        else if ((kk & 3) == 2) acc2 = __builtin_amdgcn_mfma_f32_16x16x32_bf16(aw.v, bh.v, acc2, 0, 0, 0);
        else                    acc3 = __builtin_amdgcn_mfma_f32_16x16x32_bf16(aw.v, bh.v, acc3, 0, 0, 0);
      }
    }
    const f32x4 g4 = (acc0 + acc1) + (acc2 + acc3);  // i,f,g,o for (batch lm, unit wid*4+lg)

    const float si = 1.f / (1.f + __expf(-g4[0]));
    const float sf = 1.f / (1.f + __expf(-g4[1]));
    const float so = 1.f / (1.f + __expf(-g4[3]));
    const float cn = sf * c_reg + si * ftanh(g4[2]);
    c_reg = cn;
    const float hn = so * ftanh(cn);
    const int hb = (int)f2b(hn);

    // gather units wid*4+0..3 of batch lm from lanes lm, lm+16, lm+32, lm+48
    const int v0 = __shfl(hb, lm, 64);
    const int v1 = __shfl(hb, lm + 16, 64);
    const int v2 = __shfl(hb, lm + 32, 64);
    const int v3 = __shfl(hb, lm + 48, 64);
    if (lg == 0 && lm < 8) {
      const u64 pack = (u64)(v0 & 0xFFFF) | ((u64)(v1 & 0xFFFF) << 16)
                     | ((u64)(v2 & 0xFFFF) << 32) | ((u64)(v3 & 0xFFFF) << 48);
      astore((u64*)(hbuf + ((size_t)t * 64 + bx) * 128 + lm * 16 + wid * 4), pack);
    }
    __syncthreads();   // S5: hlds reads done before next step's copy overwrites
  }
}

// blocks 0..63: LSTM; 64..191: k-projection GEMM; 192..255: streamers
// (wo fp32->bf16 convert + pattern_mask byte-pack) hidden under the LSTM.
__global__ __launch_bounds__(256) void lstm_plus(
    const u16* __restrict__ xpre, const u16* __restrict__ whh,
    u16* __restrict__ hbuf,
    const u16* __restrict__ encb, const u16* __restrict__ wkb,
    float* __restrict__ klin, const float* __restrict__ bk,
    const float* __restrict__ wo, u16* __restrict__ wob,
    const void* __restrict__ pmask, unsigned char* __restrict__ pmaskb,
    const int* __restrict__ bflag)
{
  __shared__ alignas(16) char smem[147456];
  const int bx = blockIdx.x;
  if (bx < 64) {
    lstm_body(smem, xpre, whh, hbuf, bx);
  } else if (bx < 192) {
    const int idx = bx - 64;               // 16 m-tiles x 8 n-tiles
    gemm_core<float, false, 0>(smem, smem + 8192, smem + 16384, smem + 24576,
        (idx >> 3) * 128, (idx & 7) * 128, 0,
        encb, 1024, 0, wkb, 1024, 0, klin, 1024, 0, bk, nullptr, nullptr, 1024, 1.f);
  } else {
    const int s = bx - 192;                // 0..63
    const int tid = threadIdx.x;
    if (wob) {
      for (int r = s; r < Vdim; r += 64) {
        const size_t i = (size_t)r * 1024 + tid * 4;
        const float4 v = *(const float4*)(wo + i);
        u16* op = wob + i;
        op[0] = f2b(v.x); op[1] = f2b(v.y); op[2] = f2b(v.z); op[3] = f2b(v.w);
      }
    }
    if (pmaskb) {
      const int bfl = *bflag;
      const size_t total = (size_t)Bdim * Tdim * Vdim;       // 32,768,000
      const size_t nthr = 64 * 256;
      if (bfl == 0) {     // int32 bools -> bytes
        for (size_t i = ((size_t)s * 256 + tid) * 4; i < total; i += nthr * 4) {
          const int4 v = *(const int4*)((const int*)pmask + i);
          uchar4 o;
          o.x = v.x ? 1 : 0; o.y = v.y ? 1 : 0; o.z = v.z ? 1 : 0; o.w = v.w ? 1 : 0;
          *(uchar4*)(pmaskb + i) = o;
        }
      } else {            // already bytes -> copy 16B
        for (size_t i = ((size_t)s * 256 + tid) * 16; i < total; i += nthr * 16) {
          *(int4*)(pmaskb + i) = *(const int4*)((const unsigned char*)pmask + i);
        }
      }
    }
  }
}

// hbuf [t][p][m][u16x16] -> cat rows (m*Tdim+t), cols p*16.. (left half of 2048)
__global__ __launch_bounds__(256) void hbuf_cat_k(const u16* __restrict__ hbuf, u16* __restrict__ cat){
  const int t = blockIdx.x, tid = threadIdx.x;
  const int p = tid >> 2, q = tid & 3;
  const u64* src = (const u64*)(hbuf + ((size_t)t * 64 + p) * 128);
#pragma unroll
  for (int m = 0; m < 8; m++) {
    const u64 v = src[m * 4 + q];
    *(u64*)(cat + (size_t)(m * Tdim + t) * 2048 + p * 16 + q * 4) = v;
  }
}

// ---------------- fused prep: weight converts + embed + bias + hbuf sentinel
__global__ __launch_bounds__(256) void prep_k(
    const float* __restrict__ w_hh, const float* __restrict__ w_ih,
    const float* __restrict__ wq,   const float* __restrict__ wk,
    const float* __restrict__ wc,   const float* __restrict__ enc,
    const int* __restrict__ ids,
    const float* __restrict__ tok,  const float* __restrict__ pos,
    const float* __restrict__ b_ih, const float* __restrict__ b_hh,
    u16* __restrict__ whhb, u16* __restrict__ wihb,
    u16* __restrict__ wqb,  u16* __restrict__ wkb,  u16* __restrict__ wcb,
    u16* __restrict__ encb, u16* __restrict__ xbf,
    float* __restrict__ biasf, u64* __restrict__ hbuf)
{
  const int b = blockIdx.x, tid = threadIdx.x;
  if (b < 8192) {                        // gate-permuted whh / w_ih rows
    const bool ih = b >= 4096;
    const int r = b & 4095;
    const int p = (r & 3) * Hdim + (r >> 2);
    const float4 v = *(const float4*)((ih ? w_ih : w_hh) + (size_t)p * Hdim + tid * 4);
    u16* op = (ih ? wihb : whhb) + (size_t)r * Hdim + tid * 4;
    op[0] = f2b(v.x); op[1] = f2b(v.y); op[2] = f2b(v.z); op[3] = f2b(v.w);
  } else if (b < 9216) {
    const size_t i = (size_t)(b - 8192) * 1024 + tid * 4;
    const float4 v = *(const float4*)(wq + i);
    u16* op = wqb + i;
    op[0] = f2b(v.x); op[1] = f2b(v.y); op[2] = f2b(v.z); op[3] = f2b(v.w);
  } else if (b < 10240) {
    const size_t i = (size_t)(b - 9216) * 1024 + tid * 4;
    const float4 v = *(const float4*)(wk + i);
    u16* op = wkb + i;
    op[0] = f2b(v.x); op[1] = f2b(v.y); op[2] = f2b(v.z); op[3] = f2b(v.w);
  } else if (b < 12288) {
    const size_t i = (size_t)(b - 10240) * 1024 + tid * 4;
    const float4 v = *(const float4*)(wc + i);
    u16* op = wcb + i;
    op[0] = f2b(v.x); op[1] = f2b(v.y); op[2] = f2b(v.z); op[3] = f2b(v.w);
  } else if (b < 14336) {
    const size_t i = (size_t)(b - 12288) * 1024 + tid * 4;
    const float4 v = *(const float4*)(enc + i);
    u16* op = encb + i;
    op[0] = f2b(v.x); op[1] = f2b(v.y); op[2] = f2b(v.z); op[3] = f2b(v.w);
  } else if (b < 15360) {                // embed
    const int row = b - 14336;
    const int t = row & (Tdim - 1);
    const int id = ids[row];
    const int h0 = tid * 4;
    const float4 a = *(const float4*)(tok + (size_t)id * Hdim + h0);
    const float4 p = *(const float4*)(pos + (size_t)t * Hdim + h0);
    u16* op = xbf + (size_t)row * Hdim + h0;
    op[0] = f2b(a.x + p.x); op[1] = f2b(a.y + p.y); op[2] = f2b(a.z + p.z); op[3] = f2b(a.w + p.w);
  } else if (b < 15364) {                // bias fold (gate-permuted)
    const int n0 = (b - 15360) * 1024 + tid * 4;
#pragma unroll
    for (int j = 0; j < 4; j++) {
      const int n = n0 + j;
      const int p = (n & 3) * Hdim + (n >> 2);
      biasf[n] = b_ih[p] + b_hh[p];
    }
  } else {                               // hbuf sentinel: 256 blocks x 256 thr x 4 u64
    const size_t i = ((size_t)(b - 15364) * 256 + tid) * 4;
    u64x2 s2; s2[0] = SENT; s2[1] = SENT;
    *(u64x2*)(hbuf + i)     = s2;
    *(u64x2*)(hbuf + i + 2) = s2;
  }
}

// ---------------- small kernels
__global__ __launch_bounds__(256) void ln_rows(const float* __restrict__ in, u16* __restrict__ out,
                                               const float* __restrict__ g, const float* __restrict__ be){
  const int row = blockIdx.x, tid = threadIdx.x;
  const int lane = tid & 63, wid = tid >> 6;
  const float4 x = *(const float4*)(in + (size_t)row * Hdim + tid * 4);
  float s = x.x + x.y + x.z + x.w;
  float q = x.x * x.x + x.y * x.y + x.z * x.z + x.w * x.w;
  for (int o = 32; o; o >>= 1) { s += __shfl_down(s, o, 64); q += __shfl_down(q, o, 64); }
  __shared__ float sm[8];
  if (lane == 0) { sm[wid] = s; sm[4 + wid] = q; }
  __syncthreads();
  const float ts = sm[0] + sm[1] + sm[2] + sm[3];
  const float tq = sm[4] + sm[5] + sm[6] + sm[7];
  const float mean = ts * (1.f / Hdim);
  const float var  = tq * (1.f / Hdim) - mean * mean;
  const float r = rsqrtf(var + 1e-5f);
  const int h0 = tid * 4;
  const float4 gv = *(const float4*)(g + h0);
  const float4 bv = *(const float4*)(be + h0);
  u16* op = out + (size_t)row * Hdim + h0;
  op[0] = f2b((x.x - mean) * r * gv.x + bv.x);
  op[1] = f2b((x.y - mean) * r * gv.y + bv.y);
  op[2] = f2b((x.z - mean) * r * gv.z + bv.z);
  op[3] = f2b((x.w - mean) * r * gv.w + bv.w);
}
__global__ __launch_bounds__(256) void softmax_k(const float* __restrict__ sc, const void* __restrict__ am,
                                                 const int* __restrict__ mflag, u16* __restrict__ w){
  const int row = blockIdx.x, tid = threadIdx.x;
  const int lane = tid & 63, wid = tid >> 6;
  const int b = row >> 7;
  const int bflag = *mflag;
  const float v = sc[(size_t)row * Sdim + tid];
  const bool mk = mask_at(am, (size_t)b * Sdim + tid, bflag);
  const float vm = mk ? v : -10000.0f;
  float mx = vm;
  for (int o = 32; o; o >>= 1) mx = fmaxf(mx, __shfl_down(mx, o, 64));
  __shared__ float sm[8];
  if (lane == 0) sm[wid] = mx;
  __syncthreads();
  mx = fmaxf(fmaxf(sm[0], sm[1]), fmaxf(sm[2], sm[3]));
  const float ex = mk ? expf(vm - mx) : 0.f;
  float ss = ex;
  for (int o = 32; o; o >>= 1) ss += __shfl_down(ss, o, 64);
  if (lane == 0) sm[4 + wid] = ss;
  __syncthreads();
  const float tot = sm[4] + sm[5] + sm[6] + sm[7];
  w[(size_t)row * Sdim + tid] = f2b(ex / (tot + 1e-6f));
}
__global__ __launch_bounds__(256) void transp_k(const u16* __restrict__ kn, u16* __restrict__ knT){
  __shared__ u16 tile[64][65];
  const int b = blockIdx.z, h0 = blockIdx.x * 64, s0 = blockIdx.y * 64;
  const u16* src = kn  + (size_t)b * Sdim * Hdim;
  u16* dst       = knT + (size_t)b * Hdim * Sdim;
  for (int e = threadIdx.x; e < 4096; e += 256) {
    const int r = e >> 6, c = e & 63;
    tile[r][c] = src[(size_t)(s0 + r) * Hdim + h0 + c];
  }
  __syncthreads();
  for (int e = threadIdx.x; e < 4096; e += 256) {
    const int hr = e >> 6, scc = e & 63;
    dst[(size_t)(h0 + hr) * Sdim + s0 + scc] = tile[scc][hr];
  }
}

extern "C" void kernel_launch(void* const* d_in, const int* in_sizes, int n_in,
                              void* d_out, int out_size, void* d_ws, size_t ws_size,
                              hipStream_t stream) {
  const int*   input_ids = (const int*)d_in[0];
  const float* enc   = (const float*)d_in[1];
  const void*  pmask = d_in[2];
  const void*  amask = d_in[3];
  const float* tok  = (const float*)d_in[4];
  const float* pos  = (const float*)d_in[5];
  const float* w_ih = (const float*)d_in[6];
  const float* w_hh = (const float*)d_in[7];
  const float* b_ih = (const float*)d_in[8];
  const float* b_hh = (const float*)d_in[9];
  const float* wq = (const float*)d_in[10];
  const float* bq = (const float*)d_in[11];
  const float* wk = (const float*)d_in[12];
  const float* bk = (const float*)d_in[13];
  const float* wc = (const float*)d_in[14];
  const float* bc = (const float*)d_in[15];
  const float* wo = (const float*)d_in[16];
  const float* bo = (const float*)d_in[17];
  const float* g1  = (const float*)d_in[18];
  const float* be1 = (const float*)d_in[19];
  const float* g2  = (const float*)d_in[20];
  const float* be2 = (const float*)d_in[21];
  float* out = (float*)d_out;

  char* ws = (char*)d_ws;
  size_t off = 0;
  auto alloc = [&](size_t b){ size_t o = off; off += (b + 255) & ~(size_t)255; return o; };
  u16*   whhb  = (u16*)  (ws + alloc((size_t)4096 * 1024 * 2));
  u16*   wihb  = (u16*)  (ws + alloc((size_t)4096 * 1024 * 2));
  u16*   wqb   = (u16*)  (ws + alloc((size_t)1024 * 1024 * 2));
  u16*   wkb   = (u16*)  (ws + alloc((size_t)1024 * 1024 * 2));
  u16*   wcb   = (u16*)  (ws + alloc((size_t)1024 * 2048 * 2));
  float* biasf = (float*)(ws + alloc(4096 * 4));
  u16*   xbf   = (u16*)  (ws + alloc((size_t)1024 * 1024 * 2));
  u16*   encb  = (u16*)  (ws + alloc((size_t)2048 * 1024 * 2));
  u16*   xpre  = (u16*)  (ws + alloc((size_t)1024 * 4096 * 2));
  u16*   hbuf  = (u16*)  (ws + alloc((size_t)Tdim * 64 * 128 * 2));
  u16*   cat   = (u16*)  (ws + alloc((size_t)1024 * 2048 * 2));
  float* qlin  = (float*)(ws + alloc((size_t)1024 * 1024 * 4));
  u16*   qn    = (u16*)  (ws + alloc((size_t)1024 * 1024 * 2));
  float* klin  = (float*)(ws + alloc((size_t)2048 * 1024 * 4));
  u16*   kn    = (u16*)  (ws + alloc((size_t)2048 * 1024 * 2));
  u16*   knT   = (u16*)  (ws + alloc((size_t)2048 * 1024 * 2));
  float* scores= (float*)(ws + alloc((size_t)8 * 128 * 256 * 4));
  u16*   attw  = (u16*)  (ws + alloc((size_t)8 * 128 * 256 * 2));
  float* hlin  = (float*)(ws + alloc((size_t)1024 * 1024 * 4));
  u16*   hid   = (u16*)  (ws + alloc((size_t)1024 * 1024 * 2));
  int*   bflag = (int*)  (ws + alloc(256));
  unsigned char* pmaskb = (unsigned char*)(ws + alloc((size_t)Bdim * Tdim * Vdim));
  const bool havePak = off <= ws_size;
  u16*   wob   = (u16*)  (ws + alloc((size_t)Vdim * Hdim * 2));
  const bool haveWob = off <= ws_size;
  if (!havePak) pmaskb = nullptr;
  if (!haveWob) wob = nullptr;
  (void)in_sizes; (void)n_in; (void)out_size;

  detect_bool_k<<<1, 256, 0, stream>>>((const unsigned char*)pmask, bflag);
  prep_k<<<15620, 256, 0, stream>>>(w_hh, w_ih, wq, wk, wc, enc, input_ids,
      tok, pos, b_ih, b_hh, whhb, wihb, wqb, wkb, wcb, encb, xbf, biasf, (u64*)hbuf);

  // x_pre = x @ w_ih_perm.T + (b_ih + b_hh)   -> bf16 (1024 x 4096)
  gemm_bt<u16, false, 0, false><<<dim3(32, 8, 1), 256, 0, stream>>>(
      xbf, 1024, 0, wihb, 1024, 0, xpre, 4096, 0, biasf, nullptr, nullptr, 1024, 1.f);

  // LSTM (0-63) + k-projection (64-191) + wo/mask streamers (192-255)
  lstm_plus<<<256, 256, 0, stream>>>(xpre, whhb, hbuf, encb, wkb, klin, bk,
                                     wo, wob, pmask, pmaskb, bflag);
  hbuf_cat_k<<<Tdim, 256, 0, stream>>>(hbuf, cat);

  // q = lstm_out @ wq.T + bq ; LN(g1,be1)
  gemm_bt<float, false, 0, false><<<dim3(8, 8, 1), 256, 0, stream>>>(
      cat, 2048, 0, wqb, 1024, 0, qlin, 1024, 0, bq, nullptr, nullptr, 1024, 1.f);
  ln_rows<<<1024, 256, 0, stream>>>(qlin, qn, g1, be1);
  ln_rows<<<2048, 256, 0, stream>>>(klin, kn, g1, be1);
  transp_k<<<dim3(16, 4, 8), 256, 0, stream>>>(kn, knT);

  // scores = qn @ kn^T * scale   (batched over 8)
  gemm_bt<float, false, 0, false><<<dim3(2, 1, 8), 256, 0, stream>>>(
      qn, 1024, 131072, kn, 1024, 262144, scores, 256, 32768, nullptr, nullptr, nullptr, 1024, 0.015625f);
  softmax_k<<<1024, 256, 0, stream>>>(scores, amask, bflag, attw);
  // ctx = w @ kn  -> right half of cat   (batched)
  gemm_bt<u16, false, 0, false><<<dim3(8, 1, 8), 256, 0, stream>>>(
      attw, 256, 32768, knT, 256, 262144, cat + 1024, 2048, 262144, nullptr, nullptr, nullptr, 256, 1.f);

  // hidden = LN( cat @ wc.T + bc ; g2,be2 )
  gemm_bt<float, false, 0, false><<<dim3(8, 8, 1), 256, 0, stream>>>(
      cat, 2048, 0, wcb, 2048, 0, hlin, 1024, 0, bc, nullptr, nullptr, 2048, 1.f);
  ln_rows<<<1024, 256, 0, stream>>>(hlin, hid, g2, be2);

  // logits = hidden @ wo.T + bo, masked — SWAP grid for B-tile reuse
  if (wob && pmaskb)
    gemm_bt<float, false, 2, true><<<dim3(8, 250, 1), 256, 0, stream>>>(
        hid, 1024, 0, wob, 1024, 0, out, 32000, 0, bo, pmaskb, nullptr, 1024, 1.f);
  else if (wob)
    gemm_bt<float, false, 1, true><<<dim3(8, 250, 1), 256, 0, stream>>>(
        hid, 1024, 0, wob, 1024, 0, out, 32000, 0, bo, pmask, bflag, 1024, 1.f);
  else
    gemm_bt<float, true, 1, true><<<dim3(8, 250, 1), 256, 0, stream>>>(
        hid, 1024, 0, wo, 1024, 0, out, 32000, 0, bo, pmask, bflag, 1024, 1.f);
}